// Round 1
// baseline (1609.687 us; speedup 1.0000x reference)
//
#include <hip/hip_runtime.h>
#include <hip/hip_bf16.h>
#include <math.h>

// Problem constants
static constexpr int Bc = 2;
static constexpr int Sc = 2048;
static constexpr int Dc = 1024;
static constexpr int Hc = 2048;
static constexpr int Ac = 128;
static constexpr int Ec = 8;
static constexpr int GSc = 4;
static constexpr int Gc = 2;
static constexpr int Kc = 2;
static constexpr int Nc = Bc * Sc;   // 4096 tokens
static constexpr float LN_EPSc = 1e-5f;

// ---------------- generic fp32 tiled GEMM ----------------
// C = op(A,B) where TRANSB=1: C[M,N] = A[M,K] @ B[N,K]^T ; TRANSB=0: C = A[M,K] @ B[K,N]
// EPI: 0 = store, 1 = silu(clip(v,-5,5)) store, 2 = C += alpha*v, 3 = C = rowscale[row]*v
template<int TRANSB, int EPI>
__global__ __launch_bounds__(256) void gemm_k(
    const float* __restrict__ Ag, const float* __restrict__ Bg, float* __restrict__ Cg,
    int M, int N, int K, float alpha, const float* __restrict__ rowscale,
    long long sA, long long sB, long long sC)
{
    const float* A = Ag + (long long)blockIdx.z * sA;
    const float* B = Bg + (long long)blockIdx.z * sB;
    float* C = Cg + (long long)blockIdx.z * sC;

    __shared__ float As[16][68];
    __shared__ float Bs[16][68];

    const int tid = threadIdx.x;
    const int tx = tid & 15;        // n-dim
    const int ty = tid >> 4;        // m-dim
    const int bm = blockIdx.y * 64;
    const int bn = blockIdx.x * 64;

    const int lr = tid >> 2;        // 0..63 : row of tile being loaded
    const int lc = (tid & 3) * 4;   // 0,4,8,12 : k group

    float acc[4][4] = {};

    for (int k0 = 0; k0 < K; k0 += 16) {
        // A tile: rows bm..bm+63, cols k0..k0+15  (A row-major [M,K])
        const float4 a4 = *(const float4*)(A + (long long)(bm + lr) * K + k0 + lc);
        As[lc + 0][lr] = a4.x; As[lc + 1][lr] = a4.y;
        As[lc + 2][lr] = a4.z; As[lc + 3][lr] = a4.w;
        if (TRANSB) {
            const float4 b4 = *(const float4*)(B + (long long)(bn + lr) * K + k0 + lc);
            Bs[lc + 0][lr] = b4.x; Bs[lc + 1][lr] = b4.y;
            Bs[lc + 2][lr] = b4.z; Bs[lc + 3][lr] = b4.w;
        } else {
            const float4 b4 = *(const float4*)(B + (long long)(k0 + ty) * N + bn + tx * 4);
            *(float4*)&Bs[ty][tx * 4] = b4;
        }
        __syncthreads();
        #pragma unroll
        for (int kk = 0; kk < 16; ++kk) {
            float av[4], bv[4];
            #pragma unroll
            for (int i = 0; i < 4; ++i) av[i] = As[kk][ty * 4 + i];
            #pragma unroll
            for (int j = 0; j < 4; ++j) bv[j] = Bs[kk][tx * 4 + j];
            #pragma unroll
            for (int i = 0; i < 4; ++i)
                #pragma unroll
                for (int j = 0; j < 4; ++j)
                    acc[i][j] += av[i] * bv[j];
        }
        __syncthreads();
    }

    #pragma unroll
    for (int i = 0; i < 4; ++i) {
        const long long row = bm + ty * 4 + i;
        float rs = 1.f;
        if (EPI == 3) rs = rowscale[row];
        #pragma unroll
        for (int j = 0; j < 4; ++j) {
            const long long cidx = row * (long long)N + bn + tx * 4 + j;
            float v = acc[i][j];
            if (EPI == 0) {
                C[cidx] = v;
            } else if (EPI == 1) {
                v = fminf(fmaxf(v, -5.f), 5.f);
                C[cidx] = v / (1.f + expf(-v));
            } else if (EPI == 2) {
                C[cidx] += alpha * v;
            } else {
                C[cidx] = rs * v;
            }
        }
    }
}

// ---------------- LayerNorm over A=128, one wave per row ----------------
__global__ __launch_bounds__(64) void ln_k(const float* __restrict__ in, float* __restrict__ out,
                                           const float* __restrict__ g, const float* __restrict__ b)
{
    const int row = blockIdx.x;
    const int lane = threadIdx.x;
    float z0 = in[(long long)row * 128 + lane];
    float z1 = in[(long long)row * 128 + 64 + lane];
    float s = z0 + z1;
    for (int o = 32; o > 0; o >>= 1) s += __shfl_down(s, o, 64);
    s = __shfl(s, 0, 64);
    const float mu = s * (1.f / 128.f);
    const float d0 = z0 - mu, d1 = z1 - mu;
    float v = d0 * d0 + d1 * d1;
    for (int o = 32; o > 0; o >>= 1) v += __shfl_down(v, o, 64);
    v = __shfl(v, 0, 64);
    const float r = rsqrtf(v * (1.f / 128.f) + LN_EPSc);
    out[(long long)row * 128 + lane] = d0 * r * g[lane] + b[lane];
    out[(long long)row * 128 + 64 + lane] = d1 * r * g[lane + 64] + b[lane + 64];
}

// ---------------- hidden = silu(gate) * up ----------------
__global__ __launch_bounds__(256) void silu_mul_k(float* __restrict__ hidden,
                                                  const float* __restrict__ up, int n)
{
    int i = blockIdx.x * blockDim.x + threadIdx.x;
    const int stride = gridDim.x * blockDim.x;
    for (; i < n; i += stride) {
        const float g = hidden[i], u = up[i];
        hidden[i] = (g / (1.f + expf(-g))) * u;
    }
}

// ---------------- router: one wave per token ----------------
__global__ __launch_bounds__(64) void router_k(const float* __restrict__ x,
                                               const float* __restrict__ W_rg,
                                               const float* __restrict__ W_re,
                                               float* __restrict__ load, float* __restrict__ acc2,
                                               int* __restrict__ eidx, float* __restrict__ fw,
                                               float* __restrict__ dmsum)
{
    const int t = blockIdx.x;
    const int lane = threadIdx.x;
    const float* xr = x + (long long)t * Dc;
    float a0 = 0, a1 = 0, a2 = 0, a3 = 0, a4 = 0, a5 = 0;
    for (int d = lane; d < Dc; d += 64) {
        const float xv = xr[d];
        a0 += xv * W_rg[d];        a1 += xv * W_rg[Dc + d];
        a2 += xv * W_re[d];        a3 += xv * W_re[Dc + d];
        a4 += xv * W_re[2 * Dc + d]; a5 += xv * W_re[3 * Dc + d];
    }
    for (int o = 32; o > 0; o >>= 1) {
        a0 += __shfl_down(a0, o, 64); a1 += __shfl_down(a1, o, 64);
        a2 += __shfl_down(a2, o, 64); a3 += __shfl_down(a3, o, 64);
        a4 += __shfl_down(a4, o, 64); a5 += __shfl_down(a5, o, 64);
    }
    if (lane == 0) {
        const float gl0 = a0, gl1 = a1;
        const float m = fmaxf(gl0, gl1);
        const float e0 = expf(gl0 - m), e1 = expf(gl1 - m);
        const float inv = 1.f / (e0 + e1);
        const float gp0 = e0 * inv, gp1 = e1 * inv;
        const int gidx = (gl1 > gl0) ? 1 : 0;
        const float gw = fmaxf(gp0, gp1);
        float el[4] = { a2, a3, a4, a5 };
        const float me = fmaxf(fmaxf(el[0], el[1]), fmaxf(el[2], el[3]));
        float ep[4]; float se = 0.f;
        for (int i = 0; i < 4; ++i) { ep[i] = expf(el[i] - me); se += ep[i]; }
        const float invs = 1.f / se;
        for (int i = 0; i < 4; ++i) ep[i] *= invs;
        int i0 = 0;
        for (int i = 1; i < 4; ++i) if (ep[i] > ep[i0]) i0 = i;
        int i1 = -1;
        for (int i = 0; i < 4; ++i) { if (i == i0) continue; if (i1 < 0 || ep[i] > ep[i1]) i1 = i; }
        const float w0 = ep[i0], w1 = ep[i1];
        const float sn = w0 + w1 + 1e-7f;
        const float f0 = gw * w0 / sn, f1 = gw * w1 / sn;
        const int ei0 = gidx * GSc + i0, ei1 = gidx * GSc + i1;
        eidx[t * 2] = ei0; eidx[t * 2 + 1] = ei1;
        fw[t * 2] = f0; fw[t * 2 + 1] = f1;
        dmsum[t] = f0 + f1;
        atomicAdd(&load[ei0], f0);
        atomicAdd(&load[ei1], f1);
        atomicAdd(&acc2[0], gl0 * gl0 + gl1 * gl1);
        atomicAdd(&acc2[1], el[0] * el[0] + el[1] * el[1] + el[2] * el[2] + el[3] * el[3]);
    }
}

__global__ void loss_k(const float* __restrict__ load, const float* __restrict__ acc2,
                       float* __restrict__ out_loss)
{
    if (threadIdx.x == 0 && blockIdx.x == 0) {
        float s = 0.f;
        for (int e = 0; e < Ec; ++e) s += load[e];
        const float tgt = s / (float)Ec;
        float v = 0.f;
        for (int e = 0; e < Ec; ++e) { const float d = load[e] - tgt; v += d * d; }
        v /= (float)Ec;
        const float l = v + acc2[0] / (float)(Nc * Gc) + acc2[1] / (float)(Nc * GSc);
        *out_loss = 0.001f * l;
    }
}

// ---------------- per-token expert adapter: h2[t] = sum_s fw * LN_e(A_exp[e] @ pre[t]) ----------------
__global__ __launch_bounds__(128) void expert_k(const float* __restrict__ pre,
                                                const float* __restrict__ A_exp,
                                                const float* __restrict__ ln_g_e,
                                                const float* __restrict__ ln_b_e,
                                                const int* __restrict__ eidx,
                                                const float* __restrict__ fw,
                                                float* __restrict__ h2)
{
    const int t = blockIdx.x;
    const int tid = threadIdx.x;
    __shared__ float ps[128];
    __shared__ float red[2];
    ps[tid] = pre[(long long)t * 128 + tid];
    __syncthreads();

    float acc = 0.f;
    #pragma unroll
    for (int slot = 0; slot < 2; ++slot) {
        const int e = eidx[t * 2 + slot];
        const float w = fw[t * 2 + slot];
        const float* Ae = A_exp + (long long)e * 128 * 128 + (long long)tid * 128;
        float h = 0.f;
        #pragma unroll 8
        for (int a = 0; a < 128; ++a) h += Ae[a] * ps[a];
        // block reduce (128 threads = 2 waves)
        float v = h;
        for (int o = 32; o > 0; o >>= 1) v += __shfl_down(v, o, 64);
        if ((tid & 63) == 0) red[tid >> 6] = v;
        __syncthreads();
        const float mu = (red[0] + red[1]) * (1.f / 128.f);
        __syncthreads();
        const float d = h - mu;
        v = d * d;
        for (int o = 32; o > 0; o >>= 1) v += __shfl_down(v, o, 64);
        if ((tid & 63) == 0) red[tid >> 6] = v;
        __syncthreads();
        const float var = (red[0] + red[1]) * (1.f / 128.f);
        __syncthreads();
        const float hn = d * rsqrtf(var + LN_EPSc) * ln_g_e[e * 128 + tid] + ln_b_e[e * 128 + tid];
        acc += w * hn;
    }
    h2[(long long)t * 128 + tid] = acc;
}

// =====================================================================
extern "C" void kernel_launch(void* const* d_in, const int* in_sizes, int n_in,
                              void* d_out, int out_size, void* d_ws, size_t ws_size,
                              hipStream_t stream)
{
    const float* x       = (const float*)d_in[0];
    const float* W_up    = (const float*)d_in[1];
    const float* W_gate  = (const float*)d_in[2];
    const float* W_down  = (const float*)d_in[3];
    const float* W_pre   = (const float*)d_in[4];
    const float* W_post  = (const float*)d_in[5];
    const float* ln_g    = (const float*)d_in[6];
    const float* ln_b    = (const float*)d_in[7];
    const float* W_aproj = (const float*)d_in[8];
    const float* A_exp   = (const float*)d_in[9];
    const float* ln_g_e  = (const float*)d_in[10];
    const float* ln_b_e  = (const float*)d_in[11];
    const float* W_eproj = (const float*)d_in[12];
    const float* W_oproj = (const float*)d_in[13];
    const float* W_rg    = (const float*)d_in[14];
    const float* W_re    = (const float*)d_in[15];

    float* out = (float*)d_out;

    // workspace layout (floats)
    float* ws = (float*)d_ws;
    float* hidden   = ws;                        // [4096,2048]
    float* tmpH     = hidden + (size_t)Nc * Hc;  // [4096,2048] : up / aw[2,2048,2048] / tmp2
    float* pre      = tmpH + (size_t)Nc * Hc;    // [4096,128]
    float* adapt_in = pre + (size_t)Nc * Ac;     // [4096,128]
    float* adapt_out= adapt_in + (size_t)Nc * Ac;// [4096,128]
    float* adaptb   = adapt_out + (size_t)Nc * Ac;// [4096,128]  post / adapt
    float* h2       = adaptb + (size_t)Nc * Ac;  // [4096,128]
    float* load     = h2 + (size_t)Nc * Ac;      // [8]
    float* acc2     = load + Ec;                 // [2]
    float* fw       = acc2 + 2;                  // [4096,2]
    float* dmsum    = fw + (size_t)Nc * Kc;      // [4096]
    int*   eidx     = (int*)(dmsum + Nc);        // [4096,2]

    // ---- router ----
    hipMemsetAsync(load, 0, (Ec + 2) * sizeof(float), stream);
    router_k<<<Nc, 64, 0, stream>>>(x, W_rg, W_re, load, acc2, eidx, fw, dmsum);
    loss_k<<<1, 64, 0, stream>>>(load, acc2, out + (size_t)Nc * Dc);

    // ---- pre / adapt_in ----
    gemm_k<1, 0><<<dim3(Ac / 64, Nc / 64, 1), 256, 0, stream>>>(x, W_pre, pre, Nc, Ac, Dc, 1.f, nullptr, 0, 0, 0);
    ln_k<<<Nc, 64, 0, stream>>>(pre, adapt_in, ln_g, ln_b);

    // ---- gate, up, hidden ----
    gemm_k<1, 0><<<dim3(Hc / 64, Nc / 64, 1), 256, 0, stream>>>(x, W_gate, hidden, Nc, Hc, Dc, 1.f, nullptr, 0, 0, 0);
    gemm_k<1, 0><<<dim3(Hc / 64, Nc / 64, 1), 256, 0, stream>>>(x, W_up, tmpH, Nc, Hc, Dc, 1.f, nullptr, 0, 0, 0);
    silu_mul_k<<<2048, 256, 0, stream>>>(hidden, tmpH, Nc * Hc);

    // ---- post / adapt_out ----
    gemm_k<1, 0><<<dim3(Ac / 64, Nc / 64, 1), 256, 0, stream>>>(hidden, W_post, adaptb, Nc, Ac, Hc, 1.f, nullptr, 0, 0, 0);
    ln_k<<<Nc, 64, 0, stream>>>(adaptb, adapt_out, ln_g, ln_b);

    // ---- aw = silu(clip(adapt_in @ adapt_out^T)) per batch, into tmpH ----
    gemm_k<1, 1><<<dim3(Sc / 64, Sc / 64, Bc), 256, 0, stream>>>(
        adapt_in, adapt_out, tmpH, Sc, Sc, Ac, 1.f, nullptr,
        (long long)Sc * Ac, (long long)Sc * Ac, (long long)Sc * Sc);

    // ---- adapt = aw @ adapt_in per batch, into adaptb ----
    gemm_k<0, 0><<<dim3(Ac / 64, Sc / 64, Bc), 256, 0, stream>>>(
        tmpH, adapt_in, adaptb, Sc, Ac, Sc, 1.f, nullptr,
        (long long)Sc * Sc, (long long)Sc * Ac, (long long)Sc * Ac);

    // ---- hidden += 0.1 * adapt @ W_aproj^T ----
    gemm_k<1, 2><<<dim3(Hc / 64, Nc / 64, 1), 256, 0, stream>>>(adaptb, W_aproj, hidden, Nc, Hc, Ac, 0.1f, nullptr, 0, 0, 0);

    // ---- d_out = dmsum[row] * (hidden @ W_down^T) ----
    gemm_k<1, 3><<<dim3(Dc / 64, Nc / 64, 1), 256, 0, stream>>>(hidden, W_down, out, Nc, Dc, Hc, 1.f, dmsum, 0, 0, 0);

    // ---- expert path ----
    expert_k<<<Nc, 128, 0, stream>>>(pre, A_exp, ln_g_e, ln_b_e, eidx, fw, h2);
    gemm_k<1, 0><<<dim3(Hc / 64, Nc / 64, 1), 256, 0, stream>>>(h2, W_eproj, tmpH, Nc, Hc, Ac, 1.f, nullptr, 0, 0, 0);
    gemm_k<1, 2><<<dim3(Dc / 64, Nc / 64, 1), 256, 0, stream>>>(tmpH, W_oproj, out, Nc, Dc, Hc, 0.1f, nullptr, 0, 0, 0);
}

// Round 2
// 607.774 us; speedup vs baseline: 2.6485x; 2.6485x over previous
//
#include <hip/hip_runtime.h>
#include <hip/hip_bf16.h>
#include <math.h>

static constexpr int Bc = 2;
static constexpr int Sc = 2048;
static constexpr int Dc = 1024;
static constexpr int Hc = 2048;
static constexpr int Ac = 128;
static constexpr int Ec = 8;
static constexpr int GSc = 4;
static constexpr int Gc = 2;
static constexpr int Nc = Bc * Sc;   // 4096 tokens
static constexpr float LN_EPSc = 1e-5f;

typedef __attribute__((ext_vector_type(8))) short bf16x8;
typedef __attribute__((ext_vector_type(4))) float f32x4;
typedef __attribute__((ext_vector_type(4))) unsigned short us4;
typedef __attribute__((ext_vector_type(8))) unsigned short us8;

__device__ __forceinline__ unsigned short f2b(float f) {
    union { float f; unsigned u; } v; v.f = f;
    return (unsigned short)((v.u + 0x7FFFu + ((v.u >> 16) & 1u)) >> 16);
}
__device__ __forceinline__ float b2f(unsigned short h) {
    union { unsigned u; float f; } v; v.u = (unsigned)h << 16; return v.f;
}

#define GLOAD16(g, l) __builtin_amdgcn_global_load_lds( \
    (const __attribute__((address_space(1))) void*)(g), \
    (__attribute__((address_space(3))) void*)(l), 16, 0, 0)

// ---------------- bf16 MFMA GEMM: C[M,N] = A[M,K] @ B[N,K]^T ----------------
// 128x128 tile, BK=32, 4 waves (2x2), each wave 64x64 = 4x4 frags of 16x16x32.
// EPI: 0=store f32, 1=store bf16, 2=silu(clip(v)) bf16, 3=Cbf16 += alpha*v,
//      4=f32 rowscale[row]*v, 5=f32 C += alpha*v
template<int EPI>
__global__ __launch_bounds__(256, 2) void mgemm(
    const unsigned short* __restrict__ Ag, const unsigned short* __restrict__ Bg,
    void* __restrict__ Cg, int N, int K, float alpha,
    const float* __restrict__ rowscale,
    long long sA, long long sB, long long sC)
{
    __shared__ unsigned short As[128 * 32];
    __shared__ unsigned short Bs[128 * 32];
    const unsigned short* A = Ag + (long long)blockIdx.z * sA;
    const unsigned short* B = Bg + (long long)blockIdx.z * sB;
    float* fC = (float*)Cg + (long long)blockIdx.z * sC;
    unsigned short* usC = (unsigned short*)Cg + (long long)blockIdx.z * sC;

    const int bm = blockIdx.y * 128, bn = blockIdx.x * 128;
    const int tid = threadIdx.x;
    const int w = tid >> 6, l = tid & 63;
    const int wm = (w >> 1) * 64, wn = (w & 1) * 64;
    const int fr = l & 15, g = l >> 4;

    const f32x4 zero = { 0.f, 0.f, 0.f, 0.f };
    f32x4 acc[4][4];
    #pragma unroll
    for (int i = 0; i < 4; ++i)
        #pragma unroll
        for (int j = 0; j < 4; ++j) acc[i][j] = zero;

    for (int k0 = 0; k0 < K; k0 += 32) {
        #pragma unroll
        for (int p = 0; p < 2; ++p) {
            const int c = p * 256 + tid;
            GLOAD16(A + (long long)(bm + (c >> 2)) * K + k0 + (c & 3) * 8, &As[c * 8]);
            GLOAD16(B + (long long)(bn + (c >> 2)) * K + k0 + (c & 3) * 8, &Bs[c * 8]);
        }
        __syncthreads();
        bf16x8 af[4], bfv[4];
        #pragma unroll
        for (int i = 0; i < 4; ++i) {
            af[i]  = *(const bf16x8*)&As[(wm + i * 16 + fr) * 32 + g * 8];
            bfv[i] = *(const bf16x8*)&Bs[(wn + i * 16 + fr) * 32 + g * 8];
        }
        #pragma unroll
        for (int i = 0; i < 4; ++i)
            #pragma unroll
            for (int j = 0; j < 4; ++j)
                acc[i][j] = __builtin_amdgcn_mfma_f32_16x16x32_bf16(af[i], bfv[j], acc[i][j], 0, 0, 0);
        __syncthreads();
    }

    #pragma unroll
    for (int mi = 0; mi < 4; ++mi) {
        #pragma unroll
        for (int ni = 0; ni < 4; ++ni) {
            #pragma unroll
            for (int jr = 0; jr < 4; ++jr) {
                const long long row = bm + wm + mi * 16 + g * 4 + jr;
                const long long col = bn + wn + ni * 16 + fr;
                const long long idx = row * (long long)N + col;
                float v = acc[mi][ni][jr];
                if (EPI == 0) {
                    fC[idx] = v;
                } else if (EPI == 1) {
                    usC[idx] = f2b(v);
                } else if (EPI == 2) {
                    v = fminf(fmaxf(v, -5.f), 5.f);
                    usC[idx] = f2b(v / (1.f + expf(-v)));
                } else if (EPI == 3) {
                    usC[idx] = f2b(b2f(usC[idx]) + alpha * v);
                } else if (EPI == 4) {
                    fC[idx] = rowscale[row] * v;
                } else {
                    fC[idx] += alpha * v;
                }
            }
        }
    }
}

// ---------------- fp32 -> bf16 casts (batched) ----------------
struct CastJobs {
    const float* src[9];
    unsigned short* dst[9];
    int n4[9];
};
__global__ __launch_bounds__(256) void cast_k(CastJobs jobs) {
    const int b = blockIdx.y;
    const float4* s = (const float4*)jobs.src[b];
    us4* d = (us4*)jobs.dst[b];
    const int n = jobs.n4[b];
    for (int i = blockIdx.x * 256 + threadIdx.x; i < n; i += gridDim.x * 256) {
        const float4 v = s[i];
        us4 o;
        o.x = f2b(v.x); o.y = f2b(v.y); o.z = f2b(v.z); o.w = f2b(v.w);
        d[i] = o;
    }
}

// ---------------- hidden = silu(gate) * up (bf16) ----------------
__global__ __launch_bounds__(256) void silu_mul_b(unsigned short* __restrict__ h,
                                                  const unsigned short* __restrict__ up, int n8)
{
    for (int i = blockIdx.x * 256 + threadIdx.x; i < n8; i += gridDim.x * 256) {
        us8 gv = ((const us8*)h)[i];
        us8 uv = ((const us8*)up)[i];
        us8 o;
        #pragma unroll
        for (int k = 0; k < 8; ++k) {
            const float gf = b2f(gv[k]), uf = b2f(uv[k]);
            o[k] = f2b(gf / (1.f + expf(-gf)) * uf);
        }
        ((us8*)h)[i] = o;
    }
}

// ---------------- LayerNorm over 128, one wave per row, bf16 out ----------------
__global__ __launch_bounds__(64) void ln_k(const float* __restrict__ in, unsigned short* __restrict__ out,
                                           const float* __restrict__ gg, const float* __restrict__ bb)
{
    const int row = blockIdx.x;
    const int lane = threadIdx.x;
    const float z0 = in[(long long)row * 128 + lane];
    const float z1 = in[(long long)row * 128 + 64 + lane];
    float s = z0 + z1;
    for (int o = 32; o > 0; o >>= 1) s += __shfl_down(s, o, 64);
    s = __shfl(s, 0, 64);
    const float mu = s * (1.f / 128.f);
    const float d0 = z0 - mu, d1 = z1 - mu;
    float v = d0 * d0 + d1 * d1;
    for (int o = 32; o > 0; o >>= 1) v += __shfl_down(v, o, 64);
    v = __shfl(v, 0, 64);
    const float r = rsqrtf(v * (1.f / 128.f) + LN_EPSc);
    out[(long long)row * 128 + lane] = f2b(d0 * r * gg[lane] + bb[lane]);
    out[(long long)row * 128 + 64 + lane] = f2b(d1 * r * gg[lane + 64] + bb[lane + 64]);
}

// ---------------- transpose per batch: [2048,128] -> [128,2048] bf16 ----------------
__global__ __launch_bounds__(256) void trans_k(const unsigned short* __restrict__ in,
                                               unsigned short* __restrict__ out)
{
    const int z = blockIdx.z;
    const int t0 = blockIdx.x * 64, a0 = blockIdx.y * 64;
    __shared__ unsigned short T[64][72];
    const unsigned short* ip = in + (long long)z * Sc * Ac;
    unsigned short* op = out + (long long)z * Ac * Sc;
    const int rr = threadIdx.x >> 4, cc = (threadIdx.x & 15) * 4;
    #pragma unroll
    for (int p = 0; p < 4; ++p) {
        const int row = p * 16 + rr;
        *(us4*)&T[row][cc] = *(const us4*)&ip[(long long)(t0 + row) * Ac + a0 + cc];
    }
    __syncthreads();
    #pragma unroll
    for (int p = 0; p < 4; ++p) {
        const int arow = p * 16 + rr;
        us4 o;
        o.x = T[cc + 0][arow]; o.y = T[cc + 1][arow];
        o.z = T[cc + 2][arow]; o.w = T[cc + 3][arow];
        *(us4*)&op[(long long)(a0 + arow) * Sc + t0 + cc] = o;
    }
}

// ---------------- router: one wave per token ----------------
__global__ __launch_bounds__(64) void router_k(const float* __restrict__ x,
                                               const float* __restrict__ W_rg,
                                               const float* __restrict__ W_re,
                                               float* __restrict__ load, float* __restrict__ acc2,
                                               int* __restrict__ eidx, float* __restrict__ fw,
                                               float* __restrict__ dmsum)
{
    const int t = blockIdx.x;
    const int lane = threadIdx.x;
    const float* xr = x + (long long)t * Dc;
    float a0 = 0, a1 = 0, a2 = 0, a3 = 0, a4 = 0, a5 = 0;
    for (int d = lane; d < Dc; d += 64) {
        const float xv = xr[d];
        a0 += xv * W_rg[d];          a1 += xv * W_rg[Dc + d];
        a2 += xv * W_re[d];          a3 += xv * W_re[Dc + d];
        a4 += xv * W_re[2 * Dc + d]; a5 += xv * W_re[3 * Dc + d];
    }
    for (int o = 32; o > 0; o >>= 1) {
        a0 += __shfl_down(a0, o, 64); a1 += __shfl_down(a1, o, 64);
        a2 += __shfl_down(a2, o, 64); a3 += __shfl_down(a3, o, 64);
        a4 += __shfl_down(a4, o, 64); a5 += __shfl_down(a5, o, 64);
    }
    if (lane == 0) {
        const float gl0 = a0, gl1 = a1;
        const float m = fmaxf(gl0, gl1);
        const float e0 = expf(gl0 - m), e1 = expf(gl1 - m);
        const float inv = 1.f / (e0 + e1);
        const float gp0 = e0 * inv, gp1 = e1 * inv;
        const int gidx = (gl1 > gl0) ? 1 : 0;
        const float gw = fmaxf(gp0, gp1);
        float el[4] = { a2, a3, a4, a5 };
        const float me = fmaxf(fmaxf(el[0], el[1]), fmaxf(el[2], el[3]));
        float ep[4]; float se = 0.f;
        for (int i = 0; i < 4; ++i) { ep[i] = expf(el[i] - me); se += ep[i]; }
        const float invs = 1.f / se;
        for (int i = 0; i < 4; ++i) ep[i] *= invs;
        int i0 = 0;
        for (int i = 1; i < 4; ++i) if (ep[i] > ep[i0]) i0 = i;
        int i1 = -1;
        for (int i = 0; i < 4; ++i) { if (i == i0) continue; if (i1 < 0 || ep[i] > ep[i1]) i1 = i; }
        const float w0 = ep[i0], w1 = ep[i1];
        const float sn = w0 + w1 + 1e-7f;
        const float f0 = gw * w0 / sn, f1 = gw * w1 / sn;
        const int ei0 = gidx * GSc + i0, ei1 = gidx * GSc + i1;
        eidx[t * 2] = ei0; eidx[t * 2 + 1] = ei1;
        fw[t * 2] = f0; fw[t * 2 + 1] = f1;
        dmsum[t] = f0 + f1;
        atomicAdd(&load[ei0], f0);
        atomicAdd(&load[ei1], f1);
        atomicAdd(&acc2[0], gl0 * gl0 + gl1 * gl1);
        atomicAdd(&acc2[1], el[0] * el[0] + el[1] * el[1] + el[2] * el[2] + el[3] * el[3]);
    }
}

__global__ void loss_k(const float* __restrict__ load, const float* __restrict__ acc2,
                       float* __restrict__ out_loss)
{
    if (threadIdx.x == 0 && blockIdx.x == 0) {
        float s = 0.f;
        for (int e = 0; e < Ec; ++e) s += load[e];
        const float tgt = s / (float)Ec;
        float v = 0.f;
        for (int e = 0; e < Ec; ++e) { const float d = load[e] - tgt; v += d * d; }
        v /= (float)Ec;
        const float l = v + acc2[0] / (float)(Nc * Gc) + acc2[1] / (float)(Nc * GSc);
        *out_loss = 0.001f * l;
    }
}

// ---------------- per-token expert adapter ----------------
__global__ __launch_bounds__(128) void expert_k(const float* __restrict__ pre,
                                                const float* __restrict__ A_exp,
                                                const float* __restrict__ ln_g_e,
                                                const float* __restrict__ ln_b_e,
                                                const int* __restrict__ eidx,
                                                const float* __restrict__ fw,
                                                unsigned short* __restrict__ h2)
{
    const int t = blockIdx.x;
    const int tid = threadIdx.x;
    __shared__ float ps[128];
    __shared__ float red[2];
    ps[tid] = pre[(long long)t * 128 + tid];
    __syncthreads();

    float acc = 0.f;
    #pragma unroll
    for (int slot = 0; slot < 2; ++slot) {
        const int e = eidx[t * 2 + slot];
        const float w = fw[t * 2 + slot];
        const float* Ae = A_exp + (long long)e * 128 * 128 + (long long)tid * 128;
        float h = 0.f;
        #pragma unroll 8
        for (int a = 0; a < 128; ++a) h += Ae[a] * ps[a];
        float v = h;
        for (int o = 32; o > 0; o >>= 1) v += __shfl_down(v, o, 64);
        if ((tid & 63) == 0) red[tid >> 6] = v;
        __syncthreads();
        const float mu = (red[0] + red[1]) * (1.f / 128.f);
        __syncthreads();
        const float d = h - mu;
        v = d * d;
        for (int o = 32; o > 0; o >>= 1) v += __shfl_down(v, o, 64);
        if ((tid & 63) == 0) red[tid >> 6] = v;
        __syncthreads();
        const float var = (red[0] + red[1]) * (1.f / 128.f);
        __syncthreads();
        const float hn = d * rsqrtf(var + LN_EPSc) * ln_g_e[e * 128 + tid] + ln_b_e[e * 128 + tid];
        acc += w * hn;
    }
    h2[(long long)t * 128 + tid] = f2b(acc);
}

// =====================================================================
extern "C" void kernel_launch(void* const* d_in, const int* in_sizes, int n_in,
                              void* d_out, int out_size, void* d_ws, size_t ws_size,
                              hipStream_t stream)
{
    const float* x       = (const float*)d_in[0];
    const float* W_up    = (const float*)d_in[1];
    const float* W_gate  = (const float*)d_in[2];
    const float* W_down  = (const float*)d_in[3];
    const float* W_pre   = (const float*)d_in[4];
    const float* W_post  = (const float*)d_in[5];
    const float* ln_g    = (const float*)d_in[6];
    const float* ln_b    = (const float*)d_in[7];
    const float* W_aproj = (const float*)d_in[8];
    const float* A_exp   = (const float*)d_in[9];
    const float* ln_g_e  = (const float*)d_in[10];
    const float* ln_b_e  = (const float*)d_in[11];
    const float* W_eproj = (const float*)d_in[12];
    const float* W_oproj = (const float*)d_in[13];
    const float* W_rg    = (const float*)d_in[14];
    const float* W_re    = (const float*)d_in[15];

    float* out = (float*)d_out;

    // ---- workspace carve ----
    char* p = (char*)d_ws;
    auto alloc = [&](size_t bytes) { void* r = (void*)p; p += (bytes + 255) & ~(size_t)255; return r; };
    float* pre      = (float*)alloc((size_t)Nc * Ac * 4);
    float* postbuf  = (float*)alloc((size_t)Nc * Ac * 4);
    float* load     = (float*)alloc(16 * 4);          // load[8] + acc2[2]
    float* acc2     = load + 8;
    float* fw       = (float*)alloc((size_t)Nc * 2 * 4);
    float* dmsum    = (float*)alloc((size_t)Nc * 4);
    int*   eidx     = (int*)alloc((size_t)Nc * 2 * 4);
    unsigned short* xb      = (unsigned short*)alloc((size_t)Nc * Dc * 2);
    unsigned short* Wg_b    = (unsigned short*)alloc((size_t)Hc * Dc * 2);
    unsigned short* Wu_b    = (unsigned short*)alloc((size_t)Hc * Dc * 2);
    unsigned short* Wd_b    = (unsigned short*)alloc((size_t)Dc * Hc * 2);
    unsigned short* Wop_b   = (unsigned short*)alloc((size_t)Dc * Hc * 2);
    unsigned short* Wpre_b  = (unsigned short*)alloc((size_t)Ac * Dc * 2);
    unsigned short* Wpost_b = (unsigned short*)alloc((size_t)Ac * Hc * 2);
    unsigned short* Wap_b   = (unsigned short*)alloc((size_t)Hc * Ac * 2);
    unsigned short* Wep_b   = (unsigned short*)alloc((size_t)Hc * Ac * 2);
    unsigned short* hidden  = (unsigned short*)alloc((size_t)Nc * Hc * 2);
    unsigned short* bufB    = (unsigned short*)alloc((size_t)Nc * Hc * 2);   // up -> aw -> eproj tmp
    unsigned short* adapt_in  = (unsigned short*)alloc((size_t)Nc * Ac * 2);
    unsigned short* adapt_inT = (unsigned short*)alloc((size_t)Nc * Ac * 2);
    unsigned short* adapt_out = (unsigned short*)alloc((size_t)Nc * Ac * 2);
    unsigned short* adaptb    = (unsigned short*)alloc((size_t)Nc * Ac * 2);
    unsigned short* h2        = (unsigned short*)alloc((size_t)Nc * Ac * 2);

    // ---- casts ----
    CastJobs jobs;
    jobs.src[0] = x;       jobs.dst[0] = xb;      jobs.n4[0] = Nc * Dc / 4;
    jobs.src[1] = W_gate;  jobs.dst[1] = Wg_b;    jobs.n4[1] = Hc * Dc / 4;
    jobs.src[2] = W_up;    jobs.dst[2] = Wu_b;    jobs.n4[2] = Hc * Dc / 4;
    jobs.src[3] = W_down;  jobs.dst[3] = Wd_b;    jobs.n4[3] = Dc * Hc / 4;
    jobs.src[4] = W_oproj; jobs.dst[4] = Wop_b;   jobs.n4[4] = Dc * Hc / 4;
    jobs.src[5] = W_pre;   jobs.dst[5] = Wpre_b;  jobs.n4[5] = Ac * Dc / 4;
    jobs.src[6] = W_post;  jobs.dst[6] = Wpost_b; jobs.n4[6] = Ac * Hc / 4;
    jobs.src[7] = W_aproj; jobs.dst[7] = Wap_b;   jobs.n4[7] = Hc * Ac / 4;
    jobs.src[8] = W_eproj; jobs.dst[8] = Wep_b;   jobs.n4[8] = Hc * Ac / 4;
    cast_k<<<dim3(256, 9), 256, 0, stream>>>(jobs);

    // ---- router ----
    hipMemsetAsync(load, 0, 16 * 4, stream);
    router_k<<<Nc, 64, 0, stream>>>(x, W_rg, W_re, load, acc2, eidx, fw, dmsum);
    loss_k<<<1, 64, 0, stream>>>(load, acc2, out + (size_t)Nc * Dc);

    // ---- pre / adapt_in ----
    mgemm<0><<<dim3(1, 32), 256, 0, stream>>>(xb, Wpre_b, pre, Ac, Dc, 0.f, nullptr, 0, 0, 0);
    ln_k<<<Nc, 64, 0, stream>>>(pre, adapt_in, ln_g, ln_b);
    trans_k<<<dim3(Sc / 64, Ac / 64, Bc), 256, 0, stream>>>(adapt_in, adapt_inT);

    // ---- gate, up, hidden ----
    mgemm<1><<<dim3(16, 32), 256, 0, stream>>>(xb, Wg_b, hidden, Hc, Dc, 0.f, nullptr, 0, 0, 0);
    mgemm<1><<<dim3(16, 32), 256, 0, stream>>>(xb, Wu_b, bufB, Hc, Dc, 0.f, nullptr, 0, 0, 0);
    silu_mul_b<<<1024, 256, 0, stream>>>(hidden, bufB, Nc * Hc / 8);

    // ---- post / adapt_out ----
    mgemm<0><<<dim3(1, 32), 256, 0, stream>>>(hidden, Wpost_b, postbuf, Ac, Hc, 0.f, nullptr, 0, 0, 0);
    ln_k<<<Nc, 64, 0, stream>>>(postbuf, adapt_out, ln_g, ln_b);

    // ---- aw = silu(clip(adapt_in @ adapt_out^T)) per batch ----
    mgemm<2><<<dim3(16, 16, Bc), 256, 0, stream>>>(adapt_in, adapt_out, bufB, Sc, Ac, 0.f, nullptr,
        (long long)Sc * Ac, (long long)Sc * Ac, (long long)Sc * Sc);

    // ---- adapt = aw @ adapt_in  (B^T form via adapt_inT) ----
    mgemm<1><<<dim3(1, 16, Bc), 256, 0, stream>>>(bufB, adapt_inT, adaptb, Ac, Sc, 0.f, nullptr,
        (long long)Sc * Sc, (long long)Ac * Sc, (long long)Sc * Ac);

    // ---- hidden += 0.1 * adapt @ W_aproj^T ----
    mgemm<3><<<dim3(16, 32), 256, 0, stream>>>(adaptb, Wap_b, hidden, Hc, Ac, 0.1f, nullptr, 0, 0, 0);

    // ---- out = dmsum[row] * (hidden @ W_down^T) ----
    mgemm<4><<<dim3(8, 32), 256, 0, stream>>>(hidden, Wd_b, out, Dc, Hc, 0.f, dmsum, 0, 0, 0);

    // ---- expert path ----
    expert_k<<<Nc, 128, 0, stream>>>(pre, A_exp, ln_g_e, ln_b_e, eidx, fw, h2);
    mgemm<1><<<dim3(16, 32), 256, 0, stream>>>(h2, Wep_b, bufB, Hc, Ac, 0.f, nullptr, 0, 0, 0);
    mgemm<5><<<dim3(8, 32), 256, 0, stream>>>(bufB, Wop_b, out, Dc, Hc, 0.1f, nullptr, 0, 0, 0);
}

// Round 3
// 406.358 us; speedup vs baseline: 3.9613x; 1.4957x over previous
//
#include <hip/hip_runtime.h>
#include <hip/hip_bf16.h>
#include <math.h>

static constexpr int Bc = 2;
static constexpr int Sc = 2048;
static constexpr int Dc = 1024;
static constexpr int Hc = 2048;
static constexpr int Ac = 128;
static constexpr int Ec = 8;
static constexpr int GSc = 4;
static constexpr int Gc = 2;
static constexpr int Nc = Bc * Sc;   // 4096 tokens
static constexpr float LN_EPSc = 1e-5f;
static constexpr int RBLK = 512;     // router blocks

typedef __attribute__((ext_vector_type(8))) short bf16x8;
typedef __attribute__((ext_vector_type(4))) float f32x4;
typedef __attribute__((ext_vector_type(4))) unsigned short us4;
typedef __attribute__((ext_vector_type(8))) unsigned short us8;

__device__ __forceinline__ unsigned short f2b(float f) {
    union { float f; unsigned u; } v; v.f = f;
    return (unsigned short)((v.u + 0x7FFFu + ((v.u >> 16) & 1u)) >> 16);
}
__device__ __forceinline__ float b2f(unsigned short h) {
    union { unsigned u; float f; } v; v.u = (unsigned)h << 16; return v.f;
}

#define GLOAD16(g, l) __builtin_amdgcn_global_load_lds( \
    (const __attribute__((address_space(1))) void*)(g), \
    (__attribute__((address_space(3))) void*)(l), 16, 0, 0)

// ---------------- bf16 MFMA GEMM: C[M,N] = A[M,K] @ B[N,K]^T ----------------
// 128x128 tile, BK=32, 4 waves (2x2), each wave 64x64 = 4x4 frags of 16x16x32.
// EPI: 0=store f32, 1=store bf16, 2=silu(clip(v)) bf16, 3=Cbf16 += alpha*v,
//      4=f32 rowscale[row]*v, 5=f32 C += alpha*v
template<int EPI>
__global__ __launch_bounds__(256, 2) void mgemm(
    const unsigned short* __restrict__ Ag, const unsigned short* __restrict__ Bg,
    void* __restrict__ Cg, int N, int K, float alpha,
    const float* __restrict__ rowscale,
    long long sA, long long sB, long long sC)
{
    __shared__ unsigned short As[128 * 32];
    __shared__ unsigned short Bs[128 * 32];
    const unsigned short* A = Ag + (long long)blockIdx.z * sA;
    const unsigned short* B = Bg + (long long)blockIdx.z * sB;
    float* fC = (float*)Cg + (long long)blockIdx.z * sC;
    unsigned short* usC = (unsigned short*)Cg + (long long)blockIdx.z * sC;

    const int bm = blockIdx.y * 128, bn = blockIdx.x * 128;
    const int tid = threadIdx.x;
    const int w = tid >> 6, l = tid & 63;
    const int wm = (w >> 1) * 64, wn = (w & 1) * 64;
    const int fr = l & 15, g = l >> 4;

    const f32x4 zero = { 0.f, 0.f, 0.f, 0.f };
    f32x4 acc[4][4];
    #pragma unroll
    for (int i = 0; i < 4; ++i)
        #pragma unroll
        for (int j = 0; j < 4; ++j) acc[i][j] = zero;

    for (int k0 = 0; k0 < K; k0 += 32) {
        #pragma unroll
        for (int p = 0; p < 2; ++p) {
            const int c = p * 256 + tid;
            GLOAD16(A + (long long)(bm + (c >> 2)) * K + k0 + (c & 3) * 8, &As[c * 8]);
            GLOAD16(B + (long long)(bn + (c >> 2)) * K + k0 + (c & 3) * 8, &Bs[c * 8]);
        }
        __syncthreads();
        bf16x8 af[4], bfv[4];
        #pragma unroll
        for (int i = 0; i < 4; ++i) {
            af[i]  = *(const bf16x8*)&As[(wm + i * 16 + fr) * 32 + g * 8];
            bfv[i] = *(const bf16x8*)&Bs[(wn + i * 16 + fr) * 32 + g * 8];
        }
        #pragma unroll
        for (int i = 0; i < 4; ++i)
            #pragma unroll
            for (int j = 0; j < 4; ++j)
                acc[i][j] = __builtin_amdgcn_mfma_f32_16x16x32_bf16(af[i], bfv[j], acc[i][j], 0, 0, 0);
        __syncthreads();
    }

    #pragma unroll
    for (int mi = 0; mi < 4; ++mi) {
        #pragma unroll
        for (int ni = 0; ni < 4; ++ni) {
            #pragma unroll
            for (int jr = 0; jr < 4; ++jr) {
                const long long row = bm + wm + mi * 16 + g * 4 + jr;
                const long long col = bn + wn + ni * 16 + fr;
                const long long idx = row * (long long)N + col;
                float v = acc[mi][ni][jr];
                if (EPI == 0) {
                    fC[idx] = v;
                } else if (EPI == 1) {
                    usC[idx] = f2b(v);
                } else if (EPI == 2) {
                    v = fminf(fmaxf(v, -5.f), 5.f);
                    usC[idx] = f2b(v / (1.f + expf(-v)));
                } else if (EPI == 3) {
                    usC[idx] = f2b(b2f(usC[idx]) + alpha * v);
                } else if (EPI == 4) {
                    fC[idx] = rowscale[row] * v;
                } else {
                    fC[idx] += alpha * v;
                }
            }
        }
    }
}

// ---------------- fp32 -> bf16 casts (batched) ----------------
struct CastJobs {
    const float* src[9];
    unsigned short* dst[9];
    int n4[9];
};
__global__ __launch_bounds__(256) void cast_k(CastJobs jobs) {
    const int b = blockIdx.y;
    const float4* s = (const float4*)jobs.src[b];
    us4* d = (us4*)jobs.dst[b];
    const int n = jobs.n4[b];
    for (int i = blockIdx.x * 256 + threadIdx.x; i < n; i += gridDim.x * 256) {
        const float4 v = s[i];
        us4 o;
        o.x = f2b(v.x); o.y = f2b(v.y); o.z = f2b(v.z); o.w = f2b(v.w);
        d[i] = o;
    }
}

// ---------------- hidden = silu(gate) * up (bf16) ----------------
__global__ __launch_bounds__(256) void silu_mul_b(unsigned short* __restrict__ h,
                                                  const unsigned short* __restrict__ up, int n8)
{
    for (int i = blockIdx.x * 256 + threadIdx.x; i < n8; i += gridDim.x * 256) {
        us8 gv = ((const us8*)h)[i];
        us8 uv = ((const us8*)up)[i];
        us8 o;
        #pragma unroll
        for (int k = 0; k < 8; ++k) {
            const float gf = b2f(gv[k]), uf = b2f(uv[k]);
            o[k] = f2b(gf / (1.f + expf(-gf)) * uf);
        }
        ((us8*)h)[i] = o;
    }
}

// ---------------- LayerNorm over 128, one wave per row, bf16 out ----------------
__global__ __launch_bounds__(64) void ln_k(const float* __restrict__ in, unsigned short* __restrict__ out,
                                           const float* __restrict__ gg, const float* __restrict__ bb)
{
    const int row = blockIdx.x;
    const int lane = threadIdx.x;
    const float z0 = in[(long long)row * 128 + lane];
    const float z1 = in[(long long)row * 128 + 64 + lane];
    float s = z0 + z1;
    for (int o = 32; o > 0; o >>= 1) s += __shfl_down(s, o, 64);
    s = __shfl(s, 0, 64);
    const float mu = s * (1.f / 128.f);
    const float d0 = z0 - mu, d1 = z1 - mu;
    float v = d0 * d0 + d1 * d1;
    for (int o = 32; o > 0; o >>= 1) v += __shfl_down(v, o, 64);
    v = __shfl(v, 0, 64);
    const float r = rsqrtf(v * (1.f / 128.f) + LN_EPSc);
    out[(long long)row * 128 + lane] = f2b(d0 * r * gg[lane] + bb[lane]);
    out[(long long)row * 128 + 64 + lane] = f2b(d1 * r * gg[lane + 64] + bb[lane + 64]);
}

// ---------------- transpose per batch: [2048,128] -> [128,2048] bf16 ----------------
__global__ __launch_bounds__(256) void trans_k(const unsigned short* __restrict__ in,
                                               unsigned short* __restrict__ out)
{
    const int z = blockIdx.z;
    const int t0 = blockIdx.x * 64, a0 = blockIdx.y * 64;
    __shared__ unsigned short T[64][72];
    const unsigned short* ip = in + (long long)z * Sc * Ac;
    unsigned short* op = out + (long long)z * Ac * Sc;
    const int rr = threadIdx.x >> 4, cc = (threadIdx.x & 15) * 4;
    #pragma unroll
    for (int p = 0; p < 4; ++p) {
        const int row = p * 16 + rr;
        *(us4*)&T[row][cc] = *(const us4*)&ip[(long long)(t0 + row) * Ac + a0 + cc];
    }
    __syncthreads();
    #pragma unroll
    for (int p = 0; p < 4; ++p) {
        const int arow = p * 16 + rr;
        us4 o;
        o.x = T[cc + 0][arow]; o.y = T[cc + 1][arow];
        o.z = T[cc + 2][arow]; o.w = T[cc + 3][arow];
        *(us4*)&op[(long long)(a0 + arow) * Sc + t0 + cc] = o;
    }
}

// ---------------- router: 512 blocks x 256 threads, NO global atomics ----------------
// Each wave handles 2 tokens; per-block partials [load8, sum(gl^2), sum(el^2)] -> rpart.
__global__ __launch_bounds__(256) void router_k(const float* __restrict__ x,
                                                const float* __restrict__ W_rg,
                                                const float* __restrict__ W_re,
                                                int* __restrict__ eidx, float* __restrict__ fw,
                                                float* __restrict__ dmsum,
                                                float* __restrict__ rpart)
{
    const int wv = threadIdx.x >> 6;
    const int lane = threadIdx.x & 63;
    float load8[8] = {0.f, 0.f, 0.f, 0.f, 0.f, 0.f, 0.f, 0.f};
    float sqg = 0.f, sqe = 0.f;

    #pragma unroll
    for (int it = 0; it < 2; ++it) {
        const int t = blockIdx.x * 8 + wv * 2 + it;
        const float* xr = x + (long long)t * Dc;
        float a0 = 0, a1 = 0, a2 = 0, a3 = 0, a4 = 0, a5 = 0;
        #pragma unroll
        for (int j = 0; j < 16; ++j) {
            const int d = lane + 64 * j;
            const float xv = xr[d];
            a0 += xv * W_rg[d];          a1 += xv * W_rg[Dc + d];
            a2 += xv * W_re[d];          a3 += xv * W_re[Dc + d];
            a4 += xv * W_re[2 * Dc + d]; a5 += xv * W_re[3 * Dc + d];
        }
        #pragma unroll
        for (int o = 32; o > 0; o >>= 1) {
            a0 += __shfl_xor(a0, o, 64); a1 += __shfl_xor(a1, o, 64);
            a2 += __shfl_xor(a2, o, 64); a3 += __shfl_xor(a3, o, 64);
            a4 += __shfl_xor(a4, o, 64); a5 += __shfl_xor(a5, o, 64);
        }
        if (lane == 0) {
            const float gl0 = a0, gl1 = a1;
            const float m = fmaxf(gl0, gl1);
            const float e0 = expf(gl0 - m), e1 = expf(gl1 - m);
            const float inv = 1.f / (e0 + e1);
            const float gp0 = e0 * inv, gp1 = e1 * inv;
            const int gidx = (gl1 > gl0) ? 1 : 0;
            const float gw = fmaxf(gp0, gp1);
            float el[4] = { a2, a3, a4, a5 };
            const float me = fmaxf(fmaxf(el[0], el[1]), fmaxf(el[2], el[3]));
            float ep[4]; float se = 0.f;
            #pragma unroll
            for (int i = 0; i < 4; ++i) { ep[i] = expf(el[i] - me); se += ep[i]; }
            const float invs = 1.f / se;
            #pragma unroll
            for (int i = 0; i < 4; ++i) ep[i] *= invs;
            int i0 = 0;
            #pragma unroll
            for (int i = 1; i < 4; ++i) if (ep[i] > ep[i0]) i0 = i;
            int i1 = -1;
            #pragma unroll
            for (int i = 0; i < 4; ++i) { if (i == i0) continue; if (i1 < 0 || ep[i] > ep[i1]) i1 = i; }
            const float w0 = ep[i0], w1 = ep[i1];
            const float sn = w0 + w1 + 1e-7f;
            const float f0 = gw * w0 / sn, f1 = gw * w1 / sn;
            const int ei0 = gidx * GSc + i0, ei1 = gidx * GSc + i1;
            eidx[t * 2] = ei0; eidx[t * 2 + 1] = ei1;
            fw[t * 2] = f0; fw[t * 2 + 1] = f1;
            dmsum[t] = f0 + f1;
            #pragma unroll
            for (int e = 0; e < 8; ++e)
                load8[e] += ((e == ei0) ? f0 : 0.f) + ((e == ei1) ? f1 : 0.f);
            sqg += gl0 * gl0 + gl1 * gl1;
            sqe += el[0] * el[0] + el[1] * el[1] + el[2] * el[2] + el[3] * el[3];
        }
    }
    __shared__ float sh[4][10];
    if (lane == 0) {
        #pragma unroll
        for (int e = 0; e < 8; ++e) sh[wv][e] = load8[e];
        sh[wv][8] = sqg; sh[wv][9] = sqe;
    }
    __syncthreads();
    if (threadIdx.x < 10) {
        rpart[blockIdx.x * 10 + threadIdx.x] =
            sh[0][threadIdx.x] + sh[1][threadIdx.x] + sh[2][threadIdx.x] + sh[3][threadIdx.x];
    }
}

// ---------------- loss reduce over RBLK partial rows ----------------
__global__ __launch_bounds__(512) void loss_k(const float* __restrict__ rpart,
                                              float* __restrict__ out_loss)
{
    const int tid = threadIdx.x;
    const int lane = tid & 63, wv = tid >> 6;
    float v[10];
    #pragma unroll
    for (int c = 0; c < 10; ++c) v[c] = rpart[tid * 10 + c];
    #pragma unroll
    for (int o = 32; o > 0; o >>= 1)
        #pragma unroll
        for (int c = 0; c < 10; ++c) v[c] += __shfl_xor(v[c], o, 64);
    __shared__ float sh[8][10];
    if (lane == 0) {
        #pragma unroll
        for (int c = 0; c < 10; ++c) sh[wv][c] = v[c];
    }
    __syncthreads();
    if (tid == 0) {
        float load[8]; float sqg = 0.f, sqe = 0.f;
        #pragma unroll
        for (int e = 0; e < 8; ++e) load[e] = 0.f;
        for (int wvi = 0; wvi < 8; ++wvi) {
            #pragma unroll
            for (int e = 0; e < 8; ++e) load[e] += sh[wvi][e];
            sqg += sh[wvi][8]; sqe += sh[wvi][9];
        }
        float s = 0.f;
        for (int e = 0; e < Ec; ++e) s += load[e];
        const float tgt = s / (float)Ec;
        float var = 0.f;
        for (int e = 0; e < Ec; ++e) { const float d = load[e] - tgt; var += d * d; }
        var /= (float)Ec;
        const float l = var + sqg / (float)(Nc * Gc) + sqe / (float)(Nc * GSc);
        *out_loss = 0.001f * l;
    }
}

// ---------------- per-token expert adapter ----------------
__global__ __launch_bounds__(128) void expert_k(const float* __restrict__ pre,
                                                const float* __restrict__ A_exp,
                                                const float* __restrict__ ln_g_e,
                                                const float* __restrict__ ln_b_e,
                                                const int* __restrict__ eidx,
                                                const float* __restrict__ fw,
                                                unsigned short* __restrict__ h2)
{
    const int t = blockIdx.x;
    const int tid = threadIdx.x;
    __shared__ float ps[128];
    __shared__ float red[2];
    ps[tid] = pre[(long long)t * 128 + tid];
    __syncthreads();

    float acc = 0.f;
    #pragma unroll
    for (int slot = 0; slot < 2; ++slot) {
        const int e = eidx[t * 2 + slot];
        const float w = fw[t * 2 + slot];
        const float* Ae = A_exp + (long long)e * 128 * 128 + (long long)tid * 128;
        float h = 0.f;
        #pragma unroll 8
        for (int a = 0; a < 128; ++a) h += Ae[a] * ps[a];
        float v = h;
        for (int o = 32; o > 0; o >>= 1) v += __shfl_down(v, o, 64);
        if ((tid & 63) == 0) red[tid >> 6] = v;
        __syncthreads();
        const float mu = (red[0] + red[1]) * (1.f / 128.f);
        __syncthreads();
        const float d = h - mu;
        v = d * d;
        for (int o = 32; o > 0; o >>= 1) v += __shfl_down(v, o, 64);
        if ((tid & 63) == 0) red[tid >> 6] = v;
        __syncthreads();
        const float var = (red[0] + red[1]) * (1.f / 128.f);
        __syncthreads();
        const float hn = d * rsqrtf(var + LN_EPSc) * ln_g_e[e * 128 + tid] + ln_b_e[e * 128 + tid];
        acc += w * hn;
    }
    h2[(long long)t * 128 + tid] = f2b(acc);
}

// =====================================================================
extern "C" void kernel_launch(void* const* d_in, const int* in_sizes, int n_in,
                              void* d_out, int out_size, void* d_ws, size_t ws_size,
                              hipStream_t stream)
{
    const float* x       = (const float*)d_in[0];
    const float* W_up    = (const float*)d_in[1];
    const float* W_gate  = (const float*)d_in[2];
    const float* W_down  = (const float*)d_in[3];
    const float* W_pre   = (const float*)d_in[4];
    const float* W_post  = (const float*)d_in[5];
    const float* ln_g    = (const float*)d_in[6];
    const float* ln_b    = (const float*)d_in[7];
    const float* W_aproj = (const float*)d_in[8];
    const float* A_exp   = (const float*)d_in[9];
    const float* ln_g_e  = (const float*)d_in[10];
    const float* ln_b_e  = (const float*)d_in[11];
    const float* W_eproj = (const float*)d_in[12];
    const float* W_oproj = (const float*)d_in[13];
    const float* W_rg    = (const float*)d_in[14];
    const float* W_re    = (const float*)d_in[15];

    float* out = (float*)d_out;

    // ---- workspace carve ----
    char* p = (char*)d_ws;
    auto alloc = [&](size_t bytes) { void* r = (void*)p; p += (bytes + 255) & ~(size_t)255; return r; };
    float* pre      = (float*)alloc((size_t)Nc * Ac * 4);
    float* postbuf  = (float*)alloc((size_t)Nc * Ac * 4);
    float* rpart    = (float*)alloc((size_t)RBLK * 10 * 4);
    float* fw       = (float*)alloc((size_t)Nc * 2 * 4);
    float* dmsum    = (float*)alloc((size_t)Nc * 4);
    int*   eidx     = (int*)alloc((size_t)Nc * 2 * 4);
    unsigned short* xb      = (unsigned short*)alloc((size_t)Nc * Dc * 2);
    unsigned short* Wg_b    = (unsigned short*)alloc((size_t)Hc * Dc * 2);
    unsigned short* Wu_b    = (unsigned short*)alloc((size_t)Hc * Dc * 2);
    unsigned short* Wd_b    = (unsigned short*)alloc((size_t)Dc * Hc * 2);
    unsigned short* Wop_b   = (unsigned short*)alloc((size_t)Dc * Hc * 2);
    unsigned short* Wpre_b  = (unsigned short*)alloc((size_t)Ac * Dc * 2);
    unsigned short* Wpost_b = (unsigned short*)alloc((size_t)Ac * Hc * 2);
    unsigned short* Wap_b   = (unsigned short*)alloc((size_t)Hc * Ac * 2);
    unsigned short* Wep_b   = (unsigned short*)alloc((size_t)Hc * Ac * 2);
    unsigned short* hidden  = (unsigned short*)alloc((size_t)Nc * Hc * 2);
    unsigned short* bufB    = (unsigned short*)alloc((size_t)Nc * Hc * 2);   // up -> aw -> eproj tmp
    unsigned short* adapt_in  = (unsigned short*)alloc((size_t)Nc * Ac * 2);
    unsigned short* adapt_inT = (unsigned short*)alloc((size_t)Nc * Ac * 2);
    unsigned short* adapt_out = (unsigned short*)alloc((size_t)Nc * Ac * 2);
    unsigned short* adaptb    = (unsigned short*)alloc((size_t)Nc * Ac * 2);
    unsigned short* h2        = (unsigned short*)alloc((size_t)Nc * Ac * 2);

    // ---- casts ----
    CastJobs jobs;
    jobs.src[0] = x;       jobs.dst[0] = xb;      jobs.n4[0] = Nc * Dc / 4;
    jobs.src[1] = W_gate;  jobs.dst[1] = Wg_b;    jobs.n4[1] = Hc * Dc / 4;
    jobs.src[2] = W_up;    jobs.dst[2] = Wu_b;    jobs.n4[2] = Hc * Dc / 4;
    jobs.src[3] = W_down;  jobs.dst[3] = Wd_b;    jobs.n4[3] = Dc * Hc / 4;
    jobs.src[4] = W_oproj; jobs.dst[4] = Wop_b;   jobs.n4[4] = Dc * Hc / 4;
    jobs.src[5] = W_pre;   jobs.dst[5] = Wpre_b;  jobs.n4[5] = Ac * Dc / 4;
    jobs.src[6] = W_post;  jobs.dst[6] = Wpost_b; jobs.n4[6] = Ac * Hc / 4;
    jobs.src[7] = W_aproj; jobs.dst[7] = Wap_b;   jobs.n4[7] = Hc * Ac / 4;
    jobs.src[8] = W_eproj; jobs.dst[8] = Wep_b;   jobs.n4[8] = Hc * Ac / 4;
    cast_k<<<dim3(256, 9), 256, 0, stream>>>(jobs);

    // ---- router (atomic-free) ----
    router_k<<<RBLK, 256, 0, stream>>>(x, W_rg, W_re, eidx, fw, dmsum, rpart);
    loss_k<<<1, 512, 0, stream>>>(rpart, out + (size_t)Nc * Dc);

    // ---- pre / adapt_in ----
    mgemm<0><<<dim3(1, 32), 256, 0, stream>>>(xb, Wpre_b, pre, Ac, Dc, 0.f, nullptr, 0, 0, 0);
    ln_k<<<Nc, 64, 0, stream>>>(pre, adapt_in, ln_g, ln_b);
    trans_k<<<dim3(Sc / 64, Ac / 64, Bc), 256, 0, stream>>>(adapt_in, adapt_inT);

    // ---- gate, up, hidden ----
    mgemm<1><<<dim3(16, 32), 256, 0, stream>>>(xb, Wg_b, hidden, Hc, Dc, 0.f, nullptr, 0, 0, 0);
    mgemm<1><<<dim3(16, 32), 256, 0, stream>>>(xb, Wu_b, bufB, Hc, Dc, 0.f, nullptr, 0, 0, 0);
    silu_mul_b<<<1024, 256, 0, stream>>>(hidden, bufB, Nc * Hc / 8);

    // ---- post / adapt_out ----
    mgemm<0><<<dim3(1, 32), 256, 0, stream>>>(hidden, Wpost_b, postbuf, Ac, Hc, 0.f, nullptr, 0, 0, 0);
    ln_k<<<Nc, 64, 0, stream>>>(postbuf, adapt_out, ln_g, ln_b);

    // ---- aw = silu(clip(adapt_in @ adapt_out^T)) per batch ----
    mgemm<2><<<dim3(16, 16, Bc), 256, 0, stream>>>(adapt_in, adapt_out, bufB, Sc, Ac, 0.f, nullptr,
        (long long)Sc * Ac, (long long)Sc * Ac, (long long)Sc * Sc);

    // ---- adapt = aw @ adapt_in  (B^T form via adapt_inT) ----
    mgemm<1><<<dim3(1, 16, Bc), 256, 0, stream>>>(bufB, adapt_inT, adaptb, Ac, Sc, 0.f, nullptr,
        (long long)Sc * Sc, (long long)Ac * Sc, (long long)Sc * Ac);

    // ---- hidden += 0.1 * adapt @ W_aproj^T ----
    mgemm<3><<<dim3(16, 32), 256, 0, stream>>>(adaptb, Wap_b, hidden, Hc, Ac, 0.1f, nullptr, 0, 0, 0);

    // ---- out = dmsum[row] * (hidden @ W_down^T) ----
    mgemm<4><<<dim3(8, 32), 256, 0, stream>>>(hidden, Wd_b, out, Dc, Hc, 0.f, dmsum, 0, 0, 0);

    // ---- expert path ----
    expert_k<<<Nc, 128, 0, stream>>>(pre, A_exp, ln_g_e, ln_b_e, eidx, fw, h2);
    mgemm<1><<<dim3(16, 32), 256, 0, stream>>>(h2, Wep_b, bufB, Hc, Ac, 0.f, nullptr, 0, 0, 0);
    mgemm<5><<<dim3(8, 32), 256, 0, stream>>>(bufB, Wop_b, out, Dc, Hc, 0.1f, nullptr, 0, 0, 0);
}

// Round 4
// 350.039 us; speedup vs baseline: 4.5986x; 1.1609x over previous
//
#include <hip/hip_runtime.h>
#include <hip/hip_bf16.h>
#include <math.h>

static constexpr int Bc = 2;
static constexpr int Sc = 2048;
static constexpr int Dc = 1024;
static constexpr int Hc = 2048;
static constexpr int Ac = 128;
static constexpr int Ec = 8;
static constexpr int GSc = 4;
static constexpr int Gc = 2;
static constexpr int Nc = Bc * Sc;   // 4096 tokens
static constexpr float LN_EPSc = 1e-5f;
static constexpr int RBLK = 512;     // router blocks

typedef __attribute__((ext_vector_type(8))) short bf16x8;
typedef __attribute__((ext_vector_type(4))) float f32x4;
typedef __attribute__((ext_vector_type(4))) unsigned short us4;
typedef __attribute__((ext_vector_type(8))) unsigned short us8;

__device__ __forceinline__ unsigned short f2b(float f) {
    union { float f; unsigned u; } v; v.f = f;
    return (unsigned short)((v.u + 0x7FFFu + ((v.u >> 16) & 1u)) >> 16);
}
__device__ __forceinline__ float b2f(unsigned short h) {
    union { unsigned u; float f; } v; v.u = (unsigned)h << 16; return v.f;
}

#define GLOAD16(g, l) __builtin_amdgcn_global_load_lds( \
    (const __attribute__((address_space(1))) void*)(g), \
    (__attribute__((address_space(3))) void*)(l), 16, 0, 0)

// ---------------- bf16 MFMA GEMM: C[M,N] = A[M,K] @ B[N,K]^T ----------------
// 128x128 tile, BK=32, 4 waves (2x2), each wave 64x64 = 4x4 frags of 16x16x32.
// EPI: 0=store f32, 1=store bf16, 2=silu(clip(v)) bf16, 3=Cbf16 += alpha*v,
//      4=f32 rowscale[row]*v, 5=f32 C += alpha*v,
//      6=bf16 store silu(gate[idx])*v (aux = gate bf16), 7=f32 store + bf16 store (aux)
template<int EPI>
__global__ __launch_bounds__(256, 2) void mgemm(
    const unsigned short* __restrict__ Ag, const unsigned short* __restrict__ Bg,
    void* __restrict__ Cg, int N, int K, float alpha,
    const float* __restrict__ aux,
    long long sA, long long sB, long long sC)
{
    __shared__ unsigned short As[128 * 32];
    __shared__ unsigned short Bs[128 * 32];
    const unsigned short* A = Ag + (long long)blockIdx.z * sA;
    const unsigned short* B = Bg + (long long)blockIdx.z * sB;
    float* fC = (float*)Cg + (long long)blockIdx.z * sC;
    unsigned short* usC = (unsigned short*)Cg + (long long)blockIdx.z * sC;

    const int bm = blockIdx.y * 128, bn = blockIdx.x * 128;
    const int tid = threadIdx.x;
    const int w = tid >> 6, l = tid & 63;
    const int wm = (w >> 1) * 64, wn = (w & 1) * 64;
    const int fr = l & 15, g = l >> 4;

    const f32x4 zero = { 0.f, 0.f, 0.f, 0.f };
    f32x4 acc[4][4];
    #pragma unroll
    for (int i = 0; i < 4; ++i)
        #pragma unroll
        for (int j = 0; j < 4; ++j) acc[i][j] = zero;

    for (int k0 = 0; k0 < K; k0 += 32) {
        #pragma unroll
        for (int p = 0; p < 2; ++p) {
            const int c = p * 256 + tid;
            GLOAD16(A + (long long)(bm + (c >> 2)) * K + k0 + (c & 3) * 8, &As[c * 8]);
            GLOAD16(B + (long long)(bn + (c >> 2)) * K + k0 + (c & 3) * 8, &Bs[c * 8]);
        }
        __syncthreads();
        bf16x8 af[4], bfv[4];
        #pragma unroll
        for (int i = 0; i < 4; ++i) {
            af[i]  = *(const bf16x8*)&As[(wm + i * 16 + fr) * 32 + g * 8];
            bfv[i] = *(const bf16x8*)&Bs[(wn + i * 16 + fr) * 32 + g * 8];
        }
        #pragma unroll
        for (int i = 0; i < 4; ++i)
            #pragma unroll
            for (int j = 0; j < 4; ++j)
                acc[i][j] = __builtin_amdgcn_mfma_f32_16x16x32_bf16(af[i], bfv[j], acc[i][j], 0, 0, 0);
        __syncthreads();
    }

    #pragma unroll
    for (int mi = 0; mi < 4; ++mi) {
        #pragma unroll
        for (int ni = 0; ni < 4; ++ni) {
            #pragma unroll
            for (int jr = 0; jr < 4; ++jr) {
                const long long row = bm + wm + mi * 16 + g * 4 + jr;
                const long long col = bn + wn + ni * 16 + fr;
                const long long idx = row * (long long)N + col;
                float v = acc[mi][ni][jr];
                if (EPI == 0) {
                    fC[idx] = v;
                } else if (EPI == 1) {
                    usC[idx] = f2b(v);
                } else if (EPI == 2) {
                    v = fminf(fmaxf(v, -5.f), 5.f);
                    usC[idx] = f2b(v / (1.f + expf(-v)));
                } else if (EPI == 3) {
                    usC[idx] = f2b(b2f(usC[idx]) + alpha * v);
                } else if (EPI == 4) {
                    fC[idx] = aux[row] * v;
                } else if (EPI == 5) {
                    fC[idx] += alpha * v;
                } else if (EPI == 6) {
                    const float gf = b2f(((const unsigned short*)aux)[idx]);
                    usC[idx] = f2b(gf / (1.f + expf(-gf)) * v);
                } else {
                    fC[idx] = v;
                    ((unsigned short*)aux)[idx] = f2b(v);
                }
            }
        }
    }
}

// ---------------- fp32 -> bf16 casts (batched) ----------------
struct CastJobs {
    const float* src[10];
    unsigned short* dst[10];
    int n4[10];
};
__global__ __launch_bounds__(256) void cast_k(CastJobs jobs) {
    const int b = blockIdx.y;
    const float4* s = (const float4*)jobs.src[b];
    us4* d = (us4*)jobs.dst[b];
    const int n = jobs.n4[b];
    for (int i = blockIdx.x * 256 + threadIdx.x; i < n; i += gridDim.x * 256) {
        const float4 v = s[i];
        us4 o;
        o.x = f2b(v.x); o.y = f2b(v.y); o.z = f2b(v.z); o.w = f2b(v.w);
        d[i] = o;
    }
}

// ---------------- LayerNorm over 128, one wave per row, bf16 out ----------------
__global__ __launch_bounds__(64) void ln_k(const float* __restrict__ in, unsigned short* __restrict__ out,
                                           const float* __restrict__ gg, const float* __restrict__ bb)
{
    const int row = blockIdx.x;
    const int lane = threadIdx.x;
    const float z0 = in[(long long)row * 128 + lane];
    const float z1 = in[(long long)row * 128 + 64 + lane];
    float s = z0 + z1;
    for (int o = 32; o > 0; o >>= 1) s += __shfl_down(s, o, 64);
    s = __shfl(s, 0, 64);
    const float mu = s * (1.f / 128.f);
    const float d0 = z0 - mu, d1 = z1 - mu;
    float v = d0 * d0 + d1 * d1;
    for (int o = 32; o > 0; o >>= 1) v += __shfl_down(v, o, 64);
    v = __shfl(v, 0, 64);
    const float r = rsqrtf(v * (1.f / 128.f) + LN_EPSc);
    out[(long long)row * 128 + lane] = f2b(d0 * r * gg[lane] + bb[lane]);
    out[(long long)row * 128 + 64 + lane] = f2b(d1 * r * gg[lane + 64] + bb[lane + 64]);
}

// ---------------- transpose per batch: [2048,128] -> [128,2048] bf16 ----------------
__global__ __launch_bounds__(256) void trans_k(const unsigned short* __restrict__ in,
                                               unsigned short* __restrict__ out)
{
    const int z = blockIdx.z;
    const int t0 = blockIdx.x * 64, a0 = blockIdx.y * 64;
    __shared__ unsigned short T[64][72];
    const unsigned short* ip = in + (long long)z * Sc * Ac;
    unsigned short* op = out + (long long)z * Ac * Sc;
    const int rr = threadIdx.x >> 4, cc = (threadIdx.x & 15) * 4;
    #pragma unroll
    for (int p = 0; p < 4; ++p) {
        const int row = p * 16 + rr;
        *(us4*)&T[row][cc] = *(const us4*)&ip[(long long)(t0 + row) * Ac + a0 + cc];
    }
    __syncthreads();
    #pragma unroll
    for (int p = 0; p < 4; ++p) {
        const int arow = p * 16 + rr;
        us4 o;
        o.x = T[cc + 0][arow]; o.y = T[cc + 1][arow];
        o.z = T[cc + 2][arow]; o.w = T[cc + 3][arow];
        *(us4*)&op[(long long)(a0 + arow) * Sc + t0 + cc] = o;
    }
}

// ---------------- router: 512 blocks x 256 threads, NO global atomics ----------------
__global__ __launch_bounds__(256) void router_k(const float* __restrict__ x,
                                                const float* __restrict__ W_rg,
                                                const float* __restrict__ W_re,
                                                int* __restrict__ eidx, float* __restrict__ fw,
                                                float* __restrict__ dmsum,
                                                float* __restrict__ rpart)
{
    const int wv = threadIdx.x >> 6;
    const int lane = threadIdx.x & 63;
    float load8[8] = {0.f, 0.f, 0.f, 0.f, 0.f, 0.f, 0.f, 0.f};
    float sqg = 0.f, sqe = 0.f;

    #pragma unroll
    for (int it = 0; it < 2; ++it) {
        const int t = blockIdx.x * 8 + wv * 2 + it;
        const float* xr = x + (long long)t * Dc;
        float a0 = 0, a1 = 0, a2 = 0, a3 = 0, a4 = 0, a5 = 0;
        #pragma unroll
        for (int j = 0; j < 16; ++j) {
            const int d = lane + 64 * j;
            const float xv = xr[d];
            a0 += xv * W_rg[d];          a1 += xv * W_rg[Dc + d];
            a2 += xv * W_re[d];          a3 += xv * W_re[Dc + d];
            a4 += xv * W_re[2 * Dc + d]; a5 += xv * W_re[3 * Dc + d];
        }
        #pragma unroll
        for (int o = 32; o > 0; o >>= 1) {
            a0 += __shfl_xor(a0, o, 64); a1 += __shfl_xor(a1, o, 64);
            a2 += __shfl_xor(a2, o, 64); a3 += __shfl_xor(a3, o, 64);
            a4 += __shfl_xor(a4, o, 64); a5 += __shfl_xor(a5, o, 64);
        }
        if (lane == 0) {
            const float gl0 = a0, gl1 = a1;
            const float m = fmaxf(gl0, gl1);
            const float e0 = expf(gl0 - m), e1 = expf(gl1 - m);
            const float inv = 1.f / (e0 + e1);
            const float gp0 = e0 * inv, gp1 = e1 * inv;
            const int gidx = (gl1 > gl0) ? 1 : 0;
            const float gw = fmaxf(gp0, gp1);
            float el[4] = { a2, a3, a4, a5 };
            const float me = fmaxf(fmaxf(el[0], el[1]), fmaxf(el[2], el[3]));
            float ep[4]; float se = 0.f;
            #pragma unroll
            for (int i = 0; i < 4; ++i) { ep[i] = expf(el[i] - me); se += ep[i]; }
            const float invs = 1.f / se;
            #pragma unroll
            for (int i = 0; i < 4; ++i) ep[i] *= invs;
            int i0 = 0;
            #pragma unroll
            for (int i = 1; i < 4; ++i) if (ep[i] > ep[i0]) i0 = i;
            int i1 = -1;
            #pragma unroll
            for (int i = 0; i < 4; ++i) { if (i == i0) continue; if (i1 < 0 || ep[i] > ep[i1]) i1 = i; }
            const float w0 = ep[i0], w1 = ep[i1];
            const float sn = w0 + w1 + 1e-7f;
            const float f0 = gw * w0 / sn, f1 = gw * w1 / sn;
            const int ei0 = gidx * GSc + i0, ei1 = gidx * GSc + i1;
            eidx[t * 2] = ei0; eidx[t * 2 + 1] = ei1;
            fw[t * 2] = f0; fw[t * 2 + 1] = f1;
            dmsum[t] = f0 + f1;
            #pragma unroll
            for (int e = 0; e < 8; ++e)
                load8[e] += ((e == ei0) ? f0 : 0.f) + ((e == ei1) ? f1 : 0.f);
            sqg += gl0 * gl0 + gl1 * gl1;
            sqe += el[0] * el[0] + el[1] * el[1] + el[2] * el[2] + el[3] * el[3];
        }
    }
    __shared__ float sh[4][10];
    if (lane == 0) {
        #pragma unroll
        for (int e = 0; e < 8; ++e) sh[wv][e] = load8[e];
        sh[wv][8] = sqg; sh[wv][9] = sqe;
    }
    __syncthreads();
    if (threadIdx.x < 10) {
        rpart[blockIdx.x * 10 + threadIdx.x] =
            sh[0][threadIdx.x] + sh[1][threadIdx.x] + sh[2][threadIdx.x] + sh[3][threadIdx.x];
    }
}

// ---------------- loss reduce over RBLK partial rows ----------------
__global__ __launch_bounds__(512) void loss_k(const float* __restrict__ rpart,
                                              float* __restrict__ out_loss)
{
    const int tid = threadIdx.x;
    const int lane = tid & 63, wv = tid >> 6;
    float v[10];
    #pragma unroll
    for (int c = 0; c < 10; ++c) v[c] = rpart[tid * 10 + c];
    #pragma unroll
    for (int o = 32; o > 0; o >>= 1)
        #pragma unroll
        for (int c = 0; c < 10; ++c) v[c] += __shfl_xor(v[c], o, 64);
    __shared__ float sh[8][10];
    if (lane == 0) {
        #pragma unroll
        for (int c = 0; c < 10; ++c) sh[wv][c] = v[c];
    }
    __syncthreads();
    if (tid == 0) {
        float load[8]; float sqg = 0.f, sqe = 0.f;
        #pragma unroll
        for (int e = 0; e < 8; ++e) load[e] = 0.f;
        for (int wvi = 0; wvi < 8; ++wvi) {
            #pragma unroll
            for (int e = 0; e < 8; ++e) load[e] += sh[wvi][e];
            sqg += sh[wvi][8]; sqe += sh[wvi][9];
        }
        float s = 0.f;
        for (int e = 0; e < Ec; ++e) s += load[e];
        const float tgt = s / (float)Ec;
        float var = 0.f;
        for (int e = 0; e < Ec; ++e) { const float d = load[e] - tgt; var += d * d; }
        var /= (float)Ec;
        const float l = var + sqg / (float)(Nc * Gc) + sqe / (float)(Nc * GSc);
        *out_loss = 0.001f * l;
    }
}

// ---------------- combine: h2[t] = sum_slot fw * LN_e(h_dense[e][t]) ----------------
__global__ __launch_bounds__(128) void combine_k(const float* __restrict__ h_dense,
                                                 const float* __restrict__ ln_g_e,
                                                 const float* __restrict__ ln_b_e,
                                                 const int* __restrict__ eidx,
                                                 const float* __restrict__ fw,
                                                 unsigned short* __restrict__ h2)
{
    const int t = blockIdx.x;
    const int tid = threadIdx.x;
    __shared__ float red[2];

    float acc = 0.f;
    #pragma unroll
    for (int slot = 0; slot < 2; ++slot) {
        const int e = eidx[t * 2 + slot];
        const float w = fw[t * 2 + slot];
        const float h = h_dense[((long long)e * Nc + t) * 128 + tid];
        float v = h;
        for (int o = 32; o > 0; o >>= 1) v += __shfl_down(v, o, 64);
        if ((tid & 63) == 0) red[tid >> 6] = v;
        __syncthreads();
        const float mu = (red[0] + red[1]) * (1.f / 128.f);
        __syncthreads();
        const float d = h - mu;
        v = d * d;
        for (int o = 32; o > 0; o >>= 1) v += __shfl_down(v, o, 64);
        if ((tid & 63) == 0) red[tid >> 6] = v;
        __syncthreads();
        const float var = (red[0] + red[1]) * (1.f / 128.f);
        __syncthreads();
        acc += w * (d * rsqrtf(var + LN_EPSc) * ln_g_e[e * 128 + tid] + ln_b_e[e * 128 + tid]);
    }
    h2[(long long)t * 128 + tid] = f2b(acc);
}

// =====================================================================
extern "C" void kernel_launch(void* const* d_in, const int* in_sizes, int n_in,
                              void* d_out, int out_size, void* d_ws, size_t ws_size,
                              hipStream_t stream)
{
    const float* x       = (const float*)d_in[0];
    const float* W_up    = (const float*)d_in[1];
    const float* W_gate  = (const float*)d_in[2];
    const float* W_down  = (const float*)d_in[3];
    const float* W_pre   = (const float*)d_in[4];
    const float* W_post  = (const float*)d_in[5];
    const float* ln_g    = (const float*)d_in[6];
    const float* ln_b    = (const float*)d_in[7];
    const float* W_aproj = (const float*)d_in[8];
    const float* A_exp   = (const float*)d_in[9];
    const float* ln_g_e  = (const float*)d_in[10];
    const float* ln_b_e  = (const float*)d_in[11];
    const float* W_eproj = (const float*)d_in[12];
    const float* W_oproj = (const float*)d_in[13];
    const float* W_rg    = (const float*)d_in[14];
    const float* W_re    = (const float*)d_in[15];

    float* out = (float*)d_out;

    // ---- workspace carve ----
    char* p = (char*)d_ws;
    auto alloc = [&](size_t bytes) { void* r = (void*)p; p += (bytes + 255) & ~(size_t)255; return r; };
    float* pre      = (float*)alloc((size_t)Nc * Ac * 4);
    float* postbuf  = (float*)alloc((size_t)Nc * Ac * 4);
    float* h_dense  = (float*)alloc((size_t)Ec * Nc * Ac * 4);   // 16.8 MB
    float* rpart    = (float*)alloc((size_t)RBLK * 10 * 4);
    float* fw       = (float*)alloc((size_t)Nc * 2 * 4);
    float* dmsum    = (float*)alloc((size_t)Nc * 4);
    int*   eidx     = (int*)alloc((size_t)Nc * 2 * 4);
    unsigned short* xb      = (unsigned short*)alloc((size_t)Nc * Dc * 2);
    unsigned short* Wg_b    = (unsigned short*)alloc((size_t)Hc * Dc * 2);
    unsigned short* Wu_b    = (unsigned short*)alloc((size_t)Hc * Dc * 2);
    unsigned short* Wd_b    = (unsigned short*)alloc((size_t)Dc * Hc * 2);
    unsigned short* Wop_b   = (unsigned short*)alloc((size_t)Dc * Hc * 2);
    unsigned short* Wpre_b  = (unsigned short*)alloc((size_t)Ac * Dc * 2);
    unsigned short* Wpost_b = (unsigned short*)alloc((size_t)Ac * Hc * 2);
    unsigned short* Wap_b   = (unsigned short*)alloc((size_t)Hc * Ac * 2);
    unsigned short* Wep_b   = (unsigned short*)alloc((size_t)Hc * Ac * 2);
    unsigned short* Aexp_b  = (unsigned short*)alloc((size_t)Ec * Ac * Ac * 2);
    unsigned short* pre_b   = (unsigned short*)alloc((size_t)Nc * Ac * 2);
    unsigned short* hidden  = (unsigned short*)alloc((size_t)Nc * Hc * 2);
    unsigned short* bufB    = (unsigned short*)alloc((size_t)Nc * Hc * 2);   // gate -> aw -> eproj tmp
    unsigned short* adapt_in  = (unsigned short*)alloc((size_t)Nc * Ac * 2);
    unsigned short* adapt_inT = (unsigned short*)alloc((size_t)Nc * Ac * 2);
    unsigned short* adapt_out = (unsigned short*)alloc((size_t)Nc * Ac * 2);
    unsigned short* adaptb    = (unsigned short*)alloc((size_t)Nc * Ac * 2);
    unsigned short* h2        = (unsigned short*)alloc((size_t)Nc * Ac * 2);

    // ---- casts ----
    CastJobs jobs;
    jobs.src[0] = x;       jobs.dst[0] = xb;      jobs.n4[0] = Nc * Dc / 4;
    jobs.src[1] = W_gate;  jobs.dst[1] = Wg_b;    jobs.n4[1] = Hc * Dc / 4;
    jobs.src[2] = W_up;    jobs.dst[2] = Wu_b;    jobs.n4[2] = Hc * Dc / 4;
    jobs.src[3] = W_down;  jobs.dst[3] = Wd_b;    jobs.n4[3] = Dc * Hc / 4;
    jobs.src[4] = W_oproj; jobs.dst[4] = Wop_b;   jobs.n4[4] = Dc * Hc / 4;
    jobs.src[5] = W_pre;   jobs.dst[5] = Wpre_b;  jobs.n4[5] = Ac * Dc / 4;
    jobs.src[6] = W_post;  jobs.dst[6] = Wpost_b; jobs.n4[6] = Ac * Hc / 4;
    jobs.src[7] = W_aproj; jobs.dst[7] = Wap_b;   jobs.n4[7] = Hc * Ac / 4;
    jobs.src[8] = W_eproj; jobs.dst[8] = Wep_b;   jobs.n4[8] = Hc * Ac / 4;
    jobs.src[9] = A_exp;   jobs.dst[9] = Aexp_b;  jobs.n4[9] = Ec * Ac * Ac / 4;
    cast_k<<<dim3(256, 10), 256, 0, stream>>>(jobs);

    // ---- router (atomic-free) ----
    router_k<<<RBLK, 256, 0, stream>>>(x, W_rg, W_re, eidx, fw, dmsum, rpart);
    loss_k<<<1, 512, 0, stream>>>(rpart, out + (size_t)Nc * Dc);

    // ---- pre (f32 + bf16) / adapt_in ----
    mgemm<7><<<dim3(1, 32), 256, 0, stream>>>(xb, Wpre_b, pre, Ac, Dc, 0.f, (const float*)pre_b, 0, 0, 0);
    ln_k<<<Nc, 64, 0, stream>>>(pre, adapt_in, ln_g, ln_b);
    trans_k<<<dim3(Sc / 64, Ac / 64, Bc), 256, 0, stream>>>(adapt_in, adapt_inT);

    // ---- gate -> bufB, up (fused silu(gate)*up) -> hidden ----
    mgemm<1><<<dim3(16, 32), 256, 0, stream>>>(xb, Wg_b, bufB, Hc, Dc, 0.f, nullptr, 0, 0, 0);
    mgemm<6><<<dim3(16, 32), 256, 0, stream>>>(xb, Wu_b, hidden, Hc, Dc, 0.f, (const float*)bufB, 0, 0, 0);

    // ---- post / adapt_out ----
    mgemm<0><<<dim3(1, 32), 256, 0, stream>>>(hidden, Wpost_b, postbuf, Ac, Hc, 0.f, nullptr, 0, 0, 0);
    ln_k<<<Nc, 64, 0, stream>>>(postbuf, adapt_out, ln_g, ln_b);

    // ---- dense expert adapter: h_dense[e] = pre_b @ A_exp[e]^T ----
    mgemm<0><<<dim3(1, 32, Ec), 256, 0, stream>>>(pre_b, Aexp_b, h_dense, Ac, Ac, 0.f, nullptr,
        0, (long long)Ac * Ac, (long long)Nc * Ac);
    combine_k<<<Nc, 128, 0, stream>>>(h_dense, ln_g_e, ln_b_e, eidx, fw, h2);

    // ---- aw = silu(clip(adapt_in @ adapt_out^T)) per batch ----
    mgemm<2><<<dim3(16, 16, Bc), 256, 0, stream>>>(adapt_in, adapt_out, bufB, Sc, Ac, 0.f, nullptr,
        (long long)Sc * Ac, (long long)Sc * Ac, (long long)Sc * Sc);

    // ---- adapt = aw @ adapt_in  (B^T form via adapt_inT) ----
    mgemm<1><<<dim3(1, 16, Bc), 256, 0, stream>>>(bufB, adapt_inT, adaptb, Ac, Sc, 0.f, nullptr,
        (long long)Sc * Sc, (long long)Ac * Sc, (long long)Sc * Ac);

    // ---- hidden += 0.1 * adapt @ W_aproj^T ----
    mgemm<3><<<dim3(16, 32), 256, 0, stream>>>(adaptb, Wap_b, hidden, Hc, Ac, 0.1f, nullptr, 0, 0, 0);

    // ---- out = dmsum[row] * (hidden @ W_down^T) ----
    mgemm<4><<<dim3(8, 32), 256, 0, stream>>>(hidden, Wd_b, out, Dc, Hc, 0.f, dmsum, 0, 0, 0);

    // ---- expert projections ----
    mgemm<1><<<dim3(16, 32), 256, 0, stream>>>(h2, Wep_b, bufB, Hc, Ac, 0.f, nullptr, 0, 0, 0);
    mgemm<5><<<dim3(8, 32), 256, 0, stream>>>(bufB, Wop_b, out, Dc, Hc, 0.1f, nullptr, 0, 0, 0);
}

// Round 5
// 301.880 us; speedup vs baseline: 5.3322x; 1.1595x over previous
//
#include <hip/hip_runtime.h>
#include <hip/hip_bf16.h>
#include <math.h>

static constexpr int Bc = 2;
static constexpr int Sc = 2048;
static constexpr int Dc = 1024;
static constexpr int Hc = 2048;
static constexpr int Ac = 128;
static constexpr int Ec = 8;
static constexpr int GSc = 4;
static constexpr int Gc = 2;
static constexpr int Nc = Bc * Sc;   // 4096 tokens
static constexpr float LN_EPSc = 1e-5f;
static constexpr int RBLK = 512;     // router blocks

typedef __attribute__((ext_vector_type(8))) short bf16x8;
typedef __attribute__((ext_vector_type(4))) float f32x4;
typedef __attribute__((ext_vector_type(4))) unsigned short us4;
typedef unsigned short ushort_t;

__device__ __forceinline__ unsigned short f2b(float f) {
    union { float f; unsigned u; } v; v.f = f;
    return (unsigned short)((v.u + 0x7FFFu + ((v.u >> 16) & 1u)) >> 16);
}
__device__ __forceinline__ float b2f(unsigned short h) {
    union { unsigned u; float f; } v; v.u = (unsigned)h << 16; return v.f;
}

#define GLOAD16(g, l) __builtin_amdgcn_global_load_lds( \
    (const __attribute__((address_space(1))) void*)(g), \
    (__attribute__((address_space(3))) void*)(l), 16, 0, 0)

// ---------------- bf16 MFMA GEMM: C[M,N] = A[M,K] @ B[N,K]^T ----------------
// 128x128 tile, BK=32, 4 waves (2x2). XCD-aware bijective swizzle (needs nwg%8==0).
// EPI: 0=store f32, 1=store bf16, 2=silu(clip(v)) bf16,
//      7=f32 store + bf16 store (aux), 8=bf16 store alpha*v,
//      9=gateup paired: usC[row][col/2-space] = silu(acc_even)*acc_odd
template<int EPI>
__global__ __launch_bounds__(256, 2) void mgemm(
    const unsigned short* __restrict__ Ag, const unsigned short* __restrict__ Bg,
    void* __restrict__ Cg, int N, int K, float alpha,
    const float* __restrict__ aux,
    long long sA, long long sB, long long sC)
{
    __shared__ unsigned short As[128 * 32];
    __shared__ unsigned short Bs[128 * 32];
    const unsigned short* A = Ag + (long long)blockIdx.z * sA;
    const unsigned short* B = Bg + (long long)blockIdx.z * sB;
    float* fC = (float*)Cg + (long long)blockIdx.z * sC;
    unsigned short* usC = (unsigned short*)Cg + (long long)blockIdx.z * sC;

    const int nwg = gridDim.x * gridDim.y;
    const int flat = blockIdx.y * gridDim.x + blockIdx.x;
    const int swz = (flat & 7) * (nwg >> 3) + (flat >> 3);
    const int bx = swz % gridDim.x, by = swz / gridDim.x;
    const int bm = by * 128, bn = bx * 128;

    const int tid = threadIdx.x;
    const int w = tid >> 6, l = tid & 63;
    const int wm = (w >> 1) * 64, wn = (w & 1) * 64;
    const int fr = l & 15, g = l >> 4;

    const f32x4 zero = { 0.f, 0.f, 0.f, 0.f };
    f32x4 acc[4][4];
    #pragma unroll
    for (int i = 0; i < 4; ++i)
        #pragma unroll
        for (int j = 0; j < 4; ++j) acc[i][j] = zero;

    for (int k0 = 0; k0 < K; k0 += 32) {
        #pragma unroll
        for (int p = 0; p < 2; ++p) {
            const int c = p * 256 + tid;
            GLOAD16(A + (long long)(bm + (c >> 2)) * K + k0 + (c & 3) * 8, &As[c * 8]);
            GLOAD16(B + (long long)(bn + (c >> 2)) * K + k0 + (c & 3) * 8, &Bs[c * 8]);
        }
        __syncthreads();
        bf16x8 af[4], bfv[4];
        #pragma unroll
        for (int i = 0; i < 4; ++i) {
            af[i]  = *(const bf16x8*)&As[(wm + i * 16 + fr) * 32 + g * 8];
            bfv[i] = *(const bf16x8*)&Bs[(wn + i * 16 + fr) * 32 + g * 8];
        }
        #pragma unroll
        for (int i = 0; i < 4; ++i)
            #pragma unroll
            for (int j = 0; j < 4; ++j)
                acc[i][j] = __builtin_amdgcn_mfma_f32_16x16x32_bf16(af[i], bfv[j], acc[i][j], 0, 0, 0);
        __syncthreads();
    }

    if (EPI == 9) {
        const int Nh = N >> 1;
        #pragma unroll
        for (int mi = 0; mi < 4; ++mi) {
            #pragma unroll
            for (int j = 0; j < 2; ++j) {
                #pragma unroll
                for (int jr = 0; jr < 4; ++jr) {
                    const long long row = bm + wm + mi * 16 + g * 4 + jr;
                    const long long colh = ((bn + wn) >> 1) + j * 16 + fr;
                    const float gv = acc[mi][2 * j][jr];
                    const float uv = acc[mi][2 * j + 1][jr];
                    usC[row * Nh + colh] = f2b(gv / (1.f + expf(-gv)) * uv);
                }
            }
        }
    } else {
        #pragma unroll
        for (int mi = 0; mi < 4; ++mi) {
            #pragma unroll
            for (int ni = 0; ni < 4; ++ni) {
                #pragma unroll
                for (int jr = 0; jr < 4; ++jr) {
                    const long long row = bm + wm + mi * 16 + g * 4 + jr;
                    const long long col = bn + wn + ni * 16 + fr;
                    const long long idx = row * (long long)N + col;
                    float v = acc[mi][ni][jr];
                    if (EPI == 0) {
                        fC[idx] = v;
                    } else if (EPI == 1) {
                        usC[idx] = f2b(v);
                    } else if (EPI == 2) {
                        v = fminf(fmaxf(v, -5.f), 5.f);
                        usC[idx] = f2b(v / (1.f + expf(-v)));
                    } else if (EPI == 7) {
                        fC[idx] = v;
                        ((unsigned short*)aux)[idx] = f2b(v);
                    } else if (EPI == 8) {
                        usC[idx] = f2b(alpha * v);
                    }
                }
            }
        }
    }
}

// ---------------- final fused 3-phase GEMM ----------------
// out[4096,1024] = dmsum[row]*(hidden@Wd^T + adaptb@Wdap^T) + h2@Wopep^T
// (0.1 factors pre-folded into Wdap/Wopep)
__global__ __launch_bounds__(256, 2) void final_k(
    const unsigned short* __restrict__ hidden, const unsigned short* __restrict__ Wd,
    const unsigned short* __restrict__ adaptb, const unsigned short* __restrict__ Wdap,
    const unsigned short* __restrict__ h2, const unsigned short* __restrict__ Wopep,
    const float* __restrict__ dmsum, float* __restrict__ out)
{
    __shared__ unsigned short As[128 * 32];
    __shared__ unsigned short Bs[128 * 32];

    const int nwg = gridDim.x * gridDim.y;
    const int flat = blockIdx.y * gridDim.x + blockIdx.x;
    const int swz = (flat & 7) * (nwg >> 3) + (flat >> 3);
    const int bx = swz % gridDim.x, by = swz / gridDim.x;
    const int bm = by * 128, bn = bx * 128;

    const int tid = threadIdx.x;
    const int w = tid >> 6, l = tid & 63;
    const int wm = (w >> 1) * 64, wn = (w & 1) * 64;
    const int fr = l & 15, g = l >> 4;

    const f32x4 zero = { 0.f, 0.f, 0.f, 0.f };
    f32x4 acc[4][4];
    #pragma unroll
    for (int i = 0; i < 4; ++i)
        #pragma unroll
        for (int j = 0; j < 4; ++j) acc[i][j] = zero;

    // phase 1: hidden @ Wd^T, K = 2048 ; phase 2: adaptb @ Wdap^T, K = 128
    #pragma unroll 1
    for (int ph = 0; ph < 2; ++ph) {
        const unsigned short* A = (ph == 0) ? hidden : adaptb;
        const unsigned short* B = (ph == 0) ? Wd : Wdap;
        const int K = (ph == 0) ? Hc : Ac;
        for (int k0 = 0; k0 < K; k0 += 32) {
            #pragma unroll
            for (int p = 0; p < 2; ++p) {
                const int c = p * 256 + tid;
                GLOAD16(A + (long long)(bm + (c >> 2)) * K + k0 + (c & 3) * 8, &As[c * 8]);
                GLOAD16(B + (long long)(bn + (c >> 2)) * K + k0 + (c & 3) * 8, &Bs[c * 8]);
            }
            __syncthreads();
            bf16x8 af[4], bfv[4];
            #pragma unroll
            for (int i = 0; i < 4; ++i) {
                af[i]  = *(const bf16x8*)&As[(wm + i * 16 + fr) * 32 + g * 8];
                bfv[i] = *(const bf16x8*)&Bs[(wn + i * 16 + fr) * 32 + g * 8];
            }
            #pragma unroll
            for (int i = 0; i < 4; ++i)
                #pragma unroll
                for (int j = 0; j < 4; ++j)
                    acc[i][j] = __builtin_amdgcn_mfma_f32_16x16x32_bf16(af[i], bfv[j], acc[i][j], 0, 0, 0);
            __syncthreads();
        }
    }

    // scale by dmsum[row]
    #pragma unroll
    for (int mi = 0; mi < 4; ++mi) {
        #pragma unroll
        for (int jr = 0; jr < 4; ++jr) {
            const float rs = dmsum[bm + wm + mi * 16 + g * 4 + jr];
            #pragma unroll
            for (int ni = 0; ni < 4; ++ni) acc[mi][ni][jr] *= rs;
        }
    }

    // phase 3: h2 @ Wopep^T, K = 128
    for (int k0 = 0; k0 < Ac; k0 += 32) {
        #pragma unroll
        for (int p = 0; p < 2; ++p) {
            const int c = p * 256 + tid;
            GLOAD16(h2 + (long long)(bm + (c >> 2)) * Ac + k0 + (c & 3) * 8, &As[c * 8]);
            GLOAD16(Wopep + (long long)(bn + (c >> 2)) * Ac + k0 + (c & 3) * 8, &Bs[c * 8]);
        }
        __syncthreads();
        bf16x8 af[4], bfv[4];
        #pragma unroll
        for (int i = 0; i < 4; ++i) {
            af[i]  = *(const bf16x8*)&As[(wm + i * 16 + fr) * 32 + g * 8];
            bfv[i] = *(const bf16x8*)&Bs[(wn + i * 16 + fr) * 32 + g * 8];
        }
        #pragma unroll
        for (int i = 0; i < 4; ++i)
            #pragma unroll
            for (int j = 0; j < 4; ++j)
                acc[i][j] = __builtin_amdgcn_mfma_f32_16x16x32_bf16(af[i], bfv[j], acc[i][j], 0, 0, 0);
        __syncthreads();
    }

    #pragma unroll
    for (int mi = 0; mi < 4; ++mi)
        #pragma unroll
        for (int ni = 0; ni < 4; ++ni)
            #pragma unroll
            for (int jr = 0; jr < 4; ++jr) {
                const long long row = bm + wm + mi * 16 + g * 4 + jr;
                const long long col = bn + wn + ni * 16 + fr;
                out[row * (long long)Dc + col] = acc[mi][ni][jr];
            }
}

// ---------------- fp32 -> bf16 casts (batched) ----------------
struct CastJobs {
    const float* src[6];
    unsigned short* dst[6];
    int n4[6];
};
__global__ __launch_bounds__(256) void cast_k(CastJobs jobs) {
    const int b = blockIdx.y;
    const float4* s = (const float4*)jobs.src[b];
    us4* d = (us4*)jobs.dst[b];
    const int n = jobs.n4[b];
    for (int i = blockIdx.x * 256 + threadIdx.x; i < n; i += gridDim.x * 256) {
        const float4 v = s[i];
        us4 o;
        o.x = f2b(v.x); o.y = f2b(v.y); o.z = f2b(v.z); o.w = f2b(v.w);
        d[i] = o;
    }
}

// ---------------- gate/up interleaved cast: Wcat[4096,1024] bf16 ----------------
// Wcat row r: b=r>>5, w=r&31; w<16 -> gate row b*16+w ; else up row b*16+(w-16)
__global__ __launch_bounds__(256) void gucast_k(const float* __restrict__ Wg,
                                                const float* __restrict__ Wu,
                                                unsigned short* __restrict__ Wcat)
{
    const int r = blockIdx.x;
    const int b = r >> 5, w = r & 31;
    const float* src = (w < 16) ? Wg : Wu;
    const int srcrow = b * 16 + (w & 15);
    const float4 v = ((const float4*)(src + (long long)srcrow * Dc))[threadIdx.x];
    us4 o;
    o.x = f2b(v.x); o.y = f2b(v.y); o.z = f2b(v.z); o.w = f2b(v.w);
    ((us4*)(Wcat + (long long)r * Dc))[threadIdx.x] = o;
}

// ---------------- cast-transpose: f32 [2048,128] -> bf16 [128,2048], z=0/1 ----------------
__global__ __launch_bounds__(256) void ct_k(const float* __restrict__ in0,
                                            const float* __restrict__ in1,
                                            unsigned short* __restrict__ out0,
                                            unsigned short* __restrict__ out1)
{
    const float* in = blockIdx.z ? in1 : in0;
    unsigned short* out = blockIdx.z ? out1 : out0;
    const int t0 = blockIdx.x * 64, a0 = blockIdx.y * 64;
    __shared__ float T[64][68];
    const int rr = threadIdx.x >> 4, cc = (threadIdx.x & 15) * 4;
    #pragma unroll
    for (int p = 0; p < 4; ++p) {
        const int row = p * 16 + rr;
        *(float4*)&T[row][cc] = *(const float4*)&in[(long long)(t0 + row) * Ac + a0 + cc];
    }
    __syncthreads();
    #pragma unroll
    for (int p = 0; p < 4; ++p) {
        const int ar = p * 16 + rr;
        us4 o;
        o.x = f2b(T[cc + 0][ar]); o.y = f2b(T[cc + 1][ar]);
        o.z = f2b(T[cc + 2][ar]); o.w = f2b(T[cc + 3][ar]);
        *(us4*)&out[(long long)(a0 + ar) * Hc + t0 + cc] = o;
    }
}

// ---------------- LayerNorm over 128, one wave per row, bf16 out ----------------
__global__ __launch_bounds__(64) void ln_k(const float* __restrict__ in, unsigned short* __restrict__ out,
                                           const float* __restrict__ gg, const float* __restrict__ bb)
{
    const int row = blockIdx.x;
    const int lane = threadIdx.x;
    const float z0 = in[(long long)row * 128 + lane];
    const float z1 = in[(long long)row * 128 + 64 + lane];
    float s = z0 + z1;
    for (int o = 32; o > 0; o >>= 1) s += __shfl_down(s, o, 64);
    s = __shfl(s, 0, 64);
    const float mu = s * (1.f / 128.f);
    const float d0 = z0 - mu, d1 = z1 - mu;
    float v = d0 * d0 + d1 * d1;
    for (int o = 32; o > 0; o >>= 1) v += __shfl_down(v, o, 64);
    v = __shfl(v, 0, 64);
    const float r = rsqrtf(v * (1.f / 128.f) + LN_EPSc);
    out[(long long)row * 128 + lane] = f2b(d0 * r * gg[lane] + bb[lane]);
    out[(long long)row * 128 + 64 + lane] = f2b(d1 * r * gg[lane + 64] + bb[lane + 64]);
}

// ---------------- transpose per batch: [2048,128] -> [128,2048] bf16 ----------------
__global__ __launch_bounds__(256) void trans_k(const unsigned short* __restrict__ in,
                                               unsigned short* __restrict__ out)
{
    const int z = blockIdx.z;
    const int t0 = blockIdx.x * 64, a0 = blockIdx.y * 64;
    __shared__ unsigned short T[64][72];
    const unsigned short* ip = in + (long long)z * Sc * Ac;
    unsigned short* op = out + (long long)z * Ac * Sc;
    const int rr = threadIdx.x >> 4, cc = (threadIdx.x & 15) * 4;
    #pragma unroll
    for (int p = 0; p < 4; ++p) {
        const int row = p * 16 + rr;
        *(us4*)&T[row][cc] = *(const us4*)&ip[(long long)(t0 + row) * Ac + a0 + cc];
    }
    __syncthreads();
    #pragma unroll
    for (int p = 0; p < 4; ++p) {
        const int arow = p * 16 + rr;
        us4 o;
        o.x = T[cc + 0][arow]; o.y = T[cc + 1][arow];
        o.z = T[cc + 2][arow]; o.w = T[cc + 3][arow];
        *(us4*)&op[(long long)(a0 + arow) * Sc + t0 + cc] = o;
    }
}

// ---------------- router: 512 blocks x 256 threads, NO global atomics ----------------
__global__ __launch_bounds__(256) void router_k(const float* __restrict__ x,
                                                const float* __restrict__ W_rg,
                                                const float* __restrict__ W_re,
                                                int* __restrict__ eidx, float* __restrict__ fw,
                                                float* __restrict__ dmsum,
                                                float* __restrict__ rpart)
{
    const int wv = threadIdx.x >> 6;
    const int lane = threadIdx.x & 63;
    float load8[8] = {0.f, 0.f, 0.f, 0.f, 0.f, 0.f, 0.f, 0.f};
    float sqg = 0.f, sqe = 0.f;

    #pragma unroll
    for (int it = 0; it < 2; ++it) {
        const int t = blockIdx.x * 8 + wv * 2 + it;
        const float* xr = x + (long long)t * Dc;
        float a0 = 0, a1 = 0, a2 = 0, a3 = 0, a4 = 0, a5 = 0;
        #pragma unroll
        for (int j = 0; j < 16; ++j) {
            const int d = lane + 64 * j;
            const float xv = xr[d];
            a0 += xv * W_rg[d];          a1 += xv * W_rg[Dc + d];
            a2 += xv * W_re[d];          a3 += xv * W_re[Dc + d];
            a4 += xv * W_re[2 * Dc + d]; a5 += xv * W_re[3 * Dc + d];
        }
        #pragma unroll
        for (int o = 32; o > 0; o >>= 1) {
            a0 += __shfl_xor(a0, o, 64); a1 += __shfl_xor(a1, o, 64);
            a2 += __shfl_xor(a2, o, 64); a3 += __shfl_xor(a3, o, 64);
            a4 += __shfl_xor(a4, o, 64); a5 += __shfl_xor(a5, o, 64);
        }
        if (lane == 0) {
            const float gl0 = a0, gl1 = a1;
            const float m = fmaxf(gl0, gl1);
            const float e0 = expf(gl0 - m), e1 = expf(gl1 - m);
            const float inv = 1.f / (e0 + e1);
            const float gp0 = e0 * inv, gp1 = e1 * inv;
            const int gidx = (gl1 > gl0) ? 1 : 0;
            const float gw = fmaxf(gp0, gp1);
            float el[4] = { a2, a3, a4, a5 };
            const float me = fmaxf(fmaxf(el[0], el[1]), fmaxf(el[2], el[3]));
            float ep[4]; float se = 0.f;
            #pragma unroll
            for (int i = 0; i < 4; ++i) { ep[i] = expf(el[i] - me); se += ep[i]; }
            const float invs = 1.f / se;
            #pragma unroll
            for (int i = 0; i < 4; ++i) ep[i] *= invs;
            int i0 = 0;
            #pragma unroll
            for (int i = 1; i < 4; ++i) if (ep[i] > ep[i0]) i0 = i;
            int i1 = -1;
            #pragma unroll
            for (int i = 0; i < 4; ++i) { if (i == i0) continue; if (i1 < 0 || ep[i] > ep[i1]) i1 = i; }
            const float w0 = ep[i0], w1 = ep[i1];
            const float sn = w0 + w1 + 1e-7f;
            const float f0 = gw * w0 / sn, f1 = gw * w1 / sn;
            const int ei0 = gidx * GSc + i0, ei1 = gidx * GSc + i1;
            eidx[t * 2] = ei0; eidx[t * 2 + 1] = ei1;
            fw[t * 2] = f0; fw[t * 2 + 1] = f1;
            dmsum[t] = f0 + f1;
            #pragma unroll
            for (int e = 0; e < 8; ++e)
                load8[e] += ((e == ei0) ? f0 : 0.f) + ((e == ei1) ? f1 : 0.f);
            sqg += gl0 * gl0 + gl1 * gl1;
            sqe += el[0] * el[0] + el[1] * el[1] + el[2] * el[2] + el[3] * el[3];
        }
    }
    __shared__ float sh[4][10];
    if (lane == 0) {
        #pragma unroll
        for (int e = 0; e < 8; ++e) sh[wv][e] = load8[e];
        sh[wv][8] = sqg; sh[wv][9] = sqe;
    }
    __syncthreads();
    if (threadIdx.x < 10) {
        rpart[blockIdx.x * 10 + threadIdx.x] =
            sh[0][threadIdx.x] + sh[1][threadIdx.x] + sh[2][threadIdx.x] + sh[3][threadIdx.x];
    }
}

// ---------------- loss reduce over RBLK partial rows ----------------
__global__ __launch_bounds__(512) void loss_k(const float* __restrict__ rpart,
                                              float* __restrict__ out_loss)
{
    const int tid = threadIdx.x;
    const int lane = tid & 63, wv = tid >> 6;
    float v[10];
    #pragma unroll
    for (int c = 0; c < 10; ++c) v[c] = rpart[tid * 10 + c];
    #pragma unroll
    for (int o = 32; o > 0; o >>= 1)
        #pragma unroll
        for (int c = 0; c < 10; ++c) v[c] += __shfl_xor(v[c], o, 64);
    __shared__ float sh[8][10];
    if (lane == 0) {
        #pragma unroll
        for (int c = 0; c < 10; ++c) sh[wv][c] = v[c];
    }
    __syncthreads();
    if (tid == 0) {
        float load[8]; float sqg = 0.f, sqe = 0.f;
        #pragma unroll
        for (int e = 0; e < 8; ++e) load[e] = 0.f;
        for (int wvi = 0; wvi < 8; ++wvi) {
            #pragma unroll
            for (int e = 0; e < 8; ++e) load[e] += sh[wvi][e];
            sqg += sh[wvi][8]; sqe += sh[wvi][9];
        }
        float s = 0.f;
        for (int e = 0; e < Ec; ++e) s += load[e];
        const float tgt = s / (float)Ec;
        float var = 0.f;
        for (int e = 0; e < Ec; ++e) { const float d = load[e] - tgt; var += d * d; }
        var /= (float)Ec;
        const float l = var + sqg / (float)(Nc * Gc) + sqe / (float)(Nc * GSc);
        *out_loss = 0.001f * l;
    }
}

// ---------------- combine: h2[t] = sum_slot fw * LN_e(h_dense[e][t]) ----------------
__global__ __launch_bounds__(128) void combine_k(const float* __restrict__ h_dense,
                                                 const float* __restrict__ ln_g_e,
                                                 const float* __restrict__ ln_b_e,
                                                 const int* __restrict__ eidx,
                                                 const float* __restrict__ fw,
                                                 unsigned short* __restrict__ h2)
{
    const int t = blockIdx.x;
    const int tid = threadIdx.x;
    __shared__ float red[2];

    float acc = 0.f;
    #pragma unroll
    for (int slot = 0; slot < 2; ++slot) {
        const int e = eidx[t * 2 + slot];
        const float w = fw[t * 2 + slot];
        const float h = h_dense[((long long)e * Nc + t) * 128 + tid];
        float v = h;
        for (int o = 32; o > 0; o >>= 1) v += __shfl_down(v, o, 64);
        if ((tid & 63) == 0) red[tid >> 6] = v;
        __syncthreads();
        const float mu = (red[0] + red[1]) * (1.f / 128.f);
        __syncthreads();
        const float d = h - mu;
        v = d * d;
        for (int o = 32; o > 0; o >>= 1) v += __shfl_down(v, o, 64);
        if ((tid & 63) == 0) red[tid >> 6] = v;
        __syncthreads();
        const float var = (red[0] + red[1]) * (1.f / 128.f);
        __syncthreads();
        acc += w * (d * rsqrtf(var + LN_EPSc) * ln_g_e[e * 128 + tid] + ln_b_e[e * 128 + tid]);
    }
    h2[(long long)t * 128 + tid] = f2b(acc);
}

// =====================================================================
extern "C" void kernel_launch(void* const* d_in, const int* in_sizes, int n_in,
                              void* d_out, int out_size, void* d_ws, size_t ws_size,
                              hipStream_t stream)
{
    const float* x       = (const float*)d_in[0];
    const float* W_up    = (const float*)d_in[1];
    const float* W_gate  = (const float*)d_in[2];
    const float* W_down  = (const float*)d_in[3];
    const float* W_pre   = (const float*)d_in[4];
    const float* W_post  = (const float*)d_in[5];
    const float* ln_g    = (const float*)d_in[6];
    const float* ln_b    = (const float*)d_in[7];
    const float* W_aproj = (const float*)d_in[8];
    const float* A_exp   = (const float*)d_in[9];
    const float* ln_g_e  = (const float*)d_in[10];
    const float* ln_b_e  = (const float*)d_in[11];
    const float* W_eproj = (const float*)d_in[12];
    const float* W_oproj = (const float*)d_in[13];
    const float* W_rg    = (const float*)d_in[14];
    const float* W_re    = (const float*)d_in[15];

    float* out = (float*)d_out;

    // ---- workspace carve ----
    char* p = (char*)d_ws;
    auto alloc = [&](size_t bytes) { void* r = (void*)p; p += (bytes + 255) & ~(size_t)255; return r; };
    float* pre      = (float*)alloc((size_t)Nc * Ac * 4);
    float* postbuf  = (float*)alloc((size_t)Nc * Ac * 4);
    float* h_dense  = (float*)alloc((size_t)Ec * Nc * Ac * 4);   // 16.8 MB
    float* rpart    = (float*)alloc((size_t)RBLK * 10 * 4);
    float* fw       = (float*)alloc((size_t)Nc * 2 * 4);
    float* dmsum    = (float*)alloc((size_t)Nc * 4);
    int*   eidx     = (int*)alloc((size_t)Nc * 2 * 4);
    unsigned short* xb      = (unsigned short*)alloc((size_t)Nc * Dc * 2);
    unsigned short* Wcat_b  = (unsigned short*)alloc((size_t)2 * Hc * Dc * 2); // interleaved gate/up
    unsigned short* Wd_b    = (unsigned short*)alloc((size_t)Dc * Hc * 2);
    unsigned short* Wop_b   = (unsigned short*)alloc((size_t)Dc * Hc * 2);     // adjacent to Wd_b
    unsigned short* Wpre_b  = (unsigned short*)alloc((size_t)Ac * Dc * 2);
    unsigned short* Wpost_b = (unsigned short*)alloc((size_t)Ac * Hc * 2);
    unsigned short* WapT_b  = (unsigned short*)alloc((size_t)Ac * Hc * 2);
    unsigned short* WepT_b  = (unsigned short*)alloc((size_t)Ac * Hc * 2);     // adjacent to WapT_b
    unsigned short* Wdap_b  = (unsigned short*)alloc((size_t)Dc * Ac * 2);
    unsigned short* Wopep_b = (unsigned short*)alloc((size_t)Dc * Ac * 2);     // adjacent to Wdap_b
    unsigned short* Aexp_b  = (unsigned short*)alloc((size_t)Ec * Ac * Ac * 2);
    unsigned short* pre_b   = (unsigned short*)alloc((size_t)Nc * Ac * 2);
    unsigned short* hidden  = (unsigned short*)alloc((size_t)Nc * Hc * 2);
    unsigned short* awbuf   = (unsigned short*)alloc((size_t)Nc * Hc * 2);     // aw [2,2048,2048]
    unsigned short* adapt_in  = (unsigned short*)alloc((size_t)Nc * Ac * 2);
    unsigned short* adapt_inT = (unsigned short*)alloc((size_t)Nc * Ac * 2);
    unsigned short* adapt_out = (unsigned short*)alloc((size_t)Nc * Ac * 2);
    unsigned short* adaptb    = (unsigned short*)alloc((size_t)Nc * Ac * 2);
    unsigned short* h2        = (unsigned short*)alloc((size_t)Nc * Ac * 2);

    // ---- weight prep ----
    CastJobs jobs;
    jobs.src[0] = x;       jobs.dst[0] = xb;      jobs.n4[0] = Nc * Dc / 4;
    jobs.src[1] = W_down;  jobs.dst[1] = Wd_b;    jobs.n4[1] = Dc * Hc / 4;
    jobs.src[2] = W_oproj; jobs.dst[2] = Wop_b;   jobs.n4[2] = Dc * Hc / 4;
    jobs.src[3] = W_pre;   jobs.dst[3] = Wpre_b;  jobs.n4[3] = Ac * Dc / 4;
    jobs.src[4] = W_post;  jobs.dst[4] = Wpost_b; jobs.n4[4] = Ac * Hc / 4;
    jobs.src[5] = A_exp;   jobs.dst[5] = Aexp_b;  jobs.n4[5] = Ec * Ac * Ac / 4;
    cast_k<<<dim3(128, 6), 256, 0, stream>>>(jobs);
    gucast_k<<<2 * Hc, 256, 0, stream>>>(W_gate, W_up, Wcat_b);
    ct_k<<<dim3(Hc / 64, Ac / 64, 2), 256, 0, stream>>>(W_aproj, W_eproj, WapT_b, WepT_b);

    // Wdap = 0.1*(Wd @ Wap), Wopep = 0.1*(Wop @ Wep)  [1024,128] bf16, z batched
    mgemm<8><<<dim3(1, Dc / 128, 2), 256, 0, stream>>>(Wd_b, WapT_b, Wdap_b, Ac, Hc, 0.1f, nullptr,
        (long long)Dc * Hc, (long long)Ac * Hc, (long long)Dc * Ac);

    // ---- router (atomic-free) ----
    router_k<<<RBLK, 256, 0, stream>>>(x, W_rg, W_re, eidx, fw, dmsum, rpart);
    loss_k<<<1, 512, 0, stream>>>(rpart, out + (size_t)Nc * Dc);

    // ---- pre (f32 + bf16) / adapt_in ----
    mgemm<7><<<dim3(1, 32), 256, 0, stream>>>(xb, Wpre_b, pre, Ac, Dc, 0.f, (const float*)pre_b, 0, 0, 0);
    ln_k<<<Nc, 64, 0, stream>>>(pre, adapt_in, ln_g, ln_b);
    trans_k<<<dim3(Sc / 64, Ac / 64, Bc), 256, 0, stream>>>(adapt_in, adapt_inT);

    // ---- fused gate+up -> hidden = silu(gate)*up ----
    mgemm<9><<<dim3(32, 32), 256, 0, stream>>>(xb, Wcat_b, hidden, 2 * Hc, Dc, 0.f, nullptr, 0, 0, 0);

    // ---- post / adapt_out ----
    mgemm<0><<<dim3(1, 32), 256, 0, stream>>>(hidden, Wpost_b, postbuf, Ac, Hc, 0.f, nullptr, 0, 0, 0);
    ln_k<<<Nc, 64, 0, stream>>>(postbuf, adapt_out, ln_g, ln_b);

    // ---- dense expert adapter: h_dense[e] = pre_b @ A_exp[e]^T ----
    mgemm<0><<<dim3(1, 32, Ec), 256, 0, stream>>>(pre_b, Aexp_b, h_dense, Ac, Ac, 0.f, nullptr,
        0, (long long)Ac * Ac, (long long)Nc * Ac);
    combine_k<<<Nc, 128, 0, stream>>>(h_dense, ln_g_e, ln_b_e, eidx, fw, h2);

    // ---- aw = silu(clip(adapt_in @ adapt_out^T)) per batch ----
    mgemm<2><<<dim3(16, 16, Bc), 256, 0, stream>>>(adapt_in, adapt_out, awbuf, Sc, Ac, 0.f, nullptr,
        (long long)Sc * Ac, (long long)Sc * Ac, (long long)Sc * Sc);

    // ---- adapt = aw @ adapt_in  (B^T form via adapt_inT) ----
    mgemm<1><<<dim3(1, 16, Bc), 256, 0, stream>>>(awbuf, adapt_inT, adaptb, Ac, Sc, 0.f, nullptr,
        (long long)Sc * Sc, (long long)Ac * Sc, (long long)Sc * Ac);

    // ---- final fused: out = dmsum*(hidden@Wd^T + adaptb@Wdap^T) + h2@Wopep^T ----
    final_k<<<dim3(Dc / 128, Nc / 128), 256, 0, stream>>>(
        hidden, Wd_b, adaptb, Wdap_b, h2, Wopep_b, dmsum, out);
}

// Round 6
// 251.058 us; speedup vs baseline: 6.4116x; 1.2024x over previous
//
#include <hip/hip_runtime.h>
#include <hip/hip_bf16.h>
#include <math.h>

static constexpr int Bc = 2;
static constexpr int Sc = 2048;
static constexpr int Dc = 1024;
static constexpr int Hc = 2048;
static constexpr int Ac = 128;
static constexpr int Ec = 8;
static constexpr int GSc = 4;
static constexpr int Gc = 2;
static constexpr int Nc = Bc * Sc;   // 4096 tokens
static constexpr float LN_EPSc = 1e-5f;
static constexpr int RBLK = 512;     // router blocks

typedef __attribute__((ext_vector_type(8))) short bf16x8;
typedef __attribute__((ext_vector_type(4))) float f32x4;
typedef __attribute__((ext_vector_type(4))) unsigned short us4;

__device__ __forceinline__ unsigned short f2b(float f) {
    union { float f; unsigned u; } v; v.f = f;
    return (unsigned short)((v.u + 0x7FFFu + ((v.u >> 16) & 1u)) >> 16);
}
__device__ __forceinline__ float b2f(unsigned short h) {
    union { unsigned u; float f; } v; v.u = (unsigned)h << 16; return v.f;
}

#define GLOAD16(g, l) __builtin_amdgcn_global_load_lds( \
    (const __attribute__((address_space(1))) void*)(g), \
    (__attribute__((address_space(3))) void*)(l), 16, 0, 0)

// ---------------- bf16 MFMA GEMM, 128x128 tile: C[M,N] = A[M,K] @ B[N,K]^T ----
// EPI: 0=store f32, 1=store bf16, 2=silu(clip(v)) bf16, 8=bf16 alpha*v,
//      9=gateup paired silu + pre side-channel (aux=pre f32, aux2=pre_b bf16)
template<int EPI>
__global__ __launch_bounds__(256, 2) void mgemm(
    const unsigned short* __restrict__ Ag, const unsigned short* __restrict__ Bg,
    void* __restrict__ Cg, int N, int K, int lda, int ldb, float alpha,
    float* __restrict__ aux, void* __restrict__ aux2,
    long long sA, long long sB, long long sC)
{
    __shared__ unsigned short As[128 * 32];
    __shared__ unsigned short Bs[128 * 32];
    const unsigned short* A = Ag + (long long)blockIdx.z * sA;
    const unsigned short* B = Bg + (long long)blockIdx.z * sB;
    float* fC = (float*)Cg + (long long)blockIdx.z * sC;
    unsigned short* usC = (unsigned short*)Cg + (long long)blockIdx.z * sC;

    const int nwg = gridDim.x * gridDim.y;
    const int flat = blockIdx.y * gridDim.x + blockIdx.x;
    const int swz = (flat & 7) * (nwg >> 3) + (flat >> 3);
    const int bx = swz % gridDim.x, by = swz / gridDim.x;
    const int bm = by * 128, bn = bx * 128;

    const int tid = threadIdx.x;
    const int w = tid >> 6, l = tid & 63;
    const int wm = (w >> 1) * 64, wn = (w & 1) * 64;
    const int fr = l & 15, g = l >> 4;

    const f32x4 zero = { 0.f, 0.f, 0.f, 0.f };
    f32x4 acc[4][4];
    #pragma unroll
    for (int i = 0; i < 4; ++i)
        #pragma unroll
        for (int j = 0; j < 4; ++j) acc[i][j] = zero;

    for (int k0 = 0; k0 < K; k0 += 32) {
        #pragma unroll
        for (int p = 0; p < 2; ++p) {
            const int c = p * 256 + tid;
            GLOAD16(A + (long long)(bm + (c >> 2)) * lda + k0 + (c & 3) * 8, &As[c * 8]);
            GLOAD16(B + (long long)(bn + (c >> 2)) * ldb + k0 + (c & 3) * 8, &Bs[c * 8]);
        }
        __syncthreads();
        bf16x8 af[4], bfv[4];
        #pragma unroll
        for (int i = 0; i < 4; ++i) {
            af[i]  = *(const bf16x8*)&As[(wm + i * 16 + fr) * 32 + g * 8];
            bfv[i] = *(const bf16x8*)&Bs[(wn + i * 16 + fr) * 32 + g * 8];
        }
        #pragma unroll
        for (int i = 0; i < 4; ++i)
            #pragma unroll
            for (int j = 0; j < 4; ++j)
                acc[i][j] = __builtin_amdgcn_mfma_f32_16x16x32_bf16(af[i], bfv[j], acc[i][j], 0, 0, 0);
        __syncthreads();
    }

    if (EPI == 9) {
        if (bn < 2 * Hc) {
            // paired gate/up: even frag = gate, odd frag = up
            #pragma unroll
            for (int mi = 0; mi < 4; ++mi) {
                #pragma unroll
                for (int j = 0; j < 2; ++j) {
                    #pragma unroll
                    for (int jr = 0; jr < 4; ++jr) {
                        const long long row = bm + wm + mi * 16 + g * 4 + jr;
                        const long long colh = ((bn + wn) >> 1) + j * 16 + fr;
                        const float gv = acc[mi][2 * j][jr];
                        const float uv = acc[mi][2 * j + 1][jr];
                        usC[row * Hc + colh] = f2b(gv / (1.f + expf(-gv)) * uv);
                    }
                }
            }
        } else {
            // pre tile: cols 4096..4223 -> pre (f32) + pre_b (bf16)
            unsigned short* preb = (unsigned short*)aux2;
            #pragma unroll
            for (int mi = 0; mi < 4; ++mi) {
                #pragma unroll
                for (int ni = 0; ni < 4; ++ni) {
                    #pragma unroll
                    for (int jr = 0; jr < 4; ++jr) {
                        const long long row = bm + wm + mi * 16 + g * 4 + jr;
                        const int lc = wn + ni * 16 + fr;
                        const float v = acc[mi][ni][jr];
                        aux[row * Ac + lc] = v;
                        preb[row * Ac + lc] = f2b(v);
                    }
                }
            }
        }
    } else {
        #pragma unroll
        for (int mi = 0; mi < 4; ++mi) {
            #pragma unroll
            for (int ni = 0; ni < 4; ++ni) {
                #pragma unroll
                for (int jr = 0; jr < 4; ++jr) {
                    const long long row = bm + wm + mi * 16 + g * 4 + jr;
                    const long long col = bn + wn + ni * 16 + fr;
                    const long long idx = row * (long long)N + col;
                    float v = acc[mi][ni][jr];
                    if (EPI == 0) {
                        fC[idx] = v;
                    } else if (EPI == 1) {
                        usC[idx] = f2b(v);
                    } else if (EPI == 2) {
                        v = fminf(fmaxf(v, -5.f), 5.f);
                        usC[idx] = f2b(v / (1.f + expf(-v)));
                    } else if (EPI == 8) {
                        usC[idx] = f2b(alpha * v);
                    }
                }
            }
        }
    }
}

// ---------------- bf16 MFMA GEMM, 128x64 tile (f32 out) ----------------
// 4 waves (2x2), each wave 64x32 = 4x2 frags. For skinny-N / split-K work.
__global__ __launch_bounds__(256, 2) void mgemm64(
    const unsigned short* __restrict__ Ag, const unsigned short* __restrict__ Bg,
    float* __restrict__ Cg, int N, int K, int lda, int ldb,
    long long sA, long long sB, long long sC)
{
    __shared__ unsigned short As[128 * 32];
    __shared__ unsigned short Bs[64 * 32];
    const unsigned short* A = Ag + (long long)blockIdx.z * sA;
    const unsigned short* B = Bg + (long long)blockIdx.z * sB;
    float* fC = Cg + (long long)blockIdx.z * sC;

    const int nwg = gridDim.x * gridDim.y;
    const int flat = blockIdx.y * gridDim.x + blockIdx.x;
    const int swz = (flat & 7) * (nwg >> 3) + (flat >> 3);
    const int bx = swz % gridDim.x, by = swz / gridDim.x;
    const int bm = by * 128, bn = bx * 64;

    const int tid = threadIdx.x;
    const int w = tid >> 6, l = tid & 63;
    const int wm = (w >> 1) * 64, wn = (w & 1) * 32;
    const int fr = l & 15, g = l >> 4;

    const f32x4 zero = { 0.f, 0.f, 0.f, 0.f };
    f32x4 acc[4][2];
    #pragma unroll
    for (int i = 0; i < 4; ++i)
        #pragma unroll
        for (int j = 0; j < 2; ++j) acc[i][j] = zero;

    for (int k0 = 0; k0 < K; k0 += 32) {
        #pragma unroll
        for (int p = 0; p < 2; ++p) {
            const int c = p * 256 + tid;
            GLOAD16(A + (long long)(bm + (c >> 2)) * lda + k0 + (c & 3) * 8, &As[c * 8]);
        }
        GLOAD16(B + (long long)(bn + (tid >> 2)) * ldb + k0 + (tid & 3) * 8, &Bs[tid * 8]);
        __syncthreads();
        bf16x8 af[4], bfv[2];
        #pragma unroll
        for (int i = 0; i < 4; ++i)
            af[i]  = *(const bf16x8*)&As[(wm + i * 16 + fr) * 32 + g * 8];
        #pragma unroll
        for (int j = 0; j < 2; ++j)
            bfv[j] = *(const bf16x8*)&Bs[(wn + j * 16 + fr) * 32 + g * 8];
        #pragma unroll
        for (int i = 0; i < 4; ++i)
            #pragma unroll
            for (int j = 0; j < 2; ++j)
                acc[i][j] = __builtin_amdgcn_mfma_f32_16x16x32_bf16(af[i], bfv[j], acc[i][j], 0, 0, 0);
        __syncthreads();
    }

    #pragma unroll
    for (int mi = 0; mi < 4; ++mi)
        #pragma unroll
        for (int ni = 0; ni < 2; ++ni)
            #pragma unroll
            for (int jr = 0; jr < 4; ++jr) {
                const long long row = bm + wm + mi * 16 + g * 4 + jr;
                const long long col = bn + wn + ni * 16 + fr;
                fC[row * (long long)N + col] = acc[mi][ni][jr];
            }
}

// ---------------- final fused 3-phase GEMM, 128x64 tile ----------------
// out[4096,1024] = dmsum[row]*(hidden@Wd^T + adaptb@Wdap^T) + h2@Wopep^T
__global__ __launch_bounds__(256, 2) void final_k(
    const unsigned short* __restrict__ hidden, const unsigned short* __restrict__ Wd,
    const unsigned short* __restrict__ adaptb, const unsigned short* __restrict__ Wdap,
    const unsigned short* __restrict__ h2v, const unsigned short* __restrict__ Wopep,
    const float* __restrict__ dmsum, float* __restrict__ out)
{
    __shared__ unsigned short As[128 * 32];
    __shared__ unsigned short Bs[64 * 32];

    const int nwg = gridDim.x * gridDim.y;
    const int flat = blockIdx.y * gridDim.x + blockIdx.x;
    const int swz = (flat & 7) * (nwg >> 3) + (flat >> 3);
    const int bx = swz % gridDim.x, by = swz / gridDim.x;
    const int bm = by * 128, bn = bx * 64;

    const int tid = threadIdx.x;
    const int w = tid >> 6, l = tid & 63;
    const int wm = (w >> 1) * 64, wn = (w & 1) * 32;
    const int fr = l & 15, g = l >> 4;

    const f32x4 zero = { 0.f, 0.f, 0.f, 0.f };
    f32x4 acc[4][2];
    #pragma unroll
    for (int i = 0; i < 4; ++i)
        #pragma unroll
        for (int j = 0; j < 2; ++j) acc[i][j] = zero;

    const unsigned short* Ap[3] = { hidden, adaptb, h2v };
    const unsigned short* Bp[3] = { Wd, Wdap, Wopep };
    const int Ks[3]  = { Hc, Ac, Ac };
    const int lds[3] = { Hc, Ac, Ac };

    #pragma unroll 1
    for (int ph = 0; ph < 3; ++ph) {
        if (ph == 2) {
            // scale accumulated (hidden@Wd + adapt@Wdap) by dmsum[row]
            #pragma unroll
            for (int mi = 0; mi < 4; ++mi)
                #pragma unroll
                for (int jr = 0; jr < 4; ++jr) {
                    const float rs = dmsum[bm + wm + mi * 16 + g * 4 + jr];
                    #pragma unroll
                    for (int ni = 0; ni < 2; ++ni) acc[mi][ni][jr] *= rs;
                }
        }
        const unsigned short* A = Ap[ph];
        const unsigned short* B = Bp[ph];
        const int K = Ks[ph], ld = lds[ph];
        for (int k0 = 0; k0 < K; k0 += 32) {
            #pragma unroll
            for (int p = 0; p < 2; ++p) {
                const int c = p * 256 + tid;
                GLOAD16(A + (long long)(bm + (c >> 2)) * ld + k0 + (c & 3) * 8, &As[c * 8]);
            }
            GLOAD16(B + (long long)(bn + (tid >> 2)) * ld + k0 + (tid & 3) * 8, &Bs[tid * 8]);
            __syncthreads();
            bf16x8 af[4], bfv[2];
            #pragma unroll
            for (int i = 0; i < 4; ++i)
                af[i]  = *(const bf16x8*)&As[(wm + i * 16 + fr) * 32 + g * 8];
            #pragma unroll
            for (int j = 0; j < 2; ++j)
                bfv[j] = *(const bf16x8*)&Bs[(wn + j * 16 + fr) * 32 + g * 8];
            #pragma unroll
            for (int i = 0; i < 4; ++i)
                #pragma unroll
                for (int j = 0; j < 2; ++j)
                    acc[i][j] = __builtin_amdgcn_mfma_f32_16x16x32_bf16(af[i], bfv[j], acc[i][j], 0, 0, 0);
            __syncthreads();
        }
    }

    #pragma unroll
    for (int mi = 0; mi < 4; ++mi)
        #pragma unroll
        for (int ni = 0; ni < 2; ++ni)
            #pragma unroll
            for (int jr = 0; jr < 4; ++jr) {
                const long long row = bm + wm + mi * 16 + g * 4 + jr;
                const long long col = bn + wn + ni * 16 + fr;
                out[row * (long long)Dc + col] = acc[mi][ni][jr];
            }
}

// ---------------- partial-sum reduce: out = sum_p in[p*stride + i] ----------------
template<int NP, int BF>
__global__ __launch_bounds__(256) void reduce_k(const float* __restrict__ in,
                                                void* __restrict__ outp,
                                                long long pstride, int n4)
{
    for (int i = blockIdx.x * 256 + threadIdx.x; i < n4; i += gridDim.x * 256) {
        float4 s = ((const float4*)in)[i];
        #pragma unroll
        for (int p = 1; p < NP; ++p) {
            const float4 v = ((const float4*)(in + (long long)p * pstride))[i];
            s.x += v.x; s.y += v.y; s.z += v.z; s.w += v.w;
        }
        if (BF) {
            us4 o = { f2b(s.x), f2b(s.y), f2b(s.z), f2b(s.w) };
            ((us4*)outp)[i] = o;
        } else {
            ((float4*)outp)[i] = s;
        }
    }
}

// ---------------- fp32 -> bf16 casts (batched) ----------------
struct CastJobs {
    const float* src[5];
    unsigned short* dst[5];
    int n4[5];
};
__global__ __launch_bounds__(256) void cast_k(CastJobs jobs) {
    const int b = blockIdx.y;
    const float4* s = (const float4*)jobs.src[b];
    us4* d = (us4*)jobs.dst[b];
    const int n = jobs.n4[b];
    for (int i = blockIdx.x * 256 + threadIdx.x; i < n; i += gridDim.x * 256) {
        const float4 v = s[i];
        us4 o;
        o.x = f2b(v.x); o.y = f2b(v.y); o.z = f2b(v.z); o.w = f2b(v.w);
        d[i] = o;
    }
}

// ---------------- gate/up interleaved + pre appended: Wcat[4224,1024] bf16 ----
__global__ __launch_bounds__(256) void gucast_k(const float* __restrict__ Wg,
                                                const float* __restrict__ Wu,
                                                const float* __restrict__ Wpre,
                                                unsigned short* __restrict__ Wcat)
{
    const int r = blockIdx.x;
    const float* src;
    int srcrow;
    if (r < 2 * Hc) {
        const int b = r >> 5, w = r & 31;
        src = (w < 16) ? Wg : Wu;
        srcrow = b * 16 + (w & 15);
    } else {
        src = Wpre;
        srcrow = r - 2 * Hc;
    }
    const float4 v = ((const float4*)(src + (long long)srcrow * Dc))[threadIdx.x];
    us4 o;
    o.x = f2b(v.x); o.y = f2b(v.y); o.z = f2b(v.z); o.w = f2b(v.w);
    ((us4*)(Wcat + (long long)r * Dc))[threadIdx.x] = o;
}

// ---------------- cast-transpose: f32 [2048,128] -> bf16 [128,2048], z=0/1 ----
__global__ __launch_bounds__(256) void ct_k(const float* __restrict__ in0,
                                            const float* __restrict__ in1,
                                            unsigned short* __restrict__ out0,
                                            unsigned short* __restrict__ out1)
{
    const float* in = blockIdx.z ? in1 : in0;
    unsigned short* out = blockIdx.z ? out1 : out0;
    const int t0 = blockIdx.x * 64, a0 = blockIdx.y * 64;
    __shared__ float T[64][68];
    const int rr = threadIdx.x >> 4, cc = (threadIdx.x & 15) * 4;
    #pragma unroll
    for (int p = 0; p < 4; ++p) {
        const int row = p * 16 + rr;
        *(float4*)&T[row][cc] = *(const float4*)&in[(long long)(t0 + row) * Ac + a0 + cc];
    }
    __syncthreads();
    #pragma unroll
    for (int p = 0; p < 4; ++p) {
        const int ar = p * 16 + rr;
        us4 o;
        o.x = f2b(T[cc + 0][ar]); o.y = f2b(T[cc + 1][ar]);
        o.z = f2b(T[cc + 2][ar]); o.w = f2b(T[cc + 3][ar]);
        *(us4*)&out[(long long)(a0 + ar) * Hc + t0 + cc] = o;
    }
}

// ---------------- LayerNorm over 128, one wave per row, bf16 out ----------------
__global__ __launch_bounds__(64) void ln_k(const float* __restrict__ in, unsigned short* __restrict__ out,
                                           const float* __restrict__ gg, const float* __restrict__ bb)
{
    const int row = blockIdx.x;
    const int lane = threadIdx.x;
    const float z0 = in[(long long)row * 128 + lane];
    const float z1 = in[(long long)row * 128 + 64 + lane];
    float s = z0 + z1;
    for (int o = 32; o > 0; o >>= 1) s += __shfl_down(s, o, 64);
    s = __shfl(s, 0, 64);
    const float mu = s * (1.f / 128.f);
    const float d0 = z0 - mu, d1 = z1 - mu;
    float v = d0 * d0 + d1 * d1;
    for (int o = 32; o > 0; o >>= 1) v += __shfl_down(v, o, 64);
    v = __shfl(v, 0, 64);
    const float r = rsqrtf(v * (1.f / 128.f) + LN_EPSc);
    out[(long long)row * 128 + lane] = f2b(d0 * r * gg[lane] + bb[lane]);
    out[(long long)row * 128 + 64 + lane] = f2b(d1 * r * gg[lane + 64] + bb[lane + 64]);
}

// ---------------- transpose per batch: [2048,128] -> [128,2048] bf16 ----------------
__global__ __launch_bounds__(256) void trans_k(const unsigned short* __restrict__ in,
                                               unsigned short* __restrict__ out)
{
    const int z = blockIdx.z;
    const int t0 = blockIdx.x * 64, a0 = blockIdx.y * 64;
    __shared__ unsigned short T[64][72];
    const unsigned short* ip = in + (long long)z * Sc * Ac;
    unsigned short* op = out + (long long)z * Ac * Sc;
    const int rr = threadIdx.x >> 4, cc = (threadIdx.x & 15) * 4;
    #pragma unroll
    for (int p = 0; p < 4; ++p) {
        const int row = p * 16 + rr;
        *(us4*)&T[row][cc] = *(const us4*)&ip[(long long)(t0 + row) * Ac + a0 + cc];
    }
    __syncthreads();
    #pragma unroll
    for (int p = 0; p < 4; ++p) {
        const int arow = p * 16 + rr;
        us4 o;
        o.x = T[cc + 0][arow]; o.y = T[cc + 1][arow];
        o.z = T[cc + 2][arow]; o.w = T[cc + 3][arow];
        *(us4*)&op[(long long)(a0 + arow) * Sc + t0 + cc] = o;
    }
}

// ---------------- router: 512 blocks x 256 threads, NO global atomics ----------------
__global__ __launch_bounds__(256) void router_k(const float* __restrict__ x,
                                                const float* __restrict__ W_rg,
                                                const float* __restrict__ W_re,
                                                int* __restrict__ eidx, float* __restrict__ fw,
                                                float* __restrict__ dmsum,
                                                float* __restrict__ rpart)
{
    const int wv = threadIdx.x >> 6;
    const int lane = threadIdx.x & 63;
    float load8[8] = {0.f, 0.f, 0.f, 0.f, 0.f, 0.f, 0.f, 0.f};
    float sqg = 0.f, sqe = 0.f;

    #pragma unroll
    for (int it = 0; it < 2; ++it) {
        const int t = blockIdx.x * 8 + wv * 2 + it;
        const float* xr = x + (long long)t * Dc;
        float a0 = 0, a1 = 0, a2 = 0, a3 = 0, a4 = 0, a5 = 0;
        #pragma unroll
        for (int j = 0; j < 16; ++j) {
            const int d = lane + 64 * j;
            const float xv = xr[d];
            a0 += xv * W_rg[d];          a1 += xv * W_rg[Dc + d];
            a2 += xv * W_re[d];          a3 += xv * W_re[Dc + d];
            a4 += xv * W_re[2 * Dc + d]; a5 += xv * W_re[3 * Dc + d];
        }
        #pragma unroll
        for (int o = 32; o > 0; o >>= 1) {
            a0 += __shfl_xor(a0, o, 64); a1 += __shfl_xor(a1, o, 64);
            a2 += __shfl_xor(a2, o, 64); a3 += __shfl_xor(a3, o, 64);
            a4 += __shfl_xor(a4, o, 64); a5 += __shfl_xor(a5, o, 64);
        }
        if (lane == 0) {
            const float gl0 = a0, gl1 = a1;
            const float m = fmaxf(gl0, gl1);
            const float e0 = expf(gl0 - m), e1 = expf(gl1 - m);
            const float inv = 1.f / (e0 + e1);
            const float gp0 = e0 * inv, gp1 = e1 * inv;
            const int gidx = (gl1 > gl0) ? 1 : 0;
            const float gw = fmaxf(gp0, gp1);
            float el[4] = { a2, a3, a4, a5 };
            const float me = fmaxf(fmaxf(el[0], el[1]), fmaxf(el[2], el[3]));
            float ep[4]; float se = 0.f;
            #pragma unroll
            for (int i = 0; i < 4; ++i) { ep[i] = expf(el[i] - me); se += ep[i]; }
            const float invs = 1.f / se;
            #pragma unroll
            for (int i = 0; i < 4; ++i) ep[i] *= invs;
            int i0 = 0;
            #pragma unroll
            for (int i = 1; i < 4; ++i) if (ep[i] > ep[i0]) i0 = i;
            int i1 = -1;
            #pragma unroll
            for (int i = 0; i < 4; ++i) { if (i == i0) continue; if (i1 < 0 || ep[i] > ep[i1]) i1 = i; }
            const float w0 = ep[i0], w1 = ep[i1];
            const float sn = w0 + w1 + 1e-7f;
            const float f0 = gw * w0 / sn, f1 = gw * w1 / sn;
            const int ei0 = gidx * GSc + i0, ei1 = gidx * GSc + i1;
            eidx[t * 2] = ei0; eidx[t * 2 + 1] = ei1;
            fw[t * 2] = f0; fw[t * 2 + 1] = f1;
            dmsum[t] = f0 + f1;
            #pragma unroll
            for (int e = 0; e < 8; ++e)
                load8[e] += ((e == ei0) ? f0 : 0.f) + ((e == ei1) ? f1 : 0.f);
            sqg += gl0 * gl0 + gl1 * gl1;
            sqe += el[0] * el[0] + el[1] * el[1] + el[2] * el[2] + el[3] * el[3];
        }
    }
    __shared__ float sh[4][10];
    if (lane == 0) {
        #pragma unroll
        for (int e = 0; e < 8; ++e) sh[wv][e] = load8[e];
        sh[wv][8] = sqg; sh[wv][9] = sqe;
    }
    __syncthreads();
    if (threadIdx.x < 10) {
        rpart[blockIdx.x * 10 + threadIdx.x] =
            sh[0][threadIdx.x] + sh[1][threadIdx.x] + sh[2][threadIdx.x] + sh[3][threadIdx.x];
    }
}

// ---------------- loss reduce over RBLK partial rows ----------------
__global__ __launch_bounds__(512) void loss_k(const float* __restrict__ rpart,
                                              float* __restrict__ out_loss)
{
    const int tid = threadIdx.x;
    const int lane = tid & 63, wv = tid >> 6;
    float v[10];
    #pragma unroll
    for (int c = 0; c < 10; ++c) v[c] = rpart[tid * 10 + c];
    #pragma unroll
    for (int o = 32; o > 0; o >>= 1)
        #pragma unroll
        for (int c = 0; c < 10; ++c) v[c] += __shfl_xor(v[c], o, 64);
    __shared__ float sh[8][10];
    if (lane == 0) {
        #pragma unroll
        for (int c = 0; c < 10; ++c) sh[wv][c] = v[c];
    }
    __syncthreads();
    if (tid == 0) {
        float load[8]; float sqg = 0.f, sqe = 0.f;
        #pragma unroll
        for (int e = 0; e < 8; ++e) load[e] = 0.f;
        for (int wvi = 0; wvi < 8; ++wvi) {
            #pragma unroll
            for (int e = 0; e < 8; ++e) load[e] += sh[wvi][e];
            sqg += sh[wvi][8]; sqe += sh[wvi][9];
        }
        float s = 0.f;
        for (int e = 0; e < Ec; ++e) s += load[e];
        const float tgt = s / (float)Ec;
        float var = 0.f;
        for (int e = 0; e < Ec; ++e) { const float d = load[e] - tgt; var += d * d; }
        var /= (float)Ec;
        const float l = var + sqg / (float)(Nc * Gc) + sqe / (float)(Nc * GSc);
        *out_loss = 0.001f * l;
    }
}

// ---------------- combine: h2[t] = sum_slot fw * LN_e(h_dense[e][t]) ----------------
__global__ __launch_bounds__(128) void combine_k(const float* __restrict__ h_dense,
                                                 const float* __restrict__ ln_g_e,
                                                 const float* __restrict__ ln_b_e,
                                                 const int* __restrict__ eidx,
                                                 const float* __restrict__ fw,
                                                 unsigned short* __restrict__ h2)
{
    const int t = blockIdx.x;
    const int tid = threadIdx.x;
    __shared__ float red[2];

    float acc = 0.f;
    #pragma unroll
    for (int slot = 0; slot < 2; ++slot) {
        const int e = eidx[t * 2 + slot];
        const float w = fw[t * 2 + slot];
        const float h = h_dense[((long long)e * Nc + t) * 128 + tid];
        float v = h;
        for (int o = 32; o > 0; o >>= 1) v += __shfl_down(v, o, 64);
        if ((tid & 63) == 0) red[tid >> 6] = v;
        __syncthreads();
        const float mu = (red[0] + red[1]) * (1.f / 128.f);
        __syncthreads();
        const float d = h - mu;
        v = d * d;
        for (int o = 32; o > 0; o >>= 1) v += __shfl_down(v, o, 64);
        if ((tid & 63) == 0) red[tid >> 6] = v;
        __syncthreads();
        const float var = (red[0] + red[1]) * (1.f / 128.f);
        __syncthreads();
        acc += w * (d * rsqrtf(var + LN_EPSc) * ln_g_e[e * 128 + tid] + ln_b_e[e * 128 + tid]);
    }
    h2[(long long)t * 128 + tid] = f2b(acc);
}

// =====================================================================
extern "C" void kernel_launch(void* const* d_in, const int* in_sizes, int n_in,
                              void* d_out, int out_size, void* d_ws, size_t ws_size,
                              hipStream_t stream)
{
    const float* x       = (const float*)d_in[0];
    const float* W_up    = (const float*)d_in[1];
    const float* W_gate  = (const float*)d_in[2];
    const float* W_down  = (const float*)d_in[3];
    const float* W_pre   = (const float*)d_in[4];
    const float* W_post  = (const float*)d_in[5];
    const float* ln_g    = (const float*)d_in[6];
    const float* ln_b    = (const float*)d_in[7];
    const float* W_aproj = (const float*)d_in[8];
    const float* A_exp   = (const float*)d_in[9];
    const float* ln_g_e  = (const float*)d_in[10];
    const float* ln_b_e  = (const float*)d_in[11];
    const float* W_eproj = (const float*)d_in[12];
    const float* W_oproj = (const float*)d_in[13];
    const float* W_rg    = (const float*)d_in[14];
    const float* W_re    = (const float*)d_in[15];

    float* out = (float*)d_out;

    // ---- workspace carve ----
    char* p = (char*)d_ws;
    auto alloc = [&](size_t bytes) { void* r = (void*)p; p += (bytes + 255) & ~(size_t)255; return r; };
    float* pre      = (float*)alloc((size_t)Nc * Ac * 4);
    float* postbuf  = (float*)alloc((size_t)Nc * Ac * 4);
    float* h_dense  = (float*)alloc((size_t)Ec * Nc * Ac * 4);   // 16.8 MB; also hosts postP / adaptP
    float* rpart    = (float*)alloc((size_t)RBLK * 10 * 4);
    float* fw       = (float*)alloc((size_t)Nc * 2 * 4);
    float* dmsum    = (float*)alloc((size_t)Nc * 4);
    int*   eidx     = (int*)alloc((size_t)Nc * 2 * 4);
    unsigned short* xb      = (unsigned short*)alloc((size_t)Nc * Dc * 2);
    unsigned short* Wcat_b  = (unsigned short*)alloc((size_t)(2 * Hc + Ac) * Dc * 2); // gate/up interleaved + pre
    unsigned short* Wd_b    = (unsigned short*)alloc((size_t)Dc * Hc * 2);
    unsigned short* Wop_b   = (unsigned short*)alloc((size_t)Dc * Hc * 2);     // adjacent to Wd_b
    unsigned short* Wpost_b = (unsigned short*)alloc((size_t)Ac * Hc * 2);
    unsigned short* WapT_b  = (unsigned short*)alloc((size_t)Ac * Hc * 2);
    unsigned short* WepT_b  = (unsigned short*)alloc((size_t)Ac * Hc * 2);     // adjacent to WapT_b
    unsigned short* Wdap_b  = (unsigned short*)alloc((size_t)Dc * Ac * 2);
    unsigned short* Wopep_b = (unsigned short*)alloc((size_t)Dc * Ac * 2);     // adjacent to Wdap_b
    unsigned short* Aexp_b  = (unsigned short*)alloc((size_t)Ec * Ac * Ac * 2);
    unsigned short* pre_b   = (unsigned short*)alloc((size_t)Nc * Ac * 2);
    unsigned short* hidden  = (unsigned short*)alloc((size_t)Nc * Hc * 2);
    unsigned short* awbuf   = (unsigned short*)alloc((size_t)Nc * Hc * 2);     // aw [2,2048,2048]
    unsigned short* adapt_in  = (unsigned short*)alloc((size_t)Nc * Ac * 2);
    unsigned short* adapt_inT = (unsigned short*)alloc((size_t)Nc * Ac * 2);
    unsigned short* adapt_out = (unsigned short*)alloc((size_t)Nc * Ac * 2);
    unsigned short* adaptb    = (unsigned short*)alloc((size_t)Nc * Ac * 2);
    unsigned short* h2        = (unsigned short*)alloc((size_t)Nc * Ac * 2);

    float* postP  = h_dense;   // [4][4096*128] f32 — dead before h_dense GEMM
    float* adaptP = h_dense;   // [16][2048*128] f32 — h_dense dead after combine

    // ---- weight prep ----
    CastJobs jobs;
    jobs.src[0] = x;       jobs.dst[0] = xb;      jobs.n4[0] = Nc * Dc / 4;
    jobs.src[1] = W_down;  jobs.dst[1] = Wd_b;    jobs.n4[1] = Dc * Hc / 4;
    jobs.src[2] = W_oproj; jobs.dst[2] = Wop_b;   jobs.n4[2] = Dc * Hc / 4;
    jobs.src[3] = W_post;  jobs.dst[3] = Wpost_b; jobs.n4[3] = Ac * Hc / 4;
    jobs.src[4] = A_exp;   jobs.dst[4] = Aexp_b;  jobs.n4[4] = Ec * Ac * Ac / 4;
    cast_k<<<dim3(128, 5), 256, 0, stream>>>(jobs);
    gucast_k<<<2 * Hc + Ac, 256, 0, stream>>>(W_gate, W_up, W_pre, Wcat_b);
    ct_k<<<dim3(Hc / 64, Ac / 64, 2), 256, 0, stream>>>(W_aproj, W_eproj, WapT_b, WepT_b);

    // Wdap = 0.1*(Wd @ Wap), Wopep = 0.1*(Wop @ Wep)  [1024,128] bf16, z batched
    mgemm<8><<<dim3(1, Dc / 128, 2), 256, 0, stream>>>(Wd_b, WapT_b, Wdap_b, Ac, Hc, Hc, Hc, 0.1f,
        nullptr, nullptr, (long long)Dc * Hc, (long long)Ac * Hc, (long long)Dc * Ac);

    // ---- router (atomic-free) ----
    router_k<<<RBLK, 256, 0, stream>>>(x, W_rg, W_re, eidx, fw, dmsum, rpart);
    loss_k<<<1, 512, 0, stream>>>(rpart, out + (size_t)Nc * Dc);

    // ---- fused gate+up+pre: hidden = silu(gate)*up ; pre (f32) + pre_b ----
    mgemm<9><<<dim3(33, 32), 256, 0, stream>>>(xb, Wcat_b, hidden, 2 * Hc + Ac, Dc, Dc, Dc, 0.f,
        pre, pre_b, 0, 0, 0);
    ln_k<<<Nc, 64, 0, stream>>>(pre, adapt_in, ln_g, ln_b);
    trans_k<<<dim3(Sc / 64, Ac / 64, Bc), 256, 0, stream>>>(adapt_in, adapt_inT);

    // ---- post split-K (4x512) -> partials -> postbuf -> adapt_out ----
    mgemm64<<<dim3(2, 32, 4), 256, 0, stream>>>(hidden, Wpost_b, postP, Ac, 512, Hc, Hc,
        512, 512, (long long)Nc * Ac);
    reduce_k<4, 0><<<512, 256, 0, stream>>>(postP, postbuf, (long long)Nc * Ac, Nc * Ac / 4);
    ln_k<<<Nc, 64, 0, stream>>>(postbuf, adapt_out, ln_g, ln_b);

    // ---- dense expert adapter: h_dense[e] = pre_b @ A_exp[e]^T ----
    mgemm64<<<dim3(2, 32, Ec), 256, 0, stream>>>(pre_b, Aexp_b, h_dense, Ac, Ac, Ac, Ac,
        0, (long long)Ac * Ac, (long long)Nc * Ac);
    combine_k<<<Nc, 128, 0, stream>>>(h_dense, ln_g_e, ln_b_e, eidx, fw, h2);

    // ---- aw = silu(clip(adapt_in @ adapt_out^T)) per batch ----
    mgemm<2><<<dim3(16, 16, Bc), 256, 0, stream>>>(adapt_in, adapt_out, awbuf, Sc, Ac, Ac, Ac, 0.f,
        nullptr, nullptr, (long long)Sc * Ac, (long long)Sc * Ac, (long long)Sc * Sc);

    // ---- adapt = aw @ adapt_in, split-K 8x256 per batch -> partials -> adaptb ----
    for (int b = 0; b < Bc; ++b) {
        mgemm64<<<dim3(2, 16, 8), 256, 0, stream>>>(
            awbuf + (size_t)b * Sc * Sc, adapt_inT + (size_t)b * Ac * Sc,
            adaptP + (size_t)b * 8 * Sc * Ac, Ac, 256, Sc, Sc,
            256, 256, (long long)Sc * Ac);
        reduce_k<8, 1><<<256, 256, 0, stream>>>(adaptP + (size_t)b * 8 * Sc * Ac,
            adaptb + (size_t)b * Sc * Ac, (long long)Sc * Ac, Sc * Ac / 4);
    }

    // ---- final fused: out = dmsum*(hidden@Wd^T + adaptb@Wdap^T) + h2@Wopep^T ----
    final_k<<<dim3(Dc / 64, Nc / 128), 256, 0, stream>>>(
        hidden, Wd_b, adaptb, Wdap_b, h2, Wopep_b, dmsum, out);
}

// Round 7
// 237.448 us; speedup vs baseline: 6.7791x; 1.0573x over previous
//
#include <hip/hip_runtime.h>
#include <hip/hip_bf16.h>
#include <math.h>

static constexpr int Bc = 2;
static constexpr int Sc = 2048;
static constexpr int Dc = 1024;
static constexpr int Hc = 2048;
static constexpr int Ac = 128;
static constexpr int Ec = 8;
static constexpr int GSc = 4;
static constexpr int Gc = 2;
static constexpr int Nc = Bc * Sc;   // 4096 tokens
static constexpr float LN_EPSc = 1e-5f;
static constexpr int RBLK = 512;     // router blocks

typedef __attribute__((ext_vector_type(8))) short bf16x8;
typedef __attribute__((ext_vector_type(4))) float f32x4;
typedef __attribute__((ext_vector_type(4))) unsigned short us4;

__device__ __forceinline__ unsigned short f2b(float f) {
    union { float f; unsigned u; } v; v.f = f;
    return (unsigned short)((v.u + 0x7FFFu + ((v.u >> 16) & 1u)) >> 16);
}
__device__ __forceinline__ float b2f(unsigned short h) {
    union { unsigned u; float f; } v; v.u = (unsigned)h << 16; return v.f;
}
__device__ __forceinline__ float fsilu(float x) {
    return x / (1.f + __expf(-x));
}

#define GLOAD16(g, l) __builtin_amdgcn_global_load_lds( \
    (const __attribute__((address_space(1))) void*)(g), \
    (__attribute__((address_space(3))) void*)(l), 16, 0, 0)

// ---------------- bf16 MFMA GEMM, 128x128 tile: C[M,N] = A[M,K] @ B[N,K]^T ----
// EPI: 0=store f32, 1=store bf16, 8=bf16 alpha*v,
//      9=gateup paired silu + pre side-channel (aux=pre f32, aux2=pre_b bf16)
template<int EPI>
__global__ __launch_bounds__(256, 2) void mgemm(
    const unsigned short* __restrict__ Ag, const unsigned short* __restrict__ Bg,
    void* __restrict__ Cg, int N, int K, int lda, int ldb, float alpha,
    float* __restrict__ aux, void* __restrict__ aux2,
    long long sA, long long sB, long long sC)
{
    __shared__ unsigned short As[128 * 32];
    __shared__ unsigned short Bs[128 * 32];
    const unsigned short* A = Ag + (long long)blockIdx.z * sA;
    const unsigned short* B = Bg + (long long)blockIdx.z * sB;
    float* fC = (float*)Cg + (long long)blockIdx.z * sC;
    unsigned short* usC = (unsigned short*)Cg + (long long)blockIdx.z * sC;

    const int nwg = gridDim.x * gridDim.y;
    const int flat = blockIdx.y * gridDim.x + blockIdx.x;
    const int swz = (flat & 7) * (nwg >> 3) + (flat >> 3);
    const int bx = swz % gridDim.x, by = swz / gridDim.x;
    const int bm = by * 128, bn = bx * 128;

    const int tid = threadIdx.x;
    const int w = tid >> 6, l = tid & 63;
    const int wm = (w >> 1) * 64, wn = (w & 1) * 64;
    const int fr = l & 15, g = l >> 4;

    const f32x4 zero = { 0.f, 0.f, 0.f, 0.f };
    f32x4 acc[4][4];
    #pragma unroll
    for (int i = 0; i < 4; ++i)
        #pragma unroll
        for (int j = 0; j < 4; ++j) acc[i][j] = zero;

    for (int k0 = 0; k0 < K; k0 += 32) {
        #pragma unroll
        for (int p = 0; p < 2; ++p) {
            const int c = p * 256 + tid;
            GLOAD16(A + (long long)(bm + (c >> 2)) * lda + k0 + (c & 3) * 8, &As[c * 8]);
            GLOAD16(B + (long long)(bn + (c >> 2)) * ldb + k0 + (c & 3) * 8, &Bs[c * 8]);
        }
        __syncthreads();
        bf16x8 af[4], bfv[4];
        #pragma unroll
        for (int i = 0; i < 4; ++i) {
            af[i]  = *(const bf16x8*)&As[(wm + i * 16 + fr) * 32 + g * 8];
            bfv[i] = *(const bf16x8*)&Bs[(wn + i * 16 + fr) * 32 + g * 8];
        }
        #pragma unroll
        for (int i = 0; i < 4; ++i)
            #pragma unroll
            for (int j = 0; j < 4; ++j)
                acc[i][j] = __builtin_amdgcn_mfma_f32_16x16x32_bf16(af[i], bfv[j], acc[i][j], 0, 0, 0);
        __syncthreads();
    }

    if (EPI == 9) {
        if (bn < 2 * Hc) {
            // paired gate/up: even frag = gate, odd frag = up
            #pragma unroll
            for (int mi = 0; mi < 4; ++mi) {
                #pragma unroll
                for (int j = 0; j < 2; ++j) {
                    #pragma unroll
                    for (int jr = 0; jr < 4; ++jr) {
                        const long long row = bm + wm + mi * 16 + g * 4 + jr;
                        const long long colh = ((bn + wn) >> 1) + j * 16 + fr;
                        const float gv = acc[mi][2 * j][jr];
                        const float uv = acc[mi][2 * j + 1][jr];
                        usC[row * Hc + colh] = f2b(fsilu(gv) * uv);
                    }
                }
            }
        } else {
            // pre tile: cols 4096..4223 -> pre (f32) + pre_b (bf16)
            unsigned short* preb = (unsigned short*)aux2;
            #pragma unroll
            for (int mi = 0; mi < 4; ++mi) {
                #pragma unroll
                for (int ni = 0; ni < 4; ++ni) {
                    #pragma unroll
                    for (int jr = 0; jr < 4; ++jr) {
                        const long long row = bm + wm + mi * 16 + g * 4 + jr;
                        const int lc = wn + ni * 16 + fr;
                        const float v = acc[mi][ni][jr];
                        aux[row * Ac + lc] = v;
                        preb[row * Ac + lc] = f2b(v);
                    }
                }
            }
        }
    } else {
        #pragma unroll
        for (int mi = 0; mi < 4; ++mi) {
            #pragma unroll
            for (int ni = 0; ni < 4; ++ni) {
                #pragma unroll
                for (int jr = 0; jr < 4; ++jr) {
                    const long long row = bm + wm + mi * 16 + g * 4 + jr;
                    const long long col = bn + wn + ni * 16 + fr;
                    const long long idx = row * (long long)N + col;
                    float v = acc[mi][ni][jr];
                    if (EPI == 0) {
                        fC[idx] = v;
                    } else if (EPI == 1) {
                        usC[idx] = f2b(v);
                    } else if (EPI == 8) {
                        usC[idx] = f2b(alpha * v);
                    }
                }
            }
        }
    }
}

// ---------------- bf16 MFMA GEMM, 128x64 tile (f32 out) ----------------
__global__ __launch_bounds__(256, 2) void mgemm64(
    const unsigned short* __restrict__ Ag, const unsigned short* __restrict__ Bg,
    float* __restrict__ Cg, int N, int K, int lda, int ldb,
    long long sA, long long sB, long long sC)
{
    __shared__ unsigned short As[128 * 32];
    __shared__ unsigned short Bs[64 * 32];
    const unsigned short* A = Ag + (long long)blockIdx.z * sA;
    const unsigned short* B = Bg + (long long)blockIdx.z * sB;
    float* fC = Cg + (long long)blockIdx.z * sC;

    const int nwg = gridDim.x * gridDim.y;
    const int flat = blockIdx.y * gridDim.x + blockIdx.x;
    const int swz = (flat & 7) * (nwg >> 3) + (flat >> 3);
    const int bx = swz % gridDim.x, by = swz / gridDim.x;
    const int bm = by * 128, bn = bx * 64;

    const int tid = threadIdx.x;
    const int w = tid >> 6, l = tid & 63;
    const int wm = (w >> 1) * 64, wn = (w & 1) * 32;
    const int fr = l & 15, g = l >> 4;

    const f32x4 zero = { 0.f, 0.f, 0.f, 0.f };
    f32x4 acc[4][2];
    #pragma unroll
    for (int i = 0; i < 4; ++i)
        #pragma unroll
        for (int j = 0; j < 2; ++j) acc[i][j] = zero;

    for (int k0 = 0; k0 < K; k0 += 32) {
        #pragma unroll
        for (int p = 0; p < 2; ++p) {
            const int c = p * 256 + tid;
            GLOAD16(A + (long long)(bm + (c >> 2)) * lda + k0 + (c & 3) * 8, &As[c * 8]);
        }
        GLOAD16(B + (long long)(bn + (tid >> 2)) * ldb + k0 + (tid & 3) * 8, &Bs[tid * 8]);
        __syncthreads();
        bf16x8 af[4], bfv[2];
        #pragma unroll
        for (int i = 0; i < 4; ++i)
            af[i]  = *(const bf16x8*)&As[(wm + i * 16 + fr) * 32 + g * 8];
        #pragma unroll
        for (int j = 0; j < 2; ++j)
            bfv[j] = *(const bf16x8*)&Bs[(wn + j * 16 + fr) * 32 + g * 8];
        #pragma unroll
        for (int i = 0; i < 4; ++i)
            #pragma unroll
            for (int j = 0; j < 2; ++j)
                acc[i][j] = __builtin_amdgcn_mfma_f32_16x16x32_bf16(af[i], bfv[j], acc[i][j], 0, 0, 0);
        __syncthreads();
    }

    #pragma unroll
    for (int mi = 0; mi < 4; ++mi)
        #pragma unroll
        for (int ni = 0; ni < 2; ++ni)
            #pragma unroll
            for (int jr = 0; jr < 4; ++jr) {
                const long long row = bm + wm + mi * 16 + g * 4 + jr;
                const long long col = bn + wn + ni * 16 + fr;
                fC[row * (long long)N + col] = acc[mi][ni][jr];
            }
}

// ---------------- fused aw+adapt flash kernel ----------------
// Per block (tslice, qtile, batch): for 2 t-subtiles of 128:
//   S = Q @ K^T (Q=adapt_in rows q0.., K=adapt_out rows t1..), P = silu(clip(S)),
//   acc += P @ V^T  (V^T = adapt_inT).  Writes f32 partial [tslice][b][128][128].
__global__ __launch_bounds__(256, 2) void fadapt_k(
    const unsigned short* __restrict__ adapt_in,
    const unsigned short* __restrict__ adapt_out,
    const unsigned short* __restrict__ adapt_inT,
    float* __restrict__ partial)
{
    __shared__ unsigned short P_lds[4 * 128 * 32];   // [t/32][row][t%32]
    __shared__ unsigned short Bs[128 * 32];

    const int b = blockIdx.z;
    const int q0 = blockIdx.y * 128;
    const int t0 = blockIdx.x * 256;

    const unsigned short* Qg = adapt_in + (long long)b * Sc * Ac;
    const unsigned short* Kg = adapt_out + (long long)b * Sc * Ac;
    const unsigned short* Vt = adapt_inT + (long long)b * Ac * Sc;

    const int tid = threadIdx.x;
    const int w = tid >> 6, l = tid & 63;
    const int wm = (w >> 1) * 64, wn = (w & 1) * 64;
    const int fr = l & 15, g = l >> 4;

    // ---- load Q fragments into registers (rows q0..q0+127, k = 0..127) ----
    bf16x8 qf[4][4];   // [m-frag][k-step]
    for (int ks = 0; ks < 4; ++ks) {
        #pragma unroll
        for (int p = 0; p < 2; ++p) {
            const int c = p * 256 + tid;
            GLOAD16(Qg + (long long)(q0 + (c >> 2)) * Ac + ks * 32 + (c & 3) * 8, &Bs[c * 8]);
        }
        __syncthreads();
        #pragma unroll
        for (int i = 0; i < 4; ++i)
            qf[i][ks] = *(const bf16x8*)&Bs[(wm + i * 16 + fr) * 32 + g * 8];
        __syncthreads();
    }

    const f32x4 zero = { 0.f, 0.f, 0.f, 0.f };
    f32x4 acc[4][4];
    #pragma unroll
    for (int i = 0; i < 4; ++i)
        #pragma unroll
        for (int j = 0; j < 4; ++j) acc[i][j] = zero;

    #pragma unroll 1
    for (int ts = 0; ts < 2; ++ts) {
        const int t1 = t0 + ts * 128;
        // ---- S = Q @ K^T ----
        f32x4 sacc[4][4];
        #pragma unroll
        for (int i = 0; i < 4; ++i)
            #pragma unroll
            for (int j = 0; j < 4; ++j) sacc[i][j] = zero;
        for (int ks = 0; ks < 4; ++ks) {
            #pragma unroll
            for (int p = 0; p < 2; ++p) {
                const int c = p * 256 + tid;
                GLOAD16(Kg + (long long)(t1 + (c >> 2)) * Ac + ks * 32 + (c & 3) * 8, &Bs[c * 8]);
            }
            __syncthreads();
            bf16x8 bfv[4];
            #pragma unroll
            for (int j = 0; j < 4; ++j)
                bfv[j] = *(const bf16x8*)&Bs[(wn + j * 16 + fr) * 32 + g * 8];
            #pragma unroll
            for (int i = 0; i < 4; ++i)
                #pragma unroll
                for (int j = 0; j < 4; ++j)
                    sacc[i][j] = __builtin_amdgcn_mfma_f32_16x16x32_bf16(qf[i][ks], bfv[j], sacc[i][j], 0, 0, 0);
            __syncthreads();
        }
        // ---- P = silu(clip(S)) -> P_lds [t/32][row][t%32] ----
        #pragma unroll
        for (int mi = 0; mi < 4; ++mi) {
            #pragma unroll
            for (int ni = 0; ni < 4; ++ni) {
                const int t = wn + ni * 16 + fr;
                const int base = (t >> 5) * 4096 + (t & 31);
                #pragma unroll
                for (int jr = 0; jr < 4; ++jr) {
                    const int row = wm + mi * 16 + g * 4 + jr;
                    float v = sacc[mi][ni][jr];
                    v = fminf(fmaxf(v, -5.f), 5.f);
                    P_lds[base + row * 32] = f2b(fsilu(v));
                }
            }
        }
        __syncthreads();
        // ---- acc += P @ V^T ----
        for (int ks = 0; ks < 4; ++ks) {
            #pragma unroll
            for (int p = 0; p < 2; ++p) {
                const int c = p * 256 + tid;
                GLOAD16(Vt + (long long)(c >> 2) * Sc + t1 + ks * 32 + (c & 3) * 8, &Bs[c * 8]);
            }
            __syncthreads();
            bf16x8 af[4], bfv[4];
            #pragma unroll
            for (int i = 0; i < 4; ++i)
                af[i] = *(const bf16x8*)&P_lds[ks * 4096 + (wm + i * 16 + fr) * 32 + g * 8];
            #pragma unroll
            for (int j = 0; j < 4; ++j)
                bfv[j] = *(const bf16x8*)&Bs[(wn + j * 16 + fr) * 32 + g * 8];
            #pragma unroll
            for (int i = 0; i < 4; ++i)
                #pragma unroll
                for (int j = 0; j < 4; ++j)
                    acc[i][j] = __builtin_amdgcn_mfma_f32_16x16x32_bf16(af[i], bfv[j], acc[i][j], 0, 0, 0);
            __syncthreads();
        }
    }

    // ---- write f32 partial: [tslice][b][q][a] ----
    float* op = partial + ((long long)blockIdx.x * Bc + b) * Sc * Ac;
    #pragma unroll
    for (int mi = 0; mi < 4; ++mi)
        #pragma unroll
        for (int ni = 0; ni < 4; ++ni)
            #pragma unroll
            for (int jr = 0; jr < 4; ++jr) {
                const long long row = q0 + wm + mi * 16 + g * 4 + jr;
                const long long col = wn + ni * 16 + fr;
                op[row * Ac + col] = acc[mi][ni][jr];
            }
}

// ---------------- final fused 3-phase GEMM, 128x64 tile ----------------
__global__ __launch_bounds__(256, 2) void final_k(
    const unsigned short* __restrict__ hidden, const unsigned short* __restrict__ Wd,
    const unsigned short* __restrict__ adaptb, const unsigned short* __restrict__ Wdap,
    const unsigned short* __restrict__ h2v, const unsigned short* __restrict__ Wopep,
    const float* __restrict__ dmsum, float* __restrict__ out)
{
    __shared__ unsigned short As[128 * 32];
    __shared__ unsigned short Bs[64 * 32];

    const int nwg = gridDim.x * gridDim.y;
    const int flat = blockIdx.y * gridDim.x + blockIdx.x;
    const int swz = (flat & 7) * (nwg >> 3) + (flat >> 3);
    const int bx = swz % gridDim.x, by = swz / gridDim.x;
    const int bm = by * 128, bn = bx * 64;

    const int tid = threadIdx.x;
    const int w = tid >> 6, l = tid & 63;
    const int wm = (w >> 1) * 64, wn = (w & 1) * 32;
    const int fr = l & 15, g = l >> 4;

    const f32x4 zero = { 0.f, 0.f, 0.f, 0.f };
    f32x4 acc[4][2];
    #pragma unroll
    for (int i = 0; i < 4; ++i)
        #pragma unroll
        for (int j = 0; j < 2; ++j) acc[i][j] = zero;

    const unsigned short* Ap[3] = { hidden, adaptb, h2v };
    const unsigned short* Bp[3] = { Wd, Wdap, Wopep };
    const int Ks[3]  = { Hc, Ac, Ac };
    const int lds[3] = { Hc, Ac, Ac };

    #pragma unroll 1
    for (int ph = 0; ph < 3; ++ph) {
        if (ph == 2) {
            #pragma unroll
            for (int mi = 0; mi < 4; ++mi)
                #pragma unroll
                for (int jr = 0; jr < 4; ++jr) {
                    const float rs = dmsum[bm + wm + mi * 16 + g * 4 + jr];
                    #pragma unroll
                    for (int ni = 0; ni < 2; ++ni) acc[mi][ni][jr] *= rs;
                }
        }
        const unsigned short* A = Ap[ph];
        const unsigned short* B = Bp[ph];
        const int K = Ks[ph], ld = lds[ph];
        for (int k0 = 0; k0 < K; k0 += 32) {
            #pragma unroll
            for (int p = 0; p < 2; ++p) {
                const int c = p * 256 + tid;
                GLOAD16(A + (long long)(bm + (c >> 2)) * ld + k0 + (c & 3) * 8, &As[c * 8]);
            }
            GLOAD16(B + (long long)(bn + (tid >> 2)) * ld + k0 + (tid & 3) * 8, &Bs[tid * 8]);
            __syncthreads();
            bf16x8 af[4], bfv[2];
            #pragma unroll
            for (int i = 0; i < 4; ++i)
                af[i]  = *(const bf16x8*)&As[(wm + i * 16 + fr) * 32 + g * 8];
            #pragma unroll
            for (int j = 0; j < 2; ++j)
                bfv[j] = *(const bf16x8*)&Bs[(wn + j * 16 + fr) * 32 + g * 8];
            #pragma unroll
            for (int i = 0; i < 4; ++i)
                #pragma unroll
                for (int j = 0; j < 2; ++j)
                    acc[i][j] = __builtin_amdgcn_mfma_f32_16x16x32_bf16(af[i], bfv[j], acc[i][j], 0, 0, 0);
            __syncthreads();
        }
    }

    #pragma unroll
    for (int mi = 0; mi < 4; ++mi)
        #pragma unroll
        for (int ni = 0; ni < 2; ++ni)
            #pragma unroll
            for (int jr = 0; jr < 4; ++jr) {
                const long long row = bm + wm + mi * 16 + g * 4 + jr;
                const long long col = bn + wn + ni * 16 + fr;
                out[row * (long long)Dc + col] = acc[mi][ni][jr];
            }
}

// ---------------- partial-sum reduce: out = sum_p in[p*stride + i] ----------------
template<int NP, int BF>
__global__ __launch_bounds__(256) void reduce_k(const float* __restrict__ in,
                                                void* __restrict__ outp,
                                                long long pstride, int n4)
{
    for (int i = blockIdx.x * 256 + threadIdx.x; i < n4; i += gridDim.x * 256) {
        float4 s = ((const float4*)in)[i];
        #pragma unroll
        for (int p = 1; p < NP; ++p) {
            const float4 v = ((const float4*)(in + (long long)p * pstride))[i];
            s.x += v.x; s.y += v.y; s.z += v.z; s.w += v.w;
        }
        if (BF) {
            us4 o = { f2b(s.x), f2b(s.y), f2b(s.z), f2b(s.w) };
            ((us4*)outp)[i] = o;
        } else {
            ((float4*)outp)[i] = s;
        }
    }
}

// ---------------- fp32 -> bf16 casts (batched) ----------------
struct CastJobs {
    const float* src[5];
    unsigned short* dst[5];
    int n4[5];
};
__global__ __launch_bounds__(256) void cast_k(CastJobs jobs) {
    const int b = blockIdx.y;
    const float4* s = (const float4*)jobs.src[b];
    us4* d = (us4*)jobs.dst[b];
    const int n = jobs.n4[b];
    for (int i = blockIdx.x * 256 + threadIdx.x; i < n; i += gridDim.x * 256) {
        const float4 v = s[i];
        us4 o;
        o.x = f2b(v.x); o.y = f2b(v.y); o.z = f2b(v.z); o.w = f2b(v.w);
        d[i] = o;
    }
}

// ---------------- gate/up interleaved + pre appended: Wcat[4224,1024] bf16 ----
__global__ __launch_bounds__(256) void gucast_k(const float* __restrict__ Wg,
                                                const float* __restrict__ Wu,
                                                const float* __restrict__ Wpre,
                                                unsigned short* __restrict__ Wcat)
{
    const int r = blockIdx.x;
    const float* src;
    int srcrow;
    if (r < 2 * Hc) {
        const int b = r >> 5, w = r & 31;
        src = (w < 16) ? Wg : Wu;
        srcrow = b * 16 + (w & 15);
    } else {
        src = Wpre;
        srcrow = r - 2 * Hc;
    }
    const float4 v = ((const float4*)(src + (long long)srcrow * Dc))[threadIdx.x];
    us4 o;
    o.x = f2b(v.x); o.y = f2b(v.y); o.z = f2b(v.z); o.w = f2b(v.w);
    ((us4*)(Wcat + (long long)r * Dc))[threadIdx.x] = o;
}

// ---------------- cast-transpose: f32 [2048,128] -> bf16 [128,2048], z=0/1 ----
__global__ __launch_bounds__(256) void ct_k(const float* __restrict__ in0,
                                            const float* __restrict__ in1,
                                            unsigned short* __restrict__ out0,
                                            unsigned short* __restrict__ out1)
{
    const float* in = blockIdx.z ? in1 : in0;
    unsigned short* out = blockIdx.z ? out1 : out0;
    const int t0 = blockIdx.x * 64, a0 = blockIdx.y * 64;
    __shared__ float T[64][68];
    const int rr = threadIdx.x >> 4, cc = (threadIdx.x & 15) * 4;
    #pragma unroll
    for (int p = 0; p < 4; ++p) {
        const int row = p * 16 + rr;
        *(float4*)&T[row][cc] = *(const float4*)&in[(long long)(t0 + row) * Ac + a0 + cc];
    }
    __syncthreads();
    #pragma unroll
    for (int p = 0; p < 4; ++p) {
        const int ar = p * 16 + rr;
        us4 o;
        o.x = f2b(T[cc + 0][ar]); o.y = f2b(T[cc + 1][ar]);
        o.z = f2b(T[cc + 2][ar]); o.w = f2b(T[cc + 3][ar]);
        *(us4*)&out[(long long)(a0 + ar) * Hc + t0 + cc] = o;
    }
}

// ---------------- LayerNorm over 128, one wave per row, bf16 out ----------------
__global__ __launch_bounds__(64) void ln_k(const float* __restrict__ in, unsigned short* __restrict__ out,
                                           const float* __restrict__ gg, const float* __restrict__ bb)
{
    const int row = blockIdx.x;
    const int lane = threadIdx.x;
    const float z0 = in[(long long)row * 128 + lane];
    const float z1 = in[(long long)row * 128 + 64 + lane];
    float s = z0 + z1;
    for (int o = 32; o > 0; o >>= 1) s += __shfl_down(s, o, 64);
    s = __shfl(s, 0, 64);
    const float mu = s * (1.f / 128.f);
    const float d0 = z0 - mu, d1 = z1 - mu;
    float v = d0 * d0 + d1 * d1;
    for (int o = 32; o > 0; o >>= 1) v += __shfl_down(v, o, 64);
    v = __shfl(v, 0, 64);
    const float r = rsqrtf(v * (1.f / 128.f) + LN_EPSc);
    out[(long long)row * 128 + lane] = f2b(d0 * r * gg[lane] + bb[lane]);
    out[(long long)row * 128 + 64 + lane] = f2b(d1 * r * gg[lane + 64] + bb[lane + 64]);
}

// ---------------- transpose per batch: [2048,128] -> [128,2048] bf16 ----------------
__global__ __launch_bounds__(256) void trans_k(const unsigned short* __restrict__ in,
                                               unsigned short* __restrict__ out)
{
    const int z = blockIdx.z;
    const int t0 = blockIdx.x * 64, a0 = blockIdx.y * 64;
    __shared__ unsigned short T[64][72];
    const unsigned short* ip = in + (long long)z * Sc * Ac;
    unsigned short* op = out + (long long)z * Ac * Sc;
    const int rr = threadIdx.x >> 4, cc = (threadIdx.x & 15) * 4;
    #pragma unroll
    for (int p = 0; p < 4; ++p) {
        const int row = p * 16 + rr;
        *(us4*)&T[row][cc] = *(const us4*)&ip[(long long)(t0 + row) * Ac + a0 + cc];
    }
    __syncthreads();
    #pragma unroll
    for (int p = 0; p < 4; ++p) {
        const int arow = p * 16 + rr;
        us4 o;
        o.x = T[cc + 0][arow]; o.y = T[cc + 1][arow];
        o.z = T[cc + 2][arow]; o.w = T[cc + 3][arow];
        *(us4*)&op[(long long)(a0 + arow) * Sc + t0 + cc] = o;
    }
}

// ---------------- router: 512 blocks x 256 threads, NO global atomics ----------------
__global__ __launch_bounds__(256) void router_k(const float* __restrict__ x,
                                                const float* __restrict__ W_rg,
                                                const float* __restrict__ W_re,
                                                int* __restrict__ eidx, float* __restrict__ fw,
                                                float* __restrict__ dmsum,
                                                float* __restrict__ rpart)
{
    const int wv = threadIdx.x >> 6;
    const int lane = threadIdx.x & 63;
    float load8[8] = {0.f, 0.f, 0.f, 0.f, 0.f, 0.f, 0.f, 0.f};
    float sqg = 0.f, sqe = 0.f;

    #pragma unroll
    for (int it = 0; it < 2; ++it) {
        const int t = blockIdx.x * 8 + wv * 2 + it;
        const float* xr = x + (long long)t * Dc;
        float a0 = 0, a1 = 0, a2 = 0, a3 = 0, a4 = 0, a5 = 0;
        #pragma unroll
        for (int j = 0; j < 16; ++j) {
            const int d = lane + 64 * j;
            const float xv = xr[d];
            a0 += xv * W_rg[d];          a1 += xv * W_rg[Dc + d];
            a2 += xv * W_re[d];          a3 += xv * W_re[Dc + d];
            a4 += xv * W_re[2 * Dc + d]; a5 += xv * W_re[3 * Dc + d];
        }
        #pragma unroll
        for (int o = 32; o > 0; o >>= 1) {
            a0 += __shfl_xor(a0, o, 64); a1 += __shfl_xor(a1, o, 64);
            a2 += __shfl_xor(a2, o, 64); a3 += __shfl_xor(a3, o, 64);
            a4 += __shfl_xor(a4, o, 64); a5 += __shfl_xor(a5, o, 64);
        }
        if (lane == 0) {
            const float gl0 = a0, gl1 = a1;
            const float m = fmaxf(gl0, gl1);
            const float e0 = expf(gl0 - m), e1 = expf(gl1 - m);
            const float inv = 1.f / (e0 + e1);
            const float gp0 = e0 * inv, gp1 = e1 * inv;
            const int gidx = (gl1 > gl0) ? 1 : 0;
            const float gw = fmaxf(gp0, gp1);
            float el[4] = { a2, a3, a4, a5 };
            const float me = fmaxf(fmaxf(el[0], el[1]), fmaxf(el[2], el[3]));
            float ep[4]; float se = 0.f;
            #pragma unroll
            for (int i = 0; i < 4; ++i) { ep[i] = expf(el[i] - me); se += ep[i]; }
            const float invs = 1.f / se;
            #pragma unroll
            for (int i = 0; i < 4; ++i) ep[i] *= invs;
            int i0 = 0;
            #pragma unroll
            for (int i = 1; i < 4; ++i) if (ep[i] > ep[i0]) i0 = i;
            int i1 = -1;
            #pragma unroll
            for (int i = 0; i < 4; ++i) { if (i == i0) continue; if (i1 < 0 || ep[i] > ep[i1]) i1 = i; }
            const float w0 = ep[i0], w1 = ep[i1];
            const float sn = w0 + w1 + 1e-7f;
            const float f0 = gw * w0 / sn, f1 = gw * w1 / sn;
            const int ei0 = gidx * GSc + i0, ei1 = gidx * GSc + i1;
            eidx[t * 2] = ei0; eidx[t * 2 + 1] = ei1;
            fw[t * 2] = f0; fw[t * 2 + 1] = f1;
            dmsum[t] = f0 + f1;
            #pragma unroll
            for (int e = 0; e < 8; ++e)
                load8[e] += ((e == ei0) ? f0 : 0.f) + ((e == ei1) ? f1 : 0.f);
            sqg += gl0 * gl0 + gl1 * gl1;
            sqe += el[0] * el[0] + el[1] * el[1] + el[2] * el[2] + el[3] * el[3];
        }
    }
    __shared__ float sh[4][10];
    if (lane == 0) {
        #pragma unroll
        for (int e = 0; e < 8; ++e) sh[wv][e] = load8[e];
        sh[wv][8] = sqg; sh[wv][9] = sqe;
    }
    __syncthreads();
    if (threadIdx.x < 10) {
        rpart[blockIdx.x * 10 + threadIdx.x] =
            sh[0][threadIdx.x] + sh[1][threadIdx.x] + sh[2][threadIdx.x] + sh[3][threadIdx.x];
    }
}

// ---------------- loss reduce over RBLK partial rows ----------------
__global__ __launch_bounds__(512) void loss_k(const float* __restrict__ rpart,
                                              float* __restrict__ out_loss)
{
    const int tid = threadIdx.x;
    const int lane = tid & 63, wv = tid >> 6;
    float v[10];
    #pragma unroll
    for (int c = 0; c < 10; ++c) v[c] = rpart[tid * 10 + c];
    #pragma unroll
    for (int o = 32; o > 0; o >>= 1)
        #pragma unroll
        for (int c = 0; c < 10; ++c) v[c] += __shfl_xor(v[c], o, 64);
    __shared__ float sh[8][10];
    if (lane == 0) {
        #pragma unroll
        for (int c = 0; c < 10; ++c) sh[wv][c] = v[c];
    }
    __syncthreads();
    if (tid == 0) {
        float load[8]; float sqg = 0.f, sqe = 0.f;
        #pragma unroll
        for (int e = 0; e < 8; ++e) load[e] = 0.f;
        for (int wvi = 0; wvi < 8; ++wvi) {
            #pragma unroll
            for (int e = 0; e < 8; ++e) load[e] += sh[wvi][e];
            sqg += sh[wvi][8]; sqe += sh[wvi][9];
        }
        float s = 0.f;
        for (int e = 0; e < Ec; ++e) s += load[e];
        const float tgt = s / (float)Ec;
        float var = 0.f;
        for (int e = 0; e < Ec; ++e) { const float d = load[e] - tgt; var += d * d; }
        var /= (float)Ec;
        const float l = var + sqg / (float)(Nc * Gc) + sqe / (float)(Nc * GSc);
        *out_loss = 0.001f * l;
    }
}

// ---------------- combine: h2[t] = sum_slot fw * LN_e(h_dense[e][t]) ----------------
__global__ __launch_bounds__(128) void combine_k(const float* __restrict__ h_dense,
                                                 const float* __restrict__ ln_g_e,
                                                 const float* __restrict__ ln_b_e,
                                                 const int* __restrict__ eidx,
                                                 const float* __restrict__ fw,
                                                 unsigned short* __restrict__ h2)
{
    const int t = blockIdx.x;
    const int tid = threadIdx.x;
    __shared__ float red[2];

    float acc = 0.f;
    #pragma unroll
    for (int slot = 0; slot < 2; ++slot) {
        const int e = eidx[t * 2 + slot];
        const float w = fw[t * 2 + slot];
        const float h = h_dense[((long long)e * Nc + t) * 128 + tid];
        float v = h;
        for (int o = 32; o > 0; o >>= 1) v += __shfl_down(v, o, 64);
        if ((tid & 63) == 0) red[tid >> 6] = v;
        __syncthreads();
        const float mu = (red[0] + red[1]) * (1.f / 128.f);
        __syncthreads();
        const float d = h - mu;
        v = d * d;
        for (int o = 32; o > 0; o >>= 1) v += __shfl_down(v, o, 64);
        if ((tid & 63) == 0) red[tid >> 6] = v;
        __syncthreads();
        const float var = (red[0] + red[1]) * (1.f / 128.f);
        __syncthreads();
        acc += w * (d * rsqrtf(var + LN_EPSc) * ln_g_e[e * 128 + tid] + ln_b_e[e * 128 + tid]);
    }
    h2[(long long)t * 128 + tid] = f2b(acc);
}

// =====================================================================
extern "C" void kernel_launch(void* const* d_in, const int* in_sizes, int n_in,
                              void* d_out, int out_size, void* d_ws, size_t ws_size,
                              hipStream_t stream)
{
    const float* x       = (const float*)d_in[0];
    const float* W_up    = (const float*)d_in[1];
    const float* W_gate  = (const float*)d_in[2];
    const float* W_down  = (const float*)d_in[3];
    const float* W_pre   = (const float*)d_in[4];
    const float* W_post  = (const float*)d_in[5];
    const float* ln_g    = (const float*)d_in[6];
    const float* ln_b    = (const float*)d_in[7];
    const float* W_aproj = (const float*)d_in[8];
    const float* A_exp   = (const float*)d_in[9];
    const float* ln_g_e  = (const float*)d_in[10];
    const float* ln_b_e  = (const float*)d_in[11];
    const float* W_eproj = (const float*)d_in[12];
    const float* W_oproj = (const float*)d_in[13];
    const float* W_rg    = (const float*)d_in[14];
    const float* W_re    = (const float*)d_in[15];

    float* out = (float*)d_out;

    // ---- workspace carve ----
    char* p = (char*)d_ws;
    auto alloc = [&](size_t bytes) { void* r = (void*)p; p += (bytes + 255) & ~(size_t)255; return r; };
    float* pre      = (float*)alloc((size_t)Nc * Ac * 4);
    float* postbuf  = (float*)alloc((size_t)Nc * Ac * 4);
    float* h_dense  = (float*)alloc((size_t)Ec * Nc * Ac * 4);   // 16.8 MB; also hosts postP / adaptP
    float* rpart    = (float*)alloc((size_t)RBLK * 10 * 4);
    float* fw       = (float*)alloc((size_t)Nc * 2 * 4);
    float* dmsum    = (float*)alloc((size_t)Nc * 4);
    int*   eidx     = (int*)alloc((size_t)Nc * 2 * 4);
    unsigned short* xb      = (unsigned short*)alloc((size_t)Nc * Dc * 2);
    unsigned short* Wcat_b  = (unsigned short*)alloc((size_t)(2 * Hc + Ac) * Dc * 2);
    unsigned short* Wd_b    = (unsigned short*)alloc((size_t)Dc * Hc * 2);
    unsigned short* Wop_b   = (unsigned short*)alloc((size_t)Dc * Hc * 2);     // adjacent to Wd_b
    unsigned short* Wpost_b = (unsigned short*)alloc((size_t)Ac * Hc * 2);
    unsigned short* WapT_b  = (unsigned short*)alloc((size_t)Ac * Hc * 2);
    unsigned short* WepT_b  = (unsigned short*)alloc((size_t)Ac * Hc * 2);     // adjacent to WapT_b
    unsigned short* Wdap_b  = (unsigned short*)alloc((size_t)Dc * Ac * 2);
    unsigned short* Wopep_b = (unsigned short*)alloc((size_t)Dc * Ac * 2);     // adjacent to Wdap_b
    unsigned short* Aexp_b  = (unsigned short*)alloc((size_t)Ec * Ac * Ac * 2);
    unsigned short* pre_b   = (unsigned short*)alloc((size_t)Nc * Ac * 2);
    unsigned short* hidden  = (unsigned short*)alloc((size_t)Nc * Hc * 2);
    unsigned short* adapt_in  = (unsigned short*)alloc((size_t)Nc * Ac * 2);
    unsigned short* adapt_inT = (unsigned short*)alloc((size_t)Nc * Ac * 2);
    unsigned short* adapt_out = (unsigned short*)alloc((size_t)Nc * Ac * 2);
    unsigned short* adaptb    = (unsigned short*)alloc((size_t)Nc * Ac * 2);
    unsigned short* h2        = (unsigned short*)alloc((size_t)Nc * Ac * 2);

    float* postP  = h_dense;   // [4][4096*128] f32 — dead before h_dense GEMM
    float* adaptP = h_dense;   // [8][2][2048*128] f32 — h_dense dead after combine

    // ---- weight prep ----
    CastJobs jobs;
    jobs.src[0] = x;       jobs.dst[0] = xb;      jobs.n4[0] = Nc * Dc / 4;
    jobs.src[1] = W_down;  jobs.dst[1] = Wd_b;    jobs.n4[1] = Dc * Hc / 4;
    jobs.src[2] = W_oproj; jobs.dst[2] = Wop_b;   jobs.n4[2] = Dc * Hc / 4;
    jobs.src[3] = W_post;  jobs.dst[3] = Wpost_b; jobs.n4[3] = Ac * Hc / 4;
    jobs.src[4] = A_exp;   jobs.dst[4] = Aexp_b;  jobs.n4[4] = Ec * Ac * Ac / 4;
    cast_k<<<dim3(128, 5), 256, 0, stream>>>(jobs);
    gucast_k<<<2 * Hc + Ac, 256, 0, stream>>>(W_gate, W_up, W_pre, Wcat_b);
    ct_k<<<dim3(Hc / 64, Ac / 64, 2), 256, 0, stream>>>(W_aproj, W_eproj, WapT_b, WepT_b);

    // Wdap = 0.1*(Wd @ Wap), Wopep = 0.1*(Wop @ Wep)  [1024,128] bf16, z batched
    mgemm<8><<<dim3(1, Dc / 128, 2), 256, 0, stream>>>(Wd_b, WapT_b, Wdap_b, Ac, Hc, Hc, Hc, 0.1f,
        nullptr, nullptr, (long long)Dc * Hc, (long long)Ac * Hc, (long long)Dc * Ac);

    // ---- router (atomic-free) ----
    router_k<<<RBLK, 256, 0, stream>>>(x, W_rg, W_re, eidx, fw, dmsum, rpart);
    loss_k<<<1, 512, 0, stream>>>(rpart, out + (size_t)Nc * Dc);

    // ---- fused gate+up+pre: hidden = silu(gate)*up ; pre (f32) + pre_b ----
    mgemm<9><<<dim3(33, 32), 256, 0, stream>>>(xb, Wcat_b, hidden, 2 * Hc + Ac, Dc, Dc, Dc, 0.f,
        pre, pre_b, 0, 0, 0);
    ln_k<<<Nc, 64, 0, stream>>>(pre, adapt_in, ln_g, ln_b);
    trans_k<<<dim3(Sc / 64, Ac / 64, Bc), 256, 0, stream>>>(adapt_in, adapt_inT);

    // ---- post split-K (4x512) -> partials -> postbuf -> adapt_out ----
    mgemm64<<<dim3(2, 32, 4), 256, 0, stream>>>(hidden, Wpost_b, postP, Ac, 512, Hc, Hc,
        512, 512, (long long)Nc * Ac);
    reduce_k<4, 0><<<512, 256, 0, stream>>>(postP, postbuf, (long long)Nc * Ac, Nc * Ac / 4);
    ln_k<<<Nc, 64, 0, stream>>>(postbuf, adapt_out, ln_g, ln_b);

    // ---- dense expert adapter: h_dense[e] = pre_b @ A_exp[e]^T ----
    mgemm64<<<dim3(2, 32, Ec), 256, 0, stream>>>(pre_b, Aexp_b, h_dense, Ac, Ac, Ac, Ac,
        0, (long long)Ac * Ac, (long long)Nc * Ac);
    combine_k<<<Nc, 128, 0, stream>>>(h_dense, ln_g_e, ln_b_e, eidx, fw, h2);

    // ---- fused aw+adapt flash kernel -> f32 partials -> adaptb (bf16) ----
    fadapt_k<<<dim3(8, 16, 2), 256, 0, stream>>>(adapt_in, adapt_out, adapt_inT, adaptP);
    reduce_k<8, 1><<<512, 256, 0, stream>>>(adaptP, adaptb,
        (long long)2 * Sc * Ac, 2 * Sc * Ac / 4);

    // ---- final fused: out = dmsum*(hidden@Wd^T + adaptb@Wdap^T) + h2@Wopep^T ----
    final_k<<<dim3(Dc / 64, Nc / 128), 256, 0, stream>>>(
        hidden, Wd_b, adaptb, Wdap_b, h2, Wopep_b, dmsum, out);
}

// Round 8
// 200.716 us; speedup vs baseline: 8.0197x; 1.1830x over previous
//
#include <hip/hip_runtime.h>
#include <hip/hip_bf16.h>
#include <math.h>

static constexpr int Bc = 2;
static constexpr int Sc = 2048;
static constexpr int Dc = 1024;
static constexpr int Hc = 2048;
static constexpr int Ac = 128;
static constexpr int Ec = 8;
static constexpr int GSc = 4;
static constexpr int Gc = 2;
static constexpr int Nc = Bc * Sc;   // 4096 tokens
static constexpr float LN_EPSc = 1e-5f;
static constexpr int RBLK = 512;     // router blocks

typedef __attribute__((ext_vector_type(8))) short bf16x8;
typedef __attribute__((ext_vector_type(4))) float f32x4;
typedef __attribute__((ext_vector_type(4))) unsigned short us4;

__device__ __forceinline__ unsigned short f2b(float f) {
    union { float f; unsigned u; } v; v.f = f;
    return (unsigned short)((v.u + 0x7FFFu + ((v.u >> 16) & 1u)) >> 16);
}
__device__ __forceinline__ float b2f(unsigned short h) {
    union { unsigned u; float f; } v; v.u = (unsigned)h << 16; return v.f;
}
__device__ __forceinline__ float fsilu(float x) {
    return x / (1.f + __expf(-x));
}

#define GLOAD16(g, l) __builtin_amdgcn_global_load_lds( \
    (const __attribute__((address_space(1))) void*)(g), \
    (__attribute__((address_space(3))) void*)(l), 16, 0, 0)

// ---------------- bf16 MFMA GEMM, 128x128 tile: C[M,N] = A[M,K] @ B[N,K]^T ----
// EPI 9 = gateup paired silu + pre side-channel (aux=pre f32, aux2=pre_b bf16)
template<int EPI>
__global__ __launch_bounds__(256, 4) void mgemm(
    const unsigned short* __restrict__ Ag, const unsigned short* __restrict__ Bg,
    void* __restrict__ Cg, int N, int K, int lda, int ldb, float alpha,
    float* __restrict__ aux, void* __restrict__ aux2,
    long long sA, long long sB, long long sC)
{
    __shared__ unsigned short As[128 * 32];
    __shared__ unsigned short Bs[128 * 32];
    const unsigned short* A = Ag + (long long)blockIdx.z * sA;
    const unsigned short* B = Bg + (long long)blockIdx.z * sB;
    float* fC = (float*)Cg + (long long)blockIdx.z * sC;
    unsigned short* usC = (unsigned short*)Cg + (long long)blockIdx.z * sC;

    const int nwg = gridDim.x * gridDim.y;
    const int flat = blockIdx.y * gridDim.x + blockIdx.x;
    const int swz = (flat & 7) * (nwg >> 3) + (flat >> 3);
    const int bx = swz % gridDim.x, by = swz / gridDim.x;
    const int bm = by * 128, bn = bx * 128;

    const int tid = threadIdx.x;
    const int w = tid >> 6, l = tid & 63;
    const int wm = (w >> 1) * 64, wn = (w & 1) * 64;
    const int fr = l & 15, g = l >> 4;

    const f32x4 zero = { 0.f, 0.f, 0.f, 0.f };
    f32x4 acc[4][4];
    #pragma unroll
    for (int i = 0; i < 4; ++i)
        #pragma unroll
        for (int j = 0; j < 4; ++j) acc[i][j] = zero;

    for (int k0 = 0; k0 < K; k0 += 32) {
        #pragma unroll
        for (int p = 0; p < 2; ++p) {
            const int c = p * 256 + tid;
            GLOAD16(A + (long long)(bm + (c >> 2)) * lda + k0 + (c & 3) * 8, &As[c * 8]);
            GLOAD16(B + (long long)(bn + (c >> 2)) * ldb + k0 + (c & 3) * 8, &Bs[c * 8]);
        }
        __syncthreads();
        bf16x8 af[4], bfv[4];
        #pragma unroll
        for (int i = 0; i < 4; ++i) {
            af[i]  = *(const bf16x8*)&As[(wm + i * 16 + fr) * 32 + g * 8];
            bfv[i] = *(const bf16x8*)&Bs[(wn + i * 16 + fr) * 32 + g * 8];
        }
        #pragma unroll
        for (int i = 0; i < 4; ++i)
            #pragma unroll
            for (int j = 0; j < 4; ++j)
                acc[i][j] = __builtin_amdgcn_mfma_f32_16x16x32_bf16(af[i], bfv[j], acc[i][j], 0, 0, 0);
        __syncthreads();
    }

    if (EPI == 9) {
        if (bn < 2 * Hc) {
            #pragma unroll
            for (int mi = 0; mi < 4; ++mi) {
                #pragma unroll
                for (int j = 0; j < 2; ++j) {
                    #pragma unroll
                    for (int jr = 0; jr < 4; ++jr) {
                        const long long row = bm + wm + mi * 16 + g * 4 + jr;
                        const long long colh = ((bn + wn) >> 1) + j * 16 + fr;
                        const float gv = acc[mi][2 * j][jr];
                        const float uv = acc[mi][2 * j + 1][jr];
                        usC[row * Hc + colh] = f2b(fsilu(gv) * uv);
                    }
                }
            }
        } else {
            unsigned short* preb = (unsigned short*)aux2;
            #pragma unroll
            for (int mi = 0; mi < 4; ++mi) {
                #pragma unroll
                for (int ni = 0; ni < 4; ++ni) {
                    #pragma unroll
                    for (int jr = 0; jr < 4; ++jr) {
                        const long long row = bm + wm + mi * 16 + g * 4 + jr;
                        const int lc = wn + ni * 16 + fr;
                        const float v = acc[mi][ni][jr];
                        aux[row * Ac + lc] = v;
                        preb[row * Ac + lc] = f2b(v);
                    }
                }
            }
        }
    } else {
        #pragma unroll
        for (int mi = 0; mi < 4; ++mi)
            #pragma unroll
            for (int ni = 0; ni < 4; ++ni)
                #pragma unroll
                for (int jr = 0; jr < 4; ++jr) {
                    const long long row = bm + wm + mi * 16 + g * 4 + jr;
                    const long long col = bn + wn + ni * 16 + fr;
                    const long long idx = row * (long long)N + col;
                    const float v = acc[mi][ni][jr];
                    if (EPI == 0) fC[idx] = v;
                    else usC[idx] = f2b(alpha * v);
                }
    }
}

// ---------------- bf16 MFMA GEMM, 128x64 tile (f32 out), 2-axis z decode ----
__global__ __launch_bounds__(256, 2) void mgemm64(
    const unsigned short* __restrict__ Ag, const unsigned short* __restrict__ Bg,
    float* __restrict__ Cg, int N, int K, int lda, int ldb, int zmod,
    long long sA1, long long sB1, long long sC1,
    long long sA2, long long sB2, long long sC2)
{
    __shared__ unsigned short As[128 * 32];
    __shared__ unsigned short Bs[64 * 32];
    const int z1 = blockIdx.z % zmod, z2 = blockIdx.z / zmod;
    const unsigned short* A = Ag + (long long)z1 * sA1 + (long long)z2 * sA2;
    const unsigned short* B = Bg + (long long)z1 * sB1 + (long long)z2 * sB2;
    float* fC = Cg + (long long)z1 * sC1 + (long long)z2 * sC2;

    const int nwg = gridDim.x * gridDim.y;
    const int flat = blockIdx.y * gridDim.x + blockIdx.x;
    const int swz = (flat & 7) * (nwg >> 3) + (flat >> 3);
    const int bx = swz % gridDim.x, by = swz / gridDim.x;
    const int bm = by * 128, bn = bx * 64;

    const int tid = threadIdx.x;
    const int w = tid >> 6, l = tid & 63;
    const int wm = (w >> 1) * 64, wn = (w & 1) * 32;
    const int fr = l & 15, g = l >> 4;

    const f32x4 zero = { 0.f, 0.f, 0.f, 0.f };
    f32x4 acc[4][2];
    #pragma unroll
    for (int i = 0; i < 4; ++i)
        #pragma unroll
        for (int j = 0; j < 2; ++j) acc[i][j] = zero;

    for (int k0 = 0; k0 < K; k0 += 32) {
        #pragma unroll
        for (int p = 0; p < 2; ++p) {
            const int c = p * 256 + tid;
            GLOAD16(A + (long long)(bm + (c >> 2)) * lda + k0 + (c & 3) * 8, &As[c * 8]);
        }
        GLOAD16(B + (long long)(bn + (tid >> 2)) * ldb + k0 + (tid & 3) * 8, &Bs[tid * 8]);
        __syncthreads();
        bf16x8 af[4], bfv[2];
        #pragma unroll
        for (int i = 0; i < 4; ++i)
            af[i]  = *(const bf16x8*)&As[(wm + i * 16 + fr) * 32 + g * 8];
        #pragma unroll
        for (int j = 0; j < 2; ++j)
            bfv[j] = *(const bf16x8*)&Bs[(wn + j * 16 + fr) * 32 + g * 8];
        #pragma unroll
        for (int i = 0; i < 4; ++i)
            #pragma unroll
            for (int j = 0; j < 2; ++j)
                acc[i][j] = __builtin_amdgcn_mfma_f32_16x16x32_bf16(af[i], bfv[j], acc[i][j], 0, 0, 0);
        __syncthreads();
    }

    #pragma unroll
    for (int mi = 0; mi < 4; ++mi)
        #pragma unroll
        for (int ni = 0; ni < 2; ++ni)
            #pragma unroll
            for (int jr = 0; jr < 4; ++jr) {
                const long long row = bm + wm + mi * 16 + g * 4 + jr;
                const long long col = bn + wn + ni * 16 + fr;
                fC[row * (long long)N + col] = acc[mi][ni][jr];
            }
}

// ---------------- fused aw+adapt flash kernel ----------------
__global__ __launch_bounds__(256, 2) void fadapt_k(
    const unsigned short* __restrict__ adapt_in,
    const unsigned short* __restrict__ adapt_out,
    const unsigned short* __restrict__ adapt_inT,
    float* __restrict__ partial)
{
    __shared__ unsigned short P_lds[4 * 128 * 32];   // [t/32][row][t%32]
    __shared__ unsigned short Bs[128 * 32];

    const int b = blockIdx.z;
    const int q0 = blockIdx.y * 128;
    const int t0 = blockIdx.x * 256;

    const unsigned short* Qg = adapt_in + (long long)b * Sc * Ac;
    const unsigned short* Kg = adapt_out + (long long)b * Sc * Ac;
    const unsigned short* Vt = adapt_inT + (long long)b * Ac * Sc;

    const int tid = threadIdx.x;
    const int w = tid >> 6, l = tid & 63;
    const int wm = (w >> 1) * 64, wn = (w & 1) * 64;
    const int fr = l & 15, g = l >> 4;

    bf16x8 qf[4][4];
    for (int ks = 0; ks < 4; ++ks) {
        #pragma unroll
        for (int p = 0; p < 2; ++p) {
            const int c = p * 256 + tid;
            GLOAD16(Qg + (long long)(q0 + (c >> 2)) * Ac + ks * 32 + (c & 3) * 8, &Bs[c * 8]);
        }
        __syncthreads();
        #pragma unroll
        for (int i = 0; i < 4; ++i)
            qf[i][ks] = *(const bf16x8*)&Bs[(wm + i * 16 + fr) * 32 + g * 8];
        __syncthreads();
    }

    const f32x4 zero = { 0.f, 0.f, 0.f, 0.f };
    f32x4 acc[4][4];
    #pragma unroll
    for (int i = 0; i < 4; ++i)
        #pragma unroll
        for (int j = 0; j < 4; ++j) acc[i][j] = zero;

    #pragma unroll 1
    for (int ts = 0; ts < 2; ++ts) {
        const int t1 = t0 + ts * 128;
        f32x4 sacc[4][4];
        #pragma unroll
        for (int i = 0; i < 4; ++i)
            #pragma unroll
            for (int j = 0; j < 4; ++j) sacc[i][j] = zero;
        for (int ks = 0; ks < 4; ++ks) {
            #pragma unroll
            for (int p = 0; p < 2; ++p) {
                const int c = p * 256 + tid;
                GLOAD16(Kg + (long long)(t1 + (c >> 2)) * Ac + ks * 32 + (c & 3) * 8, &Bs[c * 8]);
            }
            __syncthreads();
            bf16x8 bfv[4];
            #pragma unroll
            for (int j = 0; j < 4; ++j)
                bfv[j] = *(const bf16x8*)&Bs[(wn + j * 16 + fr) * 32 + g * 8];
            #pragma unroll
            for (int i = 0; i < 4; ++i)
                #pragma unroll
                for (int j = 0; j < 4; ++j)
                    sacc[i][j] = __builtin_amdgcn_mfma_f32_16x16x32_bf16(qf[i][ks], bfv[j], sacc[i][j], 0, 0, 0);
            __syncthreads();
        }
        #pragma unroll
        for (int mi = 0; mi < 4; ++mi) {
            #pragma unroll
            for (int ni = 0; ni < 4; ++ni) {
                const int t = wn + ni * 16 + fr;
                const int base = (t >> 5) * 4096 + (t & 31);
                #pragma unroll
                for (int jr = 0; jr < 4; ++jr) {
                    const int row = wm + mi * 16 + g * 4 + jr;
                    float v = sacc[mi][ni][jr];
                    v = fminf(fmaxf(v, -5.f), 5.f);
                    P_lds[base + row * 32] = f2b(fsilu(v));
                }
            }
        }
        __syncthreads();
        for (int ks = 0; ks < 4; ++ks) {
            #pragma unroll
            for (int p = 0; p < 2; ++p) {
                const int c = p * 256 + tid;
                GLOAD16(Vt + (long long)(c >> 2) * Sc + t1 + ks * 32 + (c & 3) * 8, &Bs[c * 8]);
            }
            __syncthreads();
            bf16x8 af[4], bfv[4];
            #pragma unroll
            for (int i = 0; i < 4; ++i)
                af[i] = *(const bf16x8*)&P_lds[ks * 4096 + (wm + i * 16 + fr) * 32 + g * 8];
            #pragma unroll
            for (int j = 0; j < 4; ++j)
                bfv[j] = *(const bf16x8*)&Bs[(wn + j * 16 + fr) * 32 + g * 8];
            #pragma unroll
            for (int i = 0; i < 4; ++i)
                #pragma unroll
                for (int j = 0; j < 4; ++j)
                    acc[i][j] = __builtin_amdgcn_mfma_f32_16x16x32_bf16(af[i], bfv[j], acc[i][j], 0, 0, 0);
            __syncthreads();
        }
    }

    float* op = partial + ((long long)blockIdx.x * Bc + b) * Sc * Ac;
    #pragma unroll
    for (int mi = 0; mi < 4; ++mi)
        #pragma unroll
        for (int ni = 0; ni < 4; ++ni)
            #pragma unroll
            for (int jr = 0; jr < 4; ++jr) {
                const long long row = q0 + wm + mi * 16 + g * 4 + jr;
                const long long col = wn + ni * 16 + fr;
                op[row * Ac + col] = acc[mi][ni][jr];
            }
}

// ---------------- final fused 3-phase GEMM, 128x64 tile ----------------
__global__ __launch_bounds__(256, 2) void final_k(
    const unsigned short* __restrict__ hidden, const unsigned short* __restrict__ Wd,
    const unsigned short* __restrict__ adaptb, const unsigned short* __restrict__ Wdap,
    const unsigned short* __restrict__ h2v, const unsigned short* __restrict__ Wopep,
    const float* __restrict__ dmsum, float* __restrict__ out)
{
    __shared__ unsigned short As[128 * 32];
    __shared__ unsigned short Bs[64 * 32];

    const int nwg = gridDim.x * gridDim.y;
    const int flat = blockIdx.y * gridDim.x + blockIdx.x;
    const int swz = (flat & 7) * (nwg >> 3) + (flat >> 3);
    const int bx = swz % gridDim.x, by = swz / gridDim.x;
    const int bm = by * 128, bn = bx * 64;

    const int tid = threadIdx.x;
    const int w = tid >> 6, l = tid & 63;
    const int wm = (w >> 1) * 64, wn = (w & 1) * 32;
    const int fr = l & 15, g = l >> 4;

    const f32x4 zero = { 0.f, 0.f, 0.f, 0.f };
    f32x4 acc[4][2];
    #pragma unroll
    for (int i = 0; i < 4; ++i)
        #pragma unroll
        for (int j = 0; j < 2; ++j) acc[i][j] = zero;

    const unsigned short* Ap[3] = { hidden, adaptb, h2v };
    const unsigned short* Bp[3] = { Wd, Wdap, Wopep };
    const int Ks[3]  = { Hc, Ac, Ac };
    const int lds[3] = { Hc, Ac, Ac };

    #pragma unroll 1
    for (int ph = 0; ph < 3; ++ph) {
        if (ph == 2) {
            #pragma unroll
            for (int mi = 0; mi < 4; ++mi)
                #pragma unroll
                for (int jr = 0; jr < 4; ++jr) {
                    const float rs = dmsum[bm + wm + mi * 16 + g * 4 + jr];
                    #pragma unroll
                    for (int ni = 0; ni < 2; ++ni) acc[mi][ni][jr] *= rs;
                }
        }
        const unsigned short* A = Ap[ph];
        const unsigned short* B = Bp[ph];
        const int K = Ks[ph], ld = lds[ph];
        for (int k0 = 0; k0 < K; k0 += 32) {
            #pragma unroll
            for (int p = 0; p < 2; ++p) {
                const int c = p * 256 + tid;
                GLOAD16(A + (long long)(bm + (c >> 2)) * ld + k0 + (c & 3) * 8, &As[c * 8]);
            }
            GLOAD16(B + (long long)(bn + (tid >> 2)) * ld + k0 + (tid & 3) * 8, &Bs[tid * 8]);
            __syncthreads();
            bf16x8 af[4], bfv[2];
            #pragma unroll
            for (int i = 0; i < 4; ++i)
                af[i]  = *(const bf16x8*)&As[(wm + i * 16 + fr) * 32 + g * 8];
            #pragma unroll
            for (int j = 0; j < 2; ++j)
                bfv[j] = *(const bf16x8*)&Bs[(wn + j * 16 + fr) * 32 + g * 8];
            #pragma unroll
            for (int i = 0; i < 4; ++i)
                #pragma unroll
                for (int j = 0; j < 2; ++j)
                    acc[i][j] = __builtin_amdgcn_mfma_f32_16x16x32_bf16(af[i], bfv[j], acc[i][j], 0, 0, 0);
            __syncthreads();
        }
    }

    #pragma unroll
    for (int mi = 0; mi < 4; ++mi)
        #pragma unroll
        for (int ni = 0; ni < 2; ++ni)
            #pragma unroll
            for (int jr = 0; jr < 4; ++jr) {
                const long long row = bm + wm + mi * 16 + g * 4 + jr;
                const long long col = bn + wn + ni * 16 + fr;
                out[row * (long long)Dc + col] = acc[mi][ni][jr];
            }
}

// ---------------- partial-sum reduce: out = alpha * sum_p in[p*stride + i] ----
template<int NP, int BF>
__global__ __launch_bounds__(256) void reduce_k(const float* __restrict__ in,
                                                void* __restrict__ outp,
                                                long long pstride, int n4, float alpha)
{
    for (int i = blockIdx.x * 256 + threadIdx.x; i < n4; i += gridDim.x * 256) {
        float4 s = ((const float4*)in)[i];
        #pragma unroll
        for (int p = 1; p < NP; ++p) {
            const float4 v = ((const float4*)(in + (long long)p * pstride))[i];
            s.x += v.x; s.y += v.y; s.z += v.z; s.w += v.w;
        }
        s.x *= alpha; s.y *= alpha; s.z *= alpha; s.w *= alpha;
        if (BF) {
            us4 o = { f2b(s.x), f2b(s.y), f2b(s.z), f2b(s.w) };
            ((us4*)outp)[i] = o;
        } else {
            ((float4*)outp)[i] = s;
        }
    }
}

// ---------------- fp32 -> bf16 casts (batched) ----------------
struct CastJobs {
    const float* src[4];
    unsigned short* dst[4];
    int n4[4];
};
__global__ __launch_bounds__(256) void cast_k(CastJobs jobs) {
    const int b = blockIdx.y;
    const float4* s = (const float4*)jobs.src[b];
    us4* d = (us4*)jobs.dst[b];
    const int n = jobs.n4[b];
    for (int i = blockIdx.x * 256 + threadIdx.x; i < n; i += gridDim.x * 256) {
        const float4 v = s[i];
        us4 o;
        o.x = f2b(v.x); o.y = f2b(v.y); o.z = f2b(v.z); o.w = f2b(v.w);
        d[i] = o;
    }
}

// ---------------- gate/up interleaved + pre appended: Wcat[4224,1024] bf16 ----
__global__ __launch_bounds__(256) void gucast_k(const float* __restrict__ Wg,
                                                const float* __restrict__ Wu,
                                                const float* __restrict__ Wpre,
                                                unsigned short* __restrict__ Wcat)
{
    const int r = blockIdx.x;
    const float* src;
    int srcrow;
    if (r < 2 * Hc) {
        const int b = r >> 5, w = r & 31;
        src = (w < 16) ? Wg : Wu;
        srcrow = b * 16 + (w & 15);
    } else {
        src = Wpre;
        srcrow = r - 2 * Hc;
    }
    const float4 v = ((const float4*)(src + (long long)srcrow * Dc))[threadIdx.x];
    us4 o;
    o.x = f2b(v.x); o.y = f2b(v.y); o.z = f2b(v.z); o.w = f2b(v.w);
    ((us4*)(Wcat + (long long)r * Dc))[threadIdx.x] = o;
}

// ---------------- cast-transpose: f32 [2048,128] -> bf16 [128,2048], z=0/1 ----
__global__ __launch_bounds__(256) void ct_k(const float* __restrict__ in0,
                                            const float* __restrict__ in1,
                                            unsigned short* __restrict__ out0,
                                            unsigned short* __restrict__ out1)
{
    const float* in = blockIdx.z ? in1 : in0;
    unsigned short* out = blockIdx.z ? out1 : out0;
    const int t0 = blockIdx.x * 64, a0 = blockIdx.y * 64;
    __shared__ float T[64][68];
    const int rr = threadIdx.x >> 4, cc = (threadIdx.x & 15) * 4;
    #pragma unroll
    for (int p = 0; p < 4; ++p) {
        const int row = p * 16 + rr;
        *(float4*)&T[row][cc] = *(const float4*)&in[(long long)(t0 + row) * Ac + a0 + cc];
    }
    __syncthreads();
    #pragma unroll
    for (int p = 0; p < 4; ++p) {
        const int ar = p * 16 + rr;
        us4 o;
        o.x = f2b(T[cc + 0][ar]); o.y = f2b(T[cc + 1][ar]);
        o.z = f2b(T[cc + 2][ar]); o.w = f2b(T[cc + 3][ar]);
        *(us4*)&out[(long long)(a0 + ar) * Hc + t0 + cc] = o;
    }
}

// ---------------- LayerNorm over 128, one wave per row, bf16 out ----------------
__global__ __launch_bounds__(64) void ln_k(const float* __restrict__ in, unsigned short* __restrict__ out,
                                           const float* __restrict__ gg, const float* __restrict__ bb)
{
    const int row = blockIdx.x;
    const int lane = threadIdx.x;
    const float z0 = in[(long long)row * 128 + lane];
    const float z1 = in[(long long)row * 128 + 64 + lane];
    float s = z0 + z1;
    for (int o = 32; o > 0; o >>= 1) s += __shfl_down(s, o, 64);
    s = __shfl(s, 0, 64);
    const float mu = s * (1.f / 128.f);
    const float d0 = z0 - mu, d1 = z1 - mu;
    float v = d0 * d0 + d1 * d1;
    for (int o = 32; o > 0; o >>= 1) v += __shfl_down(v, o, 64);
    v = __shfl(v, 0, 64);
    const float r = rsqrtf(v * (1.f / 128.f) + LN_EPSc);
    out[(long long)row * 128 + lane] = f2b(d0 * r * gg[lane] + bb[lane]);
    out[(long long)row * 128 + 64 + lane] = f2b(d1 * r * gg[lane + 64] + bb[lane + 64]);
}

// ---------------- fused 4-way reduce + LayerNorm (post path) ----------------
__global__ __launch_bounds__(64) void redln_k(const float* __restrict__ in,
                                              unsigned short* __restrict__ out,
                                              const float* __restrict__ gg,
                                              const float* __restrict__ bb,
                                              long long pstride)
{
    const int row = blockIdx.x;
    const int lane = threadIdx.x;
    float z0 = 0.f, z1 = 0.f;
    #pragma unroll
    for (int p = 0; p < 4; ++p) {
        z0 += in[p * pstride + (long long)row * 128 + lane];
        z1 += in[p * pstride + (long long)row * 128 + 64 + lane];
    }
    float s = z0 + z1;
    for (int o = 32; o > 0; o >>= 1) s += __shfl_down(s, o, 64);
    s = __shfl(s, 0, 64);
    const float mu = s * (1.f / 128.f);
    const float d0 = z0 - mu, d1 = z1 - mu;
    float v = d0 * d0 + d1 * d1;
    for (int o = 32; o > 0; o >>= 1) v += __shfl_down(v, o, 64);
    v = __shfl(v, 0, 64);
    const float r = rsqrtf(v * (1.f / 128.f) + LN_EPSc);
    out[(long long)row * 128 + lane] = f2b(d0 * r * gg[lane] + bb[lane]);
    out[(long long)row * 128 + 64 + lane] = f2b(d1 * r * gg[lane + 64] + bb[lane + 64]);
}

// ---------------- transpose per batch: [2048,128] -> [128,2048] bf16 ----------------
__global__ __launch_bounds__(256) void trans_k(const unsigned short* __restrict__ in,
                                               unsigned short* __restrict__ out)
{
    const int z = blockIdx.z;
    const int t0 = blockIdx.x * 64, a0 = blockIdx.y * 64;
    __shared__ unsigned short T[64][72];
    const unsigned short* ip = in + (long long)z * Sc * Ac;
    unsigned short* op = out + (long long)z * Ac * Sc;
    const int rr = threadIdx.x >> 4, cc = (threadIdx.x & 15) * 4;
    #pragma unroll
    for (int p = 0; p < 4; ++p) {
        const int row = p * 16 + rr;
        *(us4*)&T[row][cc] = *(const us4*)&ip[(long long)(t0 + row) * Ac + a0 + cc];
    }
    __syncthreads();
    #pragma unroll
    for (int p = 0; p < 4; ++p) {
        const int arow = p * 16 + rr;
        us4 o;
        o.x = T[cc + 0][arow]; o.y = T[cc + 1][arow];
        o.z = T[cc + 2][arow]; o.w = T[cc + 3][arow];
        *(us4*)&op[(long long)(a0 + arow) * Sc + t0 + cc] = o;
    }
}

// ---------------- router: also emits xb (bf16 cast of x), NO global atomics ----
__global__ __launch_bounds__(256) void router_k(const float* __restrict__ x,
                                                const float* __restrict__ W_rg,
                                                const float* __restrict__ W_re,
                                                int* __restrict__ eidx, float* __restrict__ fw,
                                                float* __restrict__ dmsum,
                                                float* __restrict__ rpart,
                                                unsigned short* __restrict__ xb)
{
    const int wv = threadIdx.x >> 6;
    const int lane = threadIdx.x & 63;
    float load8[8] = {0.f, 0.f, 0.f, 0.f, 0.f, 0.f, 0.f, 0.f};
    float sqg = 0.f, sqe = 0.f;

    #pragma unroll
    for (int it = 0; it < 2; ++it) {
        const int t = blockIdx.x * 8 + wv * 2 + it;
        const float* xr = x + (long long)t * Dc;
        float a0 = 0, a1 = 0, a2 = 0, a3 = 0, a4 = 0, a5 = 0;
        #pragma unroll
        for (int j = 0; j < 16; ++j) {
            const int d = lane + 64 * j;
            const float xv = xr[d];
            xb[(long long)t * Dc + d] = f2b(xv);
            a0 += xv * W_rg[d];          a1 += xv * W_rg[Dc + d];
            a2 += xv * W_re[d];          a3 += xv * W_re[Dc + d];
            a4 += xv * W_re[2 * Dc + d]; a5 += xv * W_re[3 * Dc + d];
        }
        #pragma unroll
        for (int o = 32; o > 0; o >>= 1) {
            a0 += __shfl_xor(a0, o, 64); a1 += __shfl_xor(a1, o, 64);
            a2 += __shfl_xor(a2, o, 64); a3 += __shfl_xor(a3, o, 64);
            a4 += __shfl_xor(a4, o, 64); a5 += __shfl_xor(a5, o, 64);
        }
        if (lane == 0) {
            const float gl0 = a0, gl1 = a1;
            const float m = fmaxf(gl0, gl1);
            const float e0 = expf(gl0 - m), e1 = expf(gl1 - m);
            const float inv = 1.f / (e0 + e1);
            const float gp0 = e0 * inv, gp1 = e1 * inv;
            const int gidx = (gl1 > gl0) ? 1 : 0;
            const float gw = fmaxf(gp0, gp1);
            float el[4] = { a2, a3, a4, a5 };
            const float me = fmaxf(fmaxf(el[0], el[1]), fmaxf(el[2], el[3]));
            float ep[4]; float se = 0.f;
            #pragma unroll
            for (int i = 0; i < 4; ++i) { ep[i] = expf(el[i] - me); se += ep[i]; }
            const float invs = 1.f / se;
            #pragma unroll
            for (int i = 0; i < 4; ++i) ep[i] *= invs;
            int i0 = 0;
            #pragma unroll
            for (int i = 1; i < 4; ++i) if (ep[i] > ep[i0]) i0 = i;
            int i1 = -1;
            #pragma unroll
            for (int i = 0; i < 4; ++i) { if (i == i0) continue; if (i1 < 0 || ep[i] > ep[i1]) i1 = i; }
            const float w0 = ep[i0], w1 = ep[i1];
            const float sn = w0 + w1 + 1e-7f;
            const float f0 = gw * w0 / sn, f1 = gw * w1 / sn;
            const int ei0 = gidx * GSc + i0, ei1 = gidx * GSc + i1;
            eidx[t * 2] = ei0; eidx[t * 2 + 1] = ei1;
            fw[t * 2] = f0; fw[t * 2 + 1] = f1;
            dmsum[t] = f0 + f1;
            #pragma unroll
            for (int e = 0; e < 8; ++e)
                load8[e] += ((e == ei0) ? f0 : 0.f) + ((e == ei1) ? f1 : 0.f);
            sqg += gl0 * gl0 + gl1 * gl1;
            sqe += el[0] * el[0] + el[1] * el[1] + el[2] * el[2] + el[3] * el[3];
        }
    }
    __shared__ float sh[4][10];
    if (lane == 0) {
        #pragma unroll
        for (int e = 0; e < 8; ++e) sh[wv][e] = load8[e];
        sh[wv][8] = sqg; sh[wv][9] = sqe;
    }
    __syncthreads();
    if (threadIdx.x < 10) {
        rpart[blockIdx.x * 10 + threadIdx.x] =
            sh[0][threadIdx.x] + sh[1][threadIdx.x] + sh[2][threadIdx.x] + sh[3][threadIdx.x];
    }
}

// ---------------- loss reduce over RBLK partial rows ----------------
__global__ __launch_bounds__(512) void loss_k(const float* __restrict__ rpart,
                                              float* __restrict__ out_loss)
{
    const int tid = threadIdx.x;
    const int lane = tid & 63, wv = tid >> 6;
    float v[10];
    #pragma unroll
    for (int c = 0; c < 10; ++c) v[c] = rpart[tid * 10 + c];
    #pragma unroll
    for (int o = 32; o > 0; o >>= 1)
        #pragma unroll
        for (int c = 0; c < 10; ++c) v[c] += __shfl_xor(v[c], o, 64);
    __shared__ float sh[8][10];
    if (lane == 0) {
        #pragma unroll
        for (int c = 0; c < 10; ++c) sh[wv][c] = v[c];
    }
    __syncthreads();
    if (tid == 0) {
        float load[8]; float sqg = 0.f, sqe = 0.f;
        #pragma unroll
        for (int e = 0; e < 8; ++e) load[e] = 0.f;
        for (int wvi = 0; wvi < 8; ++wvi) {
            #pragma unroll
            for (int e = 0; e < 8; ++e) load[e] += sh[wvi][e];
            sqg += sh[wvi][8]; sqe += sh[wvi][9];
        }
        float s = 0.f;
        for (int e = 0; e < Ec; ++e) s += load[e];
        const float tgt = s / (float)Ec;
        float var = 0.f;
        for (int e = 0; e < Ec; ++e) { const float d = load[e] - tgt; var += d * d; }
        var /= (float)Ec;
        const float l = var + sqg / (float)(Nc * Gc) + sqe / (float)(Nc * GSc);
        *out_loss = 0.001f * l;
    }
}

// ---------------- combine: h2[t] = sum_slot fw * LN_e(h_dense[e][t]) ----------------
__global__ __launch_bounds__(128) void combine_k(const float* __restrict__ h_dense,
                                                 const float* __restrict__ ln_g_e,
                                                 const float* __restrict__ ln_b_e,
                                                 const int* __restrict__ eidx,
                                                 const float* __restrict__ fw,
                                                 unsigned short* __restrict__ h2)
{
    const int t = blockIdx.x;
    const int tid = threadIdx.x;
    __shared__ float red[2];

    float acc = 0.f;
    #pragma unroll
    for (int slot = 0; slot < 2; ++slot) {
        const int e = eidx[t * 2 + slot];
        const float w = fw[t * 2 + slot];
        const float h = h_dense[((long long)e * Nc + t) * 128 + tid];
        float v = h;
        for (int o = 32; o > 0; o >>= 1) v += __shfl_down(v, o, 64);
        if ((tid & 63) == 0) red[tid >> 6] = v;
        __syncthreads();
        const float mu = (red[0] + red[1]) * (1.f / 128.f);
        __syncthreads();
        const float d = h - mu;
        v = d * d;
        for (int o = 32; o > 0; o >>= 1) v += __shfl_down(v, o, 64);
        if ((tid & 63) == 0) red[tid >> 6] = v;
        __syncthreads();
        const float var = (red[0] + red[1]) * (1.f / 128.f);
        __syncthreads();
        acc += w * (d * rsqrtf(var + LN_EPSc) * ln_g_e[e * 128 + tid] + ln_b_e[e * 128 + tid]);
    }
    h2[(long long)t * 128 + tid] = f2b(acc);
}

// =====================================================================
extern "C" void kernel_launch(void* const* d_in, const int* in_sizes, int n_in,
                              void* d_out, int out_size, void* d_ws, size_t ws_size,
                              hipStream_t stream)
{
    const float* x       = (const float*)d_in[0];
    const float* W_up    = (const float*)d_in[1];
    const float* W_gate  = (const float*)d_in[2];
    const float* W_down  = (const float*)d_in[3];
    const float* W_pre   = (const float*)d_in[4];
    const float* W_post  = (const float*)d_in[5];
    const float* ln_g    = (const float*)d_in[6];
    const float* ln_b    = (const float*)d_in[7];
    const float* W_aproj = (const float*)d_in[8];
    const float* A_exp   = (const float*)d_in[9];
    const float* ln_g_e  = (const float*)d_in[10];
    const float* ln_b_e  = (const float*)d_in[11];
    const float* W_eproj = (const float*)d_in[12];
    const float* W_oproj = (const float*)d_in[13];
    const float* W_rg    = (const float*)d_in[14];
    const float* W_re    = (const float*)d_in[15];

    float* out = (float*)d_out;

    // ---- workspace carve ----
    char* p = (char*)d_ws;
    auto alloc = [&](size_t bytes) { void* r = (void*)p; p += (bytes + 255) & ~(size_t)255; return r; };
    float* pre      = (float*)alloc((size_t)Nc * Ac * 4);
    float* h_dense  = (float*)alloc((size_t)Ec * Nc * Ac * 4);   // 16.8 MB scratch: wprepP / postP / h_dense / adaptP
    float* rpart    = (float*)alloc((size_t)RBLK * 10 * 4);
    float* fw       = (float*)alloc((size_t)Nc * 2 * 4);
    float* dmsum    = (float*)alloc((size_t)Nc * 4);
    int*   eidx     = (int*)alloc((size_t)Nc * 2 * 4);
    unsigned short* xb      = (unsigned short*)alloc((size_t)Nc * Dc * 2);
    unsigned short* Wcat_b  = (unsigned short*)alloc((size_t)(2 * Hc + Ac) * Dc * 2);
    unsigned short* Wd_b    = (unsigned short*)alloc((size_t)Dc * Hc * 2);
    unsigned short* Wop_b   = (unsigned short*)alloc((size_t)Dc * Hc * 2);     // adjacent to Wd_b (4MB, 256B-aligned -> contiguous)
    unsigned short* Wpost_b = (unsigned short*)alloc((size_t)Ac * Hc * 2);
    unsigned short* WapT_b  = (unsigned short*)alloc((size_t)Ac * Hc * 2);
    unsigned short* WepT_b  = (unsigned short*)alloc((size_t)Ac * Hc * 2);     // adjacent to WapT_b
    unsigned short* Wdap_b  = (unsigned short*)alloc((size_t)Dc * Ac * 2);
    unsigned short* Wopep_b = (unsigned short*)alloc((size_t)Dc * Ac * 2);     // adjacent to Wdap_b
    unsigned short* Aexp_b  = (unsigned short*)alloc((size_t)Ec * Ac * Ac * 2);
    unsigned short* pre_b   = (unsigned short*)alloc((size_t)Nc * Ac * 2);
    unsigned short* hidden  = (unsigned short*)alloc((size_t)Nc * Hc * 2);
    unsigned short* adapt_in  = (unsigned short*)alloc((size_t)Nc * Ac * 2);
    unsigned short* adapt_inT = (unsigned short*)alloc((size_t)Nc * Ac * 2);
    unsigned short* adapt_out = (unsigned short*)alloc((size_t)Nc * Ac * 2);
    unsigned short* adaptb    = (unsigned short*)alloc((size_t)Nc * Ac * 2);
    unsigned short* h2        = (unsigned short*)alloc((size_t)Nc * Ac * 2);

    float* wprepP = h_dense;   // [4 split][2 pair][1024*128] f32
    float* postP  = h_dense;   // [4][4096*128] f32
    float* adaptP = h_dense;   // [8][2][2048*128] f32

    // ---- weight prep ----
    CastJobs jobs;
    jobs.src[0] = W_down;  jobs.dst[0] = Wd_b;    jobs.n4[0] = Dc * Hc / 4;
    jobs.src[1] = W_oproj; jobs.dst[1] = Wop_b;   jobs.n4[1] = Dc * Hc / 4;
    jobs.src[2] = W_post;  jobs.dst[2] = Wpost_b; jobs.n4[2] = Ac * Hc / 4;
    jobs.src[3] = A_exp;   jobs.dst[3] = Aexp_b;  jobs.n4[3] = Ec * Ac * Ac / 4;
    cast_k<<<dim3(128, 4), 256, 0, stream>>>(jobs);
    gucast_k<<<2 * Hc + Ac, 256, 0, stream>>>(W_gate, W_up, W_pre, Wcat_b);
    ct_k<<<dim3(Hc / 64, Ac / 64, 2), 256, 0, stream>>>(W_aproj, W_eproj, WapT_b, WepT_b);

    // ---- router (atomic-free, also emits xb) ----
    router_k<<<RBLK, 256, 0, stream>>>(x, W_rg, W_re, eidx, fw, dmsum, rpart, xb);
    loss_k<<<1, 512, 0, stream>>>(rpart, out + (size_t)Nc * Dc);

    // ---- Wdap/Wopep split-K (4x512), z=(pair,split), then alpha=0.1 reduce ----
    mgemm64<<<dim3(2, 8, 8), 256, 0, stream>>>(Wd_b, WapT_b, wprepP, Ac, 512, Hc, Hc,
        2,
        (long long)Dc * Hc, (long long)Ac * Hc, (long long)Dc * Ac,
        512, 512, (long long)2 * Dc * Ac);
    reduce_k<4, 1><<<256, 256, 0, stream>>>(wprepP, Wdap_b,
        (long long)2 * Dc * Ac, 2 * Dc * Ac / 4, 0.1f);

    // ---- fused gate+up+pre: hidden = silu(gate)*up ; pre (f32) + pre_b ----
    mgemm<9><<<dim3(33, 32), 256, 0, stream>>>(xb, Wcat_b, hidden, 2 * Hc + Ac, Dc, Dc, Dc, 0.f,
        pre, pre_b, 0, 0, 0);
    ln_k<<<Nc, 64, 0, stream>>>(pre, adapt_in, ln_g, ln_b);
    trans_k<<<dim3(Sc / 64, Ac / 64, Bc), 256, 0, stream>>>(adapt_in, adapt_inT);

    // ---- post split-K (4x512) -> fused reduce+LN -> adapt_out ----
    mgemm64<<<dim3(2, 32, 4), 256, 0, stream>>>(hidden, Wpost_b, postP, Ac, 512, Hc, Hc,
        8, 512, 512, (long long)Nc * Ac, 0, 0, 0);
    redln_k<<<Nc, 64, 0, stream>>>(postP, adapt_out, ln_g, ln_b, (long long)Nc * Ac);

    // ---- dense expert adapter: h_dense[e] = pre_b @ A_exp[e]^T ----
    mgemm64<<<dim3(2, 32, Ec), 256, 0, stream>>>(pre_b, Aexp_b, h_dense, Ac, Ac, Ac, Ac,
        16, 0, (long long)Ac * Ac, (long long)Nc * Ac, 0, 0, 0);
    combine_k<<<Nc, 128, 0, stream>>>(h_dense, ln_g_e, ln_b_e, eidx, fw, h2);

    // ---- fused aw+adapt flash kernel -> f32 partials -> adaptb (bf16) ----
    fadapt_k<<<dim3(8, 16, 2), 256, 0, stream>>>(adapt_in, adapt_out, adapt_inT, adaptP);
    reduce_k<8, 1><<<512, 256, 0, stream>>>(adaptP, adaptb,
        (long long)2 * Sc * Ac, 2 * Sc * Ac / 4, 1.f);

    // ---- final fused: out = dmsum*(hidden@Wd^T + adaptb@Wdap^T) + h2@Wopep^T ----
    final_k<<<dim3(Dc / 64, Nc / 128), 256, 0, stream>>>(
        hidden, Wd_b, adaptb, Wdap_b, h2, Wopep_b, dmsum, out);
}

// Round 9
// 198.149 us; speedup vs baseline: 8.1236x; 1.0130x over previous
//
#include <hip/hip_runtime.h>
#include <hip/hip_bf16.h>
#include <math.h>

static constexpr int Bc = 2;
static constexpr int Sc = 2048;
static constexpr int Dc = 1024;
static constexpr int Hc = 2048;
static constexpr int Ac = 128;
static constexpr int Ec = 8;
static constexpr int GSc = 4;
static constexpr int Gc = 2;
static constexpr int Nc = Bc * Sc;   // 4096 tokens
static constexpr float LN_EPSc = 1e-5f;
static constexpr int RBLK = 512;     // router blocks

typedef __attribute__((ext_vector_type(8))) short bf16x8;
typedef __attribute__((ext_vector_type(4))) float f32x4;
typedef __attribute__((ext_vector_type(4))) unsigned short us4;

__device__ __forceinline__ unsigned short f2b(float f) {
    union { float f; unsigned u; } v; v.f = f;
    return (unsigned short)((v.u + 0x7FFFu + ((v.u >> 16) & 1u)) >> 16);
}
__device__ __forceinline__ float b2f(unsigned short h) {
    union { unsigned u; float f; } v; v.u = (unsigned)h << 16; return v.f;
}
__device__ __forceinline__ float fsilu(float x) {
    return x / (1.f + __expf(-x));
}

#define GLOAD16(g, l) __builtin_amdgcn_global_load_lds( \
    (const __attribute__((address_space(1))) void*)(g), \
    (__attribute__((address_space(3))) void*)(l), 16, 0, 0)

// ---------------- bf16 MFMA GEMM, 128x128 tile, BK=64, bank-swizzled ----------
// C[M,N] = A[M,K] @ B[N,K]^T.  Swizzle: LDS slot (row, cl) holds global chunk
// cl ^ ((row>>1)&7); staging pre-swizzles the SOURCE (LDS dest stays linear),
// ds_read applies the same XOR. 2-way conflicts (free) instead of 8-way.
// EPI 9 = gateup paired silu + pre side-channel (aux=pre f32, aux2=pre_b bf16)
template<int EPI>
__global__ __launch_bounds__(256, 4) void mgemm(
    const unsigned short* __restrict__ Ag, const unsigned short* __restrict__ Bg,
    void* __restrict__ Cg, int N, int K, int lda, int ldb, float alpha,
    float* __restrict__ aux, void* __restrict__ aux2,
    long long sA, long long sB, long long sC)
{
    __shared__ unsigned short As[128 * 64];
    __shared__ unsigned short Bs[128 * 64];
    const unsigned short* A = Ag + (long long)blockIdx.z * sA;
    const unsigned short* B = Bg + (long long)blockIdx.z * sB;
    float* fC = (float*)Cg + (long long)blockIdx.z * sC;
    unsigned short* usC = (unsigned short*)Cg + (long long)blockIdx.z * sC;

    const int nwg = gridDim.x * gridDim.y;
    const int flat = blockIdx.y * gridDim.x + blockIdx.x;
    const int swz = (flat & 7) * (nwg >> 3) + (flat >> 3);
    const int bx = swz % gridDim.x, by = swz / gridDim.x;
    const int bm = by * 128, bn = bx * 128;

    const int tid = threadIdx.x;
    const int w = tid >> 6, l = tid & 63;
    const int wm = (w >> 1) * 64, wn = (w & 1) * 64;
    const int fr = l & 15, g = l >> 4;

    const f32x4 zero = { 0.f, 0.f, 0.f, 0.f };
    f32x4 acc[4][4];
    #pragma unroll
    for (int i = 0; i < 4; ++i)
        #pragma unroll
        for (int j = 0; j < 4; ++j) acc[i][j] = zero;

    for (int k0 = 0; k0 < K; k0 += 64) {
        #pragma unroll
        for (int p = 0; p < 4; ++p) {
            const int c = p * 256 + tid;
            const int row = c >> 3;
            const int gch = (c & 7) ^ ((c >> 4) & 7);
            GLOAD16(A + (long long)(bm + row) * lda + k0 + gch * 8, &As[c * 8]);
            GLOAD16(B + (long long)(bn + row) * ldb + k0 + gch * 8, &Bs[c * 8]);
        }
        __syncthreads();
        #pragma unroll
        for (int h = 0; h < 2; ++h) {
            bf16x8 af[4], bfv[4];
            #pragma unroll
            for (int i = 0; i < 4; ++i) {
                const int ra = wm + i * 16 + fr;
                af[i]  = *(const bf16x8*)&As[ra * 64 + ((h * 4 + g) ^ ((ra >> 1) & 7)) * 8];
                const int rb = wn + i * 16 + fr;
                bfv[i] = *(const bf16x8*)&Bs[rb * 64 + ((h * 4 + g) ^ ((rb >> 1) & 7)) * 8];
            }
            #pragma unroll
            for (int i = 0; i < 4; ++i)
                #pragma unroll
                for (int j = 0; j < 4; ++j)
                    acc[i][j] = __builtin_amdgcn_mfma_f32_16x16x32_bf16(af[i], bfv[j], acc[i][j], 0, 0, 0);
        }
        __syncthreads();
    }

    if (EPI == 9) {
        if (bn < 2 * Hc) {
            #pragma unroll
            for (int mi = 0; mi < 4; ++mi) {
                #pragma unroll
                for (int j = 0; j < 2; ++j) {
                    #pragma unroll
                    for (int jr = 0; jr < 4; ++jr) {
                        const long long row = bm + wm + mi * 16 + g * 4 + jr;
                        const long long colh = ((bn + wn) >> 1) + j * 16 + fr;
                        const float gv = acc[mi][2 * j][jr];
                        const float uv = acc[mi][2 * j + 1][jr];
                        usC[row * Hc + colh] = f2b(fsilu(gv) * uv);
                    }
                }
            }
        } else {
            unsigned short* preb = (unsigned short*)aux2;
            #pragma unroll
            for (int mi = 0; mi < 4; ++mi) {
                #pragma unroll
                for (int ni = 0; ni < 4; ++ni) {
                    #pragma unroll
                    for (int jr = 0; jr < 4; ++jr) {
                        const long long row = bm + wm + mi * 16 + g * 4 + jr;
                        const int lc = wn + ni * 16 + fr;
                        const float v = acc[mi][ni][jr];
                        aux[row * Ac + lc] = v;
                        preb[row * Ac + lc] = f2b(v);
                    }
                }
            }
        }
    } else {
        #pragma unroll
        for (int mi = 0; mi < 4; ++mi)
            #pragma unroll
            for (int ni = 0; ni < 4; ++ni)
                #pragma unroll
                for (int jr = 0; jr < 4; ++jr) {
                    const long long row = bm + wm + mi * 16 + g * 4 + jr;
                    const long long col = bn + wn + ni * 16 + fr;
                    const long long idx = row * (long long)N + col;
                    const float v = acc[mi][ni][jr];
                    if (EPI == 0) fC[idx] = v;
                    else usC[idx] = f2b(alpha * v);
                }
    }
}

// ---------------- bf16 MFMA GEMM, 128x64 tile (f32 out), 2-axis z decode ----
// (BK=32, unswizzled — used for small/split-K work where K may be 128-512)
__global__ __launch_bounds__(256, 2) void mgemm64(
    const unsigned short* __restrict__ Ag, const unsigned short* __restrict__ Bg,
    float* __restrict__ Cg, int N, int K, int lda, int ldb, int zmod,
    long long sA1, long long sB1, long long sC1,
    long long sA2, long long sB2, long long sC2)
{
    __shared__ unsigned short As[128 * 32];
    __shared__ unsigned short Bs[64 * 32];
    const int z1 = blockIdx.z % zmod, z2 = blockIdx.z / zmod;
    const unsigned short* A = Ag + (long long)z1 * sA1 + (long long)z2 * sA2;
    const unsigned short* B = Bg + (long long)z1 * sB1 + (long long)z2 * sB2;
    float* fC = Cg + (long long)z1 * sC1 + (long long)z2 * sC2;

    const int nwg = gridDim.x * gridDim.y;
    const int flat = blockIdx.y * gridDim.x + blockIdx.x;
    const int swz = (flat & 7) * (nwg >> 3) + (flat >> 3);
    const int bx = swz % gridDim.x, by = swz / gridDim.x;
    const int bm = by * 128, bn = bx * 64;

    const int tid = threadIdx.x;
    const int w = tid >> 6, l = tid & 63;
    const int wm = (w >> 1) * 64, wn = (w & 1) * 32;
    const int fr = l & 15, g = l >> 4;

    const f32x4 zero = { 0.f, 0.f, 0.f, 0.f };
    f32x4 acc[4][2];
    #pragma unroll
    for (int i = 0; i < 4; ++i)
        #pragma unroll
        for (int j = 0; j < 2; ++j) acc[i][j] = zero;

    for (int k0 = 0; k0 < K; k0 += 32) {
        #pragma unroll
        for (int p = 0; p < 2; ++p) {
            const int c = p * 256 + tid;
            GLOAD16(A + (long long)(bm + (c >> 2)) * lda + k0 + (c & 3) * 8, &As[c * 8]);
        }
        GLOAD16(B + (long long)(bn + (tid >> 2)) * ldb + k0 + (tid & 3) * 8, &Bs[tid * 8]);
        __syncthreads();
        bf16x8 af[4], bfv[2];
        #pragma unroll
        for (int i = 0; i < 4; ++i)
            af[i]  = *(const bf16x8*)&As[(wm + i * 16 + fr) * 32 + g * 8];
        #pragma unroll
        for (int j = 0; j < 2; ++j)
            bfv[j] = *(const bf16x8*)&Bs[(wn + j * 16 + fr) * 32 + g * 8];
        #pragma unroll
        for (int i = 0; i < 4; ++i)
            #pragma unroll
            for (int j = 0; j < 2; ++j)
                acc[i][j] = __builtin_amdgcn_mfma_f32_16x16x32_bf16(af[i], bfv[j], acc[i][j], 0, 0, 0);
        __syncthreads();
    }

    #pragma unroll
    for (int mi = 0; mi < 4; ++mi)
        #pragma unroll
        for (int ni = 0; ni < 2; ++ni)
            #pragma unroll
            for (int jr = 0; jr < 4; ++jr) {
                const long long row = bm + wm + mi * 16 + g * 4 + jr;
                const long long col = bn + wn + ni * 16 + fr;
                fC[row * (long long)N + col] = acc[mi][ni][jr];
            }
}

// ---------------- fused aw+adapt flash kernel ----------------
__global__ __launch_bounds__(256, 2) void fadapt_k(
    const unsigned short* __restrict__ adapt_in,
    const unsigned short* __restrict__ adapt_out,
    const unsigned short* __restrict__ adapt_inT,
    float* __restrict__ partial)
{
    __shared__ unsigned short P_lds[4 * 128 * 32];   // [t/32][row][t%32]
    __shared__ unsigned short Bs[128 * 32];

    const int b = blockIdx.z;
    const int q0 = blockIdx.y * 128;
    const int t0 = blockIdx.x * 256;

    const unsigned short* Qg = adapt_in + (long long)b * Sc * Ac;
    const unsigned short* Kg = adapt_out + (long long)b * Sc * Ac;
    const unsigned short* Vt = adapt_inT + (long long)b * Ac * Sc;

    const int tid = threadIdx.x;
    const int w = tid >> 6, l = tid & 63;
    const int wm = (w >> 1) * 64, wn = (w & 1) * 64;
    const int fr = l & 15, g = l >> 4;

    bf16x8 qf[4][4];
    for (int ks = 0; ks < 4; ++ks) {
        #pragma unroll
        for (int p = 0; p < 2; ++p) {
            const int c = p * 256 + tid;
            GLOAD16(Qg + (long long)(q0 + (c >> 2)) * Ac + ks * 32 + (c & 3) * 8, &Bs[c * 8]);
        }
        __syncthreads();
        #pragma unroll
        for (int i = 0; i < 4; ++i)
            qf[i][ks] = *(const bf16x8*)&Bs[(wm + i * 16 + fr) * 32 + g * 8];
        __syncthreads();
    }

    const f32x4 zero = { 0.f, 0.f, 0.f, 0.f };
    f32x4 acc[4][4];
    #pragma unroll
    for (int i = 0; i < 4; ++i)
        #pragma unroll
        for (int j = 0; j < 4; ++j) acc[i][j] = zero;

    #pragma unroll 1
    for (int ts = 0; ts < 2; ++ts) {
        const int t1 = t0 + ts * 128;
        f32x4 sacc[4][4];
        #pragma unroll
        for (int i = 0; i < 4; ++i)
            #pragma unroll
            for (int j = 0; j < 4; ++j) sacc[i][j] = zero;
        for (int ks = 0; ks < 4; ++ks) {
            #pragma unroll
            for (int p = 0; p < 2; ++p) {
                const int c = p * 256 + tid;
                GLOAD16(Kg + (long long)(t1 + (c >> 2)) * Ac + ks * 32 + (c & 3) * 8, &Bs[c * 8]);
            }
            __syncthreads();
            bf16x8 bfv[4];
            #pragma unroll
            for (int j = 0; j < 4; ++j)
                bfv[j] = *(const bf16x8*)&Bs[(wn + j * 16 + fr) * 32 + g * 8];
            #pragma unroll
            for (int i = 0; i < 4; ++i)
                #pragma unroll
                for (int j = 0; j < 4; ++j)
                    sacc[i][j] = __builtin_amdgcn_mfma_f32_16x16x32_bf16(qf[i][ks], bfv[j], sacc[i][j], 0, 0, 0);
            __syncthreads();
        }
        #pragma unroll
        for (int mi = 0; mi < 4; ++mi) {
            #pragma unroll
            for (int ni = 0; ni < 4; ++ni) {
                const int t = wn + ni * 16 + fr;
                const int base = (t >> 5) * 4096 + (t & 31);
                #pragma unroll
                for (int jr = 0; jr < 4; ++jr) {
                    const int row = wm + mi * 16 + g * 4 + jr;
                    float v = sacc[mi][ni][jr];
                    v = fminf(fmaxf(v, -5.f), 5.f);
                    P_lds[base + row * 32] = f2b(fsilu(v));
                }
            }
        }
        __syncthreads();
        for (int ks = 0; ks < 4; ++ks) {
            #pragma unroll
            for (int p = 0; p < 2; ++p) {
                const int c = p * 256 + tid;
                GLOAD16(Vt + (long long)(c >> 2) * Sc + t1 + ks * 32 + (c & 3) * 8, &Bs[c * 8]);
            }
            __syncthreads();
            bf16x8 af[4], bfv[4];
            #pragma unroll
            for (int i = 0; i < 4; ++i)
                af[i] = *(const bf16x8*)&P_lds[ks * 4096 + (wm + i * 16 + fr) * 32 + g * 8];
            #pragma unroll
            for (int j = 0; j < 4; ++j)
                bfv[j] = *(const bf16x8*)&Bs[(wn + j * 16 + fr) * 32 + g * 8];
            #pragma unroll
            for (int i = 0; i < 4; ++i)
                #pragma unroll
                for (int j = 0; j < 4; ++j)
                    acc[i][j] = __builtin_amdgcn_mfma_f32_16x16x32_bf16(af[i], bfv[j], acc[i][j], 0, 0, 0);
            __syncthreads();
        }
    }

    float* op = partial + ((long long)blockIdx.x * Bc + b) * Sc * Ac;
    #pragma unroll
    for (int mi = 0; mi < 4; ++mi)
        #pragma unroll
        for (int ni = 0; ni < 4; ++ni)
            #pragma unroll
            for (int jr = 0; jr < 4; ++jr) {
                const long long row = q0 + wm + mi * 16 + g * 4 + jr;
                const long long col = wn + ni * 16 + fr;
                op[row * Ac + col] = acc[mi][ni][jr];
            }
}

// ---------------- final fused 3-phase GEMM, 128x64 tile, BK=64, swizzled ------
__global__ __launch_bounds__(256, 2) void final_k(
    const unsigned short* __restrict__ hidden, const unsigned short* __restrict__ Wd,
    const unsigned short* __restrict__ adaptb, const unsigned short* __restrict__ Wdap,
    const unsigned short* __restrict__ h2v, const unsigned short* __restrict__ Wopep,
    const float* __restrict__ dmsum, float* __restrict__ out)
{
    __shared__ unsigned short As[128 * 64];
    __shared__ unsigned short Bs[64 * 64];

    const int nwg = gridDim.x * gridDim.y;
    const int flat = blockIdx.y * gridDim.x + blockIdx.x;
    const int swz = (flat & 7) * (nwg >> 3) + (flat >> 3);
    const int bx = swz % gridDim.x, by = swz / gridDim.x;
    const int bm = by * 128, bn = bx * 64;

    const int tid = threadIdx.x;
    const int w = tid >> 6, l = tid & 63;
    const int wm = (w >> 1) * 64, wn = (w & 1) * 32;
    const int fr = l & 15, g = l >> 4;

    const f32x4 zero = { 0.f, 0.f, 0.f, 0.f };
    f32x4 acc[4][2];
    #pragma unroll
    for (int i = 0; i < 4; ++i)
        #pragma unroll
        for (int j = 0; j < 2; ++j) acc[i][j] = zero;

    const unsigned short* Ap[3] = { hidden, adaptb, h2v };
    const unsigned short* Bp[3] = { Wd, Wdap, Wopep };
    const int Ks[3]  = { Hc, Ac, Ac };
    const int lds[3] = { Hc, Ac, Ac };

    #pragma unroll 1
    for (int ph = 0; ph < 3; ++ph) {
        if (ph == 2) {
            #pragma unroll
            for (int mi = 0; mi < 4; ++mi)
                #pragma unroll
                for (int jr = 0; jr < 4; ++jr) {
                    const float rs = dmsum[bm + wm + mi * 16 + g * 4 + jr];
                    #pragma unroll
                    for (int ni = 0; ni < 2; ++ni) acc[mi][ni][jr] *= rs;
                }
        }
        const unsigned short* A = Ap[ph];
        const unsigned short* B = Bp[ph];
        const int K = Ks[ph], ld = lds[ph];
        for (int k0 = 0; k0 < K; k0 += 64) {
            #pragma unroll
            for (int p = 0; p < 4; ++p) {
                const int c = p * 256 + tid;
                const int row = c >> 3;
                const int gch = (c & 7) ^ ((c >> 4) & 7);
                GLOAD16(A + (long long)(bm + row) * ld + k0 + gch * 8, &As[c * 8]);
            }
            #pragma unroll
            for (int p = 0; p < 2; ++p) {
                const int c = p * 256 + tid;
                const int row = c >> 3;
                const int gch = (c & 7) ^ ((c >> 4) & 7);
                GLOAD16(B + (long long)(bn + row) * ld + k0 + gch * 8, &Bs[c * 8]);
            }
            __syncthreads();
            #pragma unroll
            for (int h = 0; h < 2; ++h) {
                bf16x8 af[4], bfv[2];
                #pragma unroll
                for (int i = 0; i < 4; ++i) {
                    const int ra = wm + i * 16 + fr;
                    af[i]  = *(const bf16x8*)&As[ra * 64 + ((h * 4 + g) ^ ((ra >> 1) & 7)) * 8];
                }
                #pragma unroll
                for (int j = 0; j < 2; ++j) {
                    const int rb = wn + j * 16 + fr;
                    bfv[j] = *(const bf16x8*)&Bs[rb * 64 + ((h * 4 + g) ^ ((rb >> 1) & 7)) * 8];
                }
                #pragma unroll
                for (int i = 0; i < 4; ++i)
                    #pragma unroll
                    for (int j = 0; j < 2; ++j)
                        acc[i][j] = __builtin_amdgcn_mfma_f32_16x16x32_bf16(af[i], bfv[j], acc[i][j], 0, 0, 0);
            }
            __syncthreads();
        }
    }

    #pragma unroll
    for (int mi = 0; mi < 4; ++mi)
        #pragma unroll
        for (int ni = 0; ni < 2; ++ni)
            #pragma unroll
            for (int jr = 0; jr < 4; ++jr) {
                const long long row = bm + wm + mi * 16 + g * 4 + jr;
                const long long col = bn + wn + ni * 16 + fr;
                out[row * (long long)Dc + col] = acc[mi][ni][jr];
            }
}

// ---------------- partial-sum reduce: out = alpha * sum_p in[p*stride + i] ----
template<int NP, int BF>
__global__ __launch_bounds__(256) void reduce_k(const float* __restrict__ in,
                                                void* __restrict__ outp,
                                                long long pstride, int n4, float alpha)
{
    for (int i = blockIdx.x * 256 + threadIdx.x; i < n4; i += gridDim.x * 256) {
        float4 s = ((const float4*)in)[i];
        #pragma unroll
        for (int p = 1; p < NP; ++p) {
            const float4 v = ((const float4*)(in + (long long)p * pstride))[i];
            s.x += v.x; s.y += v.y; s.z += v.z; s.w += v.w;
        }
        s.x *= alpha; s.y *= alpha; s.z *= alpha; s.w *= alpha;
        if (BF) {
            us4 o = { f2b(s.x), f2b(s.y), f2b(s.z), f2b(s.w) };
            ((us4*)outp)[i] = o;
        } else {
            ((float4*)outp)[i] = s;
        }
    }
}

// ---------------- merged weight prep: casts + gate/up interleave + transpose --
struct PrepArgs {
    const float* csrc[4]; unsigned short* cdst[4]; int cn4[4];
    const float* Wg; const float* Wu; const float* Wpre; unsigned short* Wcat;
    const float* tin0; const float* tin1; unsigned short* tout0; unsigned short* tout1;
};
__global__ __launch_bounds__(256) void prep_k(PrepArgs a)
{
    __shared__ float T[64][68];
    const int y = blockIdx.y;
    if (y < 4) {
        const float4* s = (const float4*)a.csrc[y];
        us4* d = (us4*)a.cdst[y];
        const int n = a.cn4[y];
        for (int i = blockIdx.x * 256 + threadIdx.x; i < n; i += gridDim.x * 256) {
            const float4 v = s[i];
            us4 o;
            o.x = f2b(v.x); o.y = f2b(v.y); o.z = f2b(v.z); o.w = f2b(v.w);
            d[i] = o;
        }
    } else if (y == 4) {
        const int total = (2 * Hc + Ac) * 256;
        for (int u = blockIdx.x * 256 + threadIdx.x; u < total; u += gridDim.x * 256) {
            const int r = u >> 8, t = u & 255;
            const float* src; int srcrow;
            if (r < 2 * Hc) {
                const int b = r >> 5, wq = r & 31;
                src = (wq < 16) ? a.Wg : a.Wu;
                srcrow = b * 16 + (wq & 15);
            } else {
                src = a.Wpre;
                srcrow = r - 2 * Hc;
            }
            const float4 v = ((const float4*)(src + (long long)srcrow * Dc))[t];
            us4 o;
            o.x = f2b(v.x); o.y = f2b(v.y); o.z = f2b(v.z); o.w = f2b(v.w);
            ((us4*)(a.Wcat + (long long)r * Dc))[t] = o;
        }
    } else {
        // transpose-cast W_aproj / W_eproj: [2048,128] f32 -> [128,2048] bf16
        const int rr = threadIdx.x >> 4, cc = (threadIdx.x & 15) * 4;
        for (int tb = blockIdx.x; tb < 128; tb += gridDim.x) {
            const int z = tb >> 6, rem = tb & 63;
            const int a0 = (rem >> 5) * 64, t0 = (rem & 31) * 64;
            const float* in = z ? a.tin1 : a.tin0;
            unsigned short* outp = z ? a.tout1 : a.tout0;
            __syncthreads();
            #pragma unroll
            for (int p = 0; p < 4; ++p) {
                const int row = p * 16 + rr;
                *(float4*)&T[row][cc] = *(const float4*)&in[(long long)(t0 + row) * Ac + a0 + cc];
            }
            __syncthreads();
            #pragma unroll
            for (int p = 0; p < 4; ++p) {
                const int ar = p * 16 + rr;
                us4 o;
                o.x = f2b(T[cc + 0][ar]); o.y = f2b(T[cc + 1][ar]);
                o.z = f2b(T[cc + 2][ar]); o.w = f2b(T[cc + 3][ar]);
                *(us4*)&outp[(long long)(a0 + ar) * Hc + t0 + cc] = o;
            }
        }
    }
}

// ---------------- fused LayerNorm + transpose (pre -> adapt_in, adapt_inT) ----
__global__ __launch_bounds__(256) void lntr_k(const float* __restrict__ in,
                                              unsigned short* __restrict__ outn,
                                              unsigned short* __restrict__ outt,
                                              const float* __restrict__ gg,
                                              const float* __restrict__ bb)
{
    __shared__ unsigned short L[64][130];
    const int z = blockIdx.y;
    const int t0 = blockIdx.x * 64;
    const int wv = threadIdx.x >> 6, lane = threadIdx.x & 63;
    const float g0 = gg[lane], g1 = gg[lane + 64];
    const float b0 = bb[lane], b1 = bb[lane + 64];

    #pragma unroll 4
    for (int it = 0; it < 16; ++it) {
        const int row = wv * 16 + it;
        const long long gr = (long long)(z * Sc + t0 + row) * 128;
        const float z0 = in[gr + lane], z1 = in[gr + 64 + lane];
        float s = z0 + z1;
        #pragma unroll
        for (int o = 32; o > 0; o >>= 1) s += __shfl_xor(s, o, 64);
        const float mu = s * (1.f / 128.f);
        const float d0 = z0 - mu, d1 = z1 - mu;
        float v = d0 * d0 + d1 * d1;
        #pragma unroll
        for (int o = 32; o > 0; o >>= 1) v += __shfl_xor(v, o, 64);
        const float r = rsqrtf(v * (1.f / 128.f) + LN_EPSc);
        L[row][lane] = f2b(d0 * r * g0 + b0);
        L[row][lane + 64] = f2b(d1 * r * g1 + b1);
    }
    __syncthreads();
    {
        const int row = threadIdx.x >> 2, seg = (threadIdx.x & 3) * 32;
        #pragma unroll
        for (int j = 0; j < 8; ++j)
            *(us4*)&outn[(long long)(z * Sc + t0 + row) * 128 + seg + j * 4] =
                *(const us4*)&L[row][seg + j * 4];
    }
    {
        const int a = threadIdx.x >> 1, tt0 = (threadIdx.x & 1) * 32;
        #pragma unroll
        for (int j4 = 0; j4 < 8; ++j4) {
            us4 o;
            o.x = L[tt0 + j4 * 4 + 0][a]; o.y = L[tt0 + j4 * 4 + 1][a];
            o.z = L[tt0 + j4 * 4 + 2][a]; o.w = L[tt0 + j4 * 4 + 3][a];
            *(us4*)&outt[(long long)z * Ac * Sc + (long long)a * Sc + t0 + tt0 + j4 * 4] = o;
        }
    }
}

// ---------------- fused 4-way reduce + LayerNorm (post path) ----------------
__global__ __launch_bounds__(64) void redln_k(const float* __restrict__ in,
                                              unsigned short* __restrict__ out,
                                              const float* __restrict__ gg,
                                              const float* __restrict__ bb,
                                              long long pstride)
{
    const int row = blockIdx.x;
    const int lane = threadIdx.x;
    float z0 = 0.f, z1 = 0.f;
    #pragma unroll
    for (int p = 0; p < 4; ++p) {
        z0 += in[p * pstride + (long long)row * 128 + lane];
        z1 += in[p * pstride + (long long)row * 128 + 64 + lane];
    }
    float s = z0 + z1;
    for (int o = 32; o > 0; o >>= 1) s += __shfl_xor(s, o, 64);
    const float mu = s * (1.f / 128.f);
    const float d0 = z0 - mu, d1 = z1 - mu;
    float v = d0 * d0 + d1 * d1;
    for (int o = 32; o > 0; o >>= 1) v += __shfl_xor(v, o, 64);
    const float r = rsqrtf(v * (1.f / 128.f) + LN_EPSc);
    out[(long long)row * 128 + lane] = f2b(d0 * r * gg[lane] + bb[lane]);
    out[(long long)row * 128 + 64 + lane] = f2b(d1 * r * gg[lane + 64] + bb[lane + 64]);
}

// ---------------- router: also emits xb (bf16 cast of x), NO global atomics ----
__global__ __launch_bounds__(256) void router_k(const float* __restrict__ x,
                                                const float* __restrict__ W_rg,
                                                const float* __restrict__ W_re,
                                                int* __restrict__ eidx, float* __restrict__ fw,
                                                float* __restrict__ dmsum,
                                                float* __restrict__ rpart,
                                                unsigned short* __restrict__ xb)
{
    const int wv = threadIdx.x >> 6;
    const int lane = threadIdx.x & 63;
    float load8[8] = {0.f, 0.f, 0.f, 0.f, 0.f, 0.f, 0.f, 0.f};
    float sqg = 0.f, sqe = 0.f;

    #pragma unroll
    for (int it = 0; it < 2; ++it) {
        const int t = blockIdx.x * 8 + wv * 2 + it;
        const float* xr = x + (long long)t * Dc;
        float a0 = 0, a1 = 0, a2 = 0, a3 = 0, a4 = 0, a5 = 0;
        #pragma unroll
        for (int j = 0; j < 16; ++j) {
            const int d = lane + 64 * j;
            const float xv = xr[d];
            xb[(long long)t * Dc + d] = f2b(xv);
            a0 += xv * W_rg[d];          a1 += xv * W_rg[Dc + d];
            a2 += xv * W_re[d];          a3 += xv * W_re[Dc + d];
            a4 += xv * W_re[2 * Dc + d]; a5 += xv * W_re[3 * Dc + d];
        }
        #pragma unroll
        for (int o = 32; o > 0; o >>= 1) {
            a0 += __shfl_xor(a0, o, 64); a1 += __shfl_xor(a1, o, 64);
            a2 += __shfl_xor(a2, o, 64); a3 += __shfl_xor(a3, o, 64);
            a4 += __shfl_xor(a4, o, 64); a5 += __shfl_xor(a5, o, 64);
        }
        if (lane == 0) {
            const float gl0 = a0, gl1 = a1;
            const float m = fmaxf(gl0, gl1);
            const float e0 = expf(gl0 - m), e1 = expf(gl1 - m);
            const float inv = 1.f / (e0 + e1);
            const float gp0 = e0 * inv, gp1 = e1 * inv;
            const int gidx = (gl1 > gl0) ? 1 : 0;
            const float gw = fmaxf(gp0, gp1);
            float el[4] = { a2, a3, a4, a5 };
            const float me = fmaxf(fmaxf(el[0], el[1]), fmaxf(el[2], el[3]));
            float ep[4]; float se = 0.f;
            #pragma unroll
            for (int i = 0; i < 4; ++i) { ep[i] = expf(el[i] - me); se += ep[i]; }
            const float invs = 1.f / se;
            #pragma unroll
            for (int i = 0; i < 4; ++i) ep[i] *= invs;
            int i0 = 0;
            #pragma unroll
            for (int i = 1; i < 4; ++i) if (ep[i] > ep[i0]) i0 = i;
            int i1 = -1;
            #pragma unroll
            for (int i = 0; i < 4; ++i) { if (i == i0) continue; if (i1 < 0 || ep[i] > ep[i1]) i1 = i; }
            const float w0 = ep[i0], w1 = ep[i1];
            const float sn = w0 + w1 + 1e-7f;
            const float f0 = gw * w0 / sn, f1 = gw * w1 / sn;
            const int ei0 = gidx * GSc + i0, ei1 = gidx * GSc + i1;
            eidx[t * 2] = ei0; eidx[t * 2 + 1] = ei1;
            fw[t * 2] = f0; fw[t * 2 + 1] = f1;
            dmsum[t] = f0 + f1;
            #pragma unroll
            for (int e = 0; e < 8; ++e)
                load8[e] += ((e == ei0) ? f0 : 0.f) + ((e == ei1) ? f1 : 0.f);
            sqg += gl0 * gl0 + gl1 * gl1;
            sqe += el[0] * el[0] + el[1] * el[1] + el[2] * el[2] + el[3] * el[3];
        }
    }
    __shared__ float sh[4][10];
    if (lane == 0) {
        #pragma unroll
        for (int e = 0; e < 8; ++e) sh[wv][e] = load8[e];
        sh[wv][8] = sqg; sh[wv][9] = sqe;
    }
    __syncthreads();
    if (threadIdx.x < 10) {
        rpart[blockIdx.x * 10 + threadIdx.x] =
            sh[0][threadIdx.x] + sh[1][threadIdx.x] + sh[2][threadIdx.x] + sh[3][threadIdx.x];
    }
}

// ---------------- loss reduce over RBLK partial rows ----------------
__global__ __launch_bounds__(512) void loss_k(const float* __restrict__ rpart,
                                              float* __restrict__ out_loss)
{
    const int tid = threadIdx.x;
    const int lane = tid & 63, wv = tid >> 6;
    float v[10];
    #pragma unroll
    for (int c = 0; c < 10; ++c) v[c] = rpart[tid * 10 + c];
    #pragma unroll
    for (int o = 32; o > 0; o >>= 1)
        #pragma unroll
        for (int c = 0; c < 10; ++c) v[c] += __shfl_xor(v[c], o, 64);
    __shared__ float sh[8][10];
    if (lane == 0) {
        #pragma unroll
        for (int c = 0; c < 10; ++c) sh[wv][c] = v[c];
    }
    __syncthreads();
    if (tid == 0) {
        float load[8]; float sqg = 0.f, sqe = 0.f;
        #pragma unroll
        for (int e = 0; e < 8; ++e) load[e] = 0.f;
        for (int wvi = 0; wvi < 8; ++wvi) {
            #pragma unroll
            for (int e = 0; e < 8; ++e) load[e] += sh[wvi][e];
            sqg += sh[wvi][8]; sqe += sh[wvi][9];
        }
        float s = 0.f;
        for (int e = 0; e < Ec; ++e) s += load[e];
        const float tgt = s / (float)Ec;
        float var = 0.f;
        for (int e = 0; e < Ec; ++e) { const float d = load[e] - tgt; var += d * d; }
        var /= (float)Ec;
        const float l = var + sqg / (float)(Nc * Gc) + sqe / (float)(Nc * GSc);
        *out_loss = 0.001f * l;
    }
}

// ---------------- combine: h2[t] = sum_slot fw * LN_e(h_dense[e][t]) ----------------
__global__ __launch_bounds__(128) void combine_k(const float* __restrict__ h_dense,
                                                 const float* __restrict__ ln_g_e,
                                                 const float* __restrict__ ln_b_e,
                                                 const int* __restrict__ eidx,
                                                 const float* __restrict__ fw,
                                                 unsigned short* __restrict__ h2)
{
    const int t = blockIdx.x;
    const int tid = threadIdx.x;
    __shared__ float red[2];

    float acc = 0.f;
    #pragma unroll
    for (int slot = 0; slot < 2; ++slot) {
        const int e = eidx[t * 2 + slot];
        const float w = fw[t * 2 + slot];
        const float h = h_dense[((long long)e * Nc + t) * 128 + tid];
        float v = h;
        for (int o = 32; o > 0; o >>= 1) v += __shfl_down(v, o, 64);
        if ((tid & 63) == 0) red[tid >> 6] = v;
        __syncthreads();
        const float mu = (red[0] + red[1]) * (1.f / 128.f);
        __syncthreads();
        const float d = h - mu;
        v = d * d;
        for (int o = 32; o > 0; o >>= 1) v += __shfl_down(v, o, 64);
        if ((tid & 63) == 0) red[tid >> 6] = v;
        __syncthreads();
        const float var = (red[0] + red[1]) * (1.f / 128.f);
        __syncthreads();
        acc += w * (d * rsqrtf(var + LN_EPSc) * ln_g_e[e * 128 + tid] + ln_b_e[e * 128 + tid]);
    }
    h2[(long long)t * 128 + tid] = f2b(acc);
}

// =====================================================================
extern "C" void kernel_launch(void* const* d_in, const int* in_sizes, int n_in,
                              void* d_out, int out_size, void* d_ws, size_t ws_size,
                              hipStream_t stream)
{
    const float* x       = (const float*)d_in[0];
    const float* W_up    = (const float*)d_in[1];
    const float* W_gate  = (const float*)d_in[2];
    const float* W_down  = (const float*)d_in[3];
    const float* W_pre   = (const float*)d_in[4];
    const float* W_post  = (const float*)d_in[5];
    const float* ln_g    = (const float*)d_in[6];
    const float* ln_b    = (const float*)d_in[7];
    const float* W_aproj = (const float*)d_in[8];
    const float* A_exp   = (const float*)d_in[9];
    const float* ln_g_e  = (const float*)d_in[10];
    const float* ln_b_e  = (const float*)d_in[11];
    const float* W_eproj = (const float*)d_in[12];
    const float* W_oproj = (const float*)d_in[13];
    const float* W_rg    = (const float*)d_in[14];
    const float* W_re    = (const float*)d_in[15];

    float* out = (float*)d_out;

    // ---- workspace carve ----
    char* p = (char*)d_ws;
    auto alloc = [&](size_t bytes) { void* r = (void*)p; p += (bytes + 255) & ~(size_t)255; return r; };
    float* pre      = (float*)alloc((size_t)Nc * Ac * 4);
    float* h_dense  = (float*)alloc((size_t)Ec * Nc * Ac * 4);   // 16.8 MB scratch: wprepP / postP / h_dense / adaptP
    float* rpart    = (float*)alloc((size_t)RBLK * 10 * 4);
    float* fw       = (float*)alloc((size_t)Nc * 2 * 4);
    float* dmsum    = (float*)alloc((size_t)Nc * 4);
    int*   eidx     = (int*)alloc((size_t)Nc * 2 * 4);
    unsigned short* xb      = (unsigned short*)alloc((size_t)Nc * Dc * 2);
    unsigned short* Wcat_b  = (unsigned short*)alloc((size_t)(2 * Hc + Ac) * Dc * 2);
    unsigned short* Wd_b    = (unsigned short*)alloc((size_t)Dc * Hc * 2);
    unsigned short* Wop_b   = (unsigned short*)alloc((size_t)Dc * Hc * 2);
    unsigned short* Wpost_b = (unsigned short*)alloc((size_t)Ac * Hc * 2);
    unsigned short* WapT_b  = (unsigned short*)alloc((size_t)Ac * Hc * 2);
    unsigned short* WepT_b  = (unsigned short*)alloc((size_t)Ac * Hc * 2);
    unsigned short* Wdap_b  = (unsigned short*)alloc((size_t)Dc * Ac * 2);
    unsigned short* Wopep_b = (unsigned short*)alloc((size_t)Dc * Ac * 2);
    unsigned short* Aexp_b  = (unsigned short*)alloc((size_t)Ec * Ac * Ac * 2);
    unsigned short* pre_b   = (unsigned short*)alloc((size_t)Nc * Ac * 2);
    unsigned short* hidden  = (unsigned short*)alloc((size_t)Nc * Hc * 2);
    unsigned short* adapt_in  = (unsigned short*)alloc((size_t)Nc * Ac * 2);
    unsigned short* adapt_inT = (unsigned short*)alloc((size_t)Nc * Ac * 2);
    unsigned short* adapt_out = (unsigned short*)alloc((size_t)Nc * Ac * 2);
    unsigned short* adaptb    = (unsigned short*)alloc((size_t)Nc * Ac * 2);
    unsigned short* h2        = (unsigned short*)alloc((size_t)Nc * Ac * 2);

    float* wprepP = h_dense;   // [4 split][2 pair][1024*128] f32
    float* postP  = h_dense;   // [4][4096*128] f32
    float* adaptP = h_dense;   // [8][2][2048*128] f32

    // ---- merged weight prep ----
    PrepArgs pa;
    pa.csrc[0] = W_down;  pa.cdst[0] = Wd_b;    pa.cn4[0] = Dc * Hc / 4;
    pa.csrc[1] = W_oproj; pa.cdst[1] = Wop_b;   pa.cn4[1] = Dc * Hc / 4;
    pa.csrc[2] = W_post;  pa.cdst[2] = Wpost_b; pa.cn4[2] = Ac * Hc / 4;
    pa.csrc[3] = A_exp;   pa.cdst[3] = Aexp_b;  pa.cn4[3] = Ec * Ac * Ac / 4;
    pa.Wg = W_gate; pa.Wu = W_up; pa.Wpre = W_pre; pa.Wcat = Wcat_b;
    pa.tin0 = W_aproj; pa.tin1 = W_eproj; pa.tout0 = WapT_b; pa.tout1 = WepT_b;
    prep_k<<<dim3(64, 6), 256, 0, stream>>>(pa);

    // ---- router (atomic-free, also emits xb) ----
    router_k<<<RBLK, 256, 0, stream>>>(x, W_rg, W_re, eidx, fw, dmsum, rpart, xb);
    loss_k<<<1, 512, 0, stream>>>(rpart, out + (size_t)Nc * Dc);

    // ---- Wdap/Wopep split-K (4x512), z=(pair,split), then alpha=0.1 reduce ----
    mgemm64<<<dim3(2, 8, 8), 256, 0, stream>>>(Wd_b, WapT_b, wprepP, Ac, 512, Hc, Hc,
        2,
        (long long)Dc * Hc, (long long)Ac * Hc, (long long)Dc * Ac,
        512, 512, (long long)2 * Dc * Ac);
    reduce_k<4, 1><<<256, 256, 0, stream>>>(wprepP, Wdap_b,
        (long long)2 * Dc * Ac, 2 * Dc * Ac / 4, 0.1f);

    // ---- fused gate+up+pre (BK=64 swizzled): hidden = silu(gate)*up ; pre ----
    mgemm<9><<<dim3(33, 32), 256, 0, stream>>>(xb, Wcat_b, hidden, 2 * Hc + Ac, Dc, Dc, Dc, 0.f,
        pre, pre_b, 0, 0, 0);
    lntr_k<<<dim3(Sc / 64, Bc), 256, 0, stream>>>(pre, adapt_in, adapt_inT, ln_g, ln_b);

    // ---- post split-K (4x512) -> fused reduce+LN -> adapt_out ----
    mgemm64<<<dim3(2, 32, 4), 256, 0, stream>>>(hidden, Wpost_b, postP, Ac, 512, Hc, Hc,
        8, 512, 512, (long long)Nc * Ac, 0, 0, 0);
    redln_k<<<Nc, 64, 0, stream>>>(postP, adapt_out, ln_g, ln_b, (long long)Nc * Ac);

    // ---- dense expert adapter: h_dense[e] = pre_b @ A_exp[e]^T ----
    mgemm64<<<dim3(2, 32, Ec), 256, 0, stream>>>(pre_b, Aexp_b, h_dense, Ac, Ac, Ac, Ac,
        16, 0, (long long)Ac * Ac, (long long)Nc * Ac, 0, 0, 0);
    combine_k<<<Nc, 128, 0, stream>>>(h_dense, ln_g_e, ln_b_e, eidx, fw, h2);

    // ---- fused aw+adapt flash kernel -> f32 partials -> adaptb (bf16) ----
    fadapt_k<<<dim3(8, 16, 2), 256, 0, stream>>>(adapt_in, adapt_out, adapt_inT, adaptP);
    reduce_k<8, 1><<<512, 256, 0, stream>>>(adaptP, adaptb,
        (long long)2 * Sc * Ac, 2 * Sc * Ac / 4, 1.f);

    // ---- final fused (BK=64 swizzled): out = dmsum*(hidden@Wd^T + adaptb@Wdap^T) + h2@Wopep^T ----
    final_k<<<dim3(Dc / 64, Nc / 128), 256, 0, stream>>>(
        hidden, Wd_b, adaptb, Wdap_b, h2, Wopep_b, dmsum, out);
}